// Round 2
// baseline (234.064 us; speedup 1.0000x reference)
//
#include <hip/hip_runtime.h>
#include <hip/hip_bf16.h>

typedef __hip_bfloat16 bf16;

#define BB 2
#define NN 2048

// workspace float offsets
#define DIAG_OFF 0u
#define FLAG_OFF 1u
#define Q_OFF    16u        // [4096][64]
#define K_OFF    262160u    // [4096][64]
#define V_OFF    524304u    // [4096][64]
#define QP_OFF   786448u    // [4096][48]
#define KP_OFF   983056u    // [4096][48]
#define VP_OFF   1179664u   // [4096][48]
#define QSQ_OFF  1376272u   // [4096][4]
#define KSQ_OFF  1392656u   // [4096][4]
#define CF_OFF   1409040u   // [4096][3]
#define CAT_OFF  1421328u   // [4096][112]
#define PAR_OFF  1880080u   // [8 bh][4 jc][2048][32]
// end = 3,977,232 floats = 15.9 MB

__device__ __forceinline__ float b2f(bf16 x) { return __bfloat162float(x); }

template<int MODE>
__device__ __forceinline__ float LD(const void* p, size_t i) {
  if (MODE) return ((const float*)p)[i];
  return __bfloat162float(((const bf16*)p)[i]);
}

__device__ __forceinline__ bool badf(float x) { return !(fabsf(x) < 1e30f); }

__device__ __forceinline__ void diag_max(float* ws, float v) {
  atomicMax((int*)(ws + DIAG_OFF), __float_as_int(v));
}

__device__ __forceinline__ float softplus_f(float x) {
  return (x > 20.f) ? x : log1pf(__expf(x));
}

__device__ __forceinline__ float dot4(const float* a, float4 v, float acc) {
  acc = fmaf(a[0], v.x, acc); acc = fmaf(a[1], v.y, acc);
  acc = fmaf(a[2], v.z, acc); acc = fmaf(a[3], v.w, acc);
  return acc;
}
__device__ __forceinline__ void fma4(float* a, float4 v, float p) {
  a[0] = fmaf(p, v.x, a[0]); a[1] = fmaf(p, v.y, a[1]);
  a[2] = fmaf(p, v.z, a[2]); a[3] = fmaf(p, v.w, a[3]);
}

// ---------------------------------------------------------------------------
// dtype detect: bf16 N(0,1) data never has exponent-field >= 0xC0; fp32 read
// as ushort halves hits it ~25% of the time. Writes flag + zeroes diag.
// ---------------------------------------------------------------------------
__global__ __launch_bounds__(256) void detect_kernel(const unsigned short* u,
                                                     float* ws) {
  __shared__ int cnt;
  if (threadIdx.x == 0) cnt = 0;
  __syncthreads();
  int local = 0;
  for (int i = threadIdx.x; i < 4096; i += 256) {
    unsigned e = (u[i] >> 7) & 0xFFu;
    local += (e >= 0xC0u) ? 1 : 0;
  }
  atomicAdd(&cnt, local);
  __syncthreads();
  if (threadIdx.x == 0) {
    ws[FLAG_OFF] = (cnt > 64) ? 1.f : 0.f;
    ((int*)ws)[0] = 0;  // diag = 0
  }
}

// ---------------------------------------------------------------------------
// Kernel A: projections. one block per (b,i) row.
// ---------------------------------------------------------------------------
template<int MODE>
__global__ __launch_bounds__(384) void proj_kernel(
    const void* feat, const void* coords,
    const void* Wq,  const void* bq,  const void* Wk,  const void* bk,
    const void* Wv,  const void* bv,  const void* Wqp, const void* bqp,
    const void* Wkp, const void* bkp, const void* Wvp, const void* bvp,
    float* ws)
{
  if (ws[FLAG_OFF] != (float)MODE) return;
  const int row = blockIdx.x;
  const int t = threadIdx.x;
  __shared__ float sf[64];
  __shared__ float spp[96];
  if (t < 64) {
    float f = LD<MODE>(feat, (size_t)row * 64 + t);
    if (!(fabsf(f) < 1e8f)) { diag_max(ws, 400000.f); f = 0.f; }
    sf[t] = f;
  }
  __syncthreads();

  if (t < 336) {
    const void *W, *bias; int odim, c, cls;
    if (t < 64)       { W = Wq;  bias = bq;  odim = 64; c = t;       cls = 0; }
    else if (t < 128) { W = Wk;  bias = bk;  odim = 64; c = t - 64;  cls = 1; }
    else if (t < 192) { W = Wv;  bias = bv;  odim = 64; c = t - 128; cls = 2; }
    else if (t < 240) { W = Wqp; bias = bqp; odim = 48; c = t - 192; cls = 3; }
    else if (t < 288) { W = Wkp; bias = bkp; odim = 48; c = t - 240; cls = 4; }
    else              { W = Wvp; bias = bvp; odim = 48; c = t - 288; cls = 5; }
    float acc = LD<MODE>(bias, c);
    if (!(fabsf(acc) < 1e6f)) { diag_max(ws, 350000.f); acc = 0.f; }
    #pragma unroll 16
    for (int f = 0; f < 64; ++f)
      acc = fmaf(sf[f], LD<MODE>(W, (size_t)f * odim + c), acc);
    if (cls >= 3) {
      float cv = LD<MODE>(coords, (size_t)row * 3 + (c % 3));
      if (!(fabsf(cv) < 1e6f)) { diag_max(ws, 370000.f); cv = 0.f; }
      acc += cv;
    }
    if (badf(acc)) { diag_max(ws, 300000.f); acc = 0.f; }
    switch (cls) {
      case 0: ws[Q_OFF  + (size_t)row * 64 + c] = acc; break;
      case 1: ws[K_OFF  + (size_t)row * 64 + c] = acc; break;
      case 2: ws[V_OFF  + (size_t)row * 64 + c] = acc; break;
      case 3: ws[QP_OFF + (size_t)row * 48 + c] = acc; spp[c] = acc; break;
      case 4: ws[KP_OFF + (size_t)row * 48 + c] = acc; spp[48 + c] = acc; break;
      default: ws[VP_OFF + (size_t)row * 48 + c] = acc; break;
    }
  } else if (t < 339) {
    float cv = LD<MODE>(coords, (size_t)row * 3 + (t - 336));
    if (!(fabsf(cv) < 1e6f)) { diag_max(ws, 370000.f); cv = 0.f; }
    ws[CF_OFF + (size_t)row * 3 + (t - 336)] = cv;
  }
  __syncthreads();
  if (t < 8) {
    const int h = t & 3; const int isk = t >> 2;
    const float* p = &spp[isk * 48 + h * 12];
    float s = 0.f;
    #pragma unroll
    for (int e = 0; e < 12; ++e) s = fmaf(p[e], p[e], s);
    ws[(isk ? KSQ_OFF : QSQ_OFF) + (size_t)row * 4 + h] = s;
  }
}

// ---------------------------------------------------------------------------
// Kernel B: fused attention partials. grid (jc=4, it=8, bh=8), 256 threads.
// ---------------------------------------------------------------------------
template<int MODE>
__global__ __launch_bounds__(256) void attn_kernel(
    float* ws, const void* w_c, const void* w_l)
{
  if (ws[FLAG_OFF] != (float)MODE) return;
  const int tid = threadIdx.x;
  const int jc = blockIdx.x;   // 0..3  (512 j each)
  const int it = blockIdx.y;   // 0..7  (256 i each)
  const int bh = blockIdx.z;   // 0..7
  const int b = bh >> 2, h = bh & 3;
  const int i = it * 256 + tid;
  const int row = b * NN + i;

  float wl = softplus_f(LD<MODE>(w_l, h)) * 0.25f;   // fold DH^-0.5
  float wc = softplus_f(LD<MODE>(w_c, h));
  if (!(wl < 1e6f) || !(wc < 1e6f)) { diag_max(ws, 250000.f); wl = 0.25f; wc = 1.f; }

  float q[16], qp[12];
  {
    const float4* p4 = (const float4*)(ws + Q_OFF + (size_t)row * 64 + h * 16);
    #pragma unroll
    for (int u = 0; u < 4; ++u) {
      float4 v = p4[u];
      q[4*u] = v.x; q[4*u+1] = v.y; q[4*u+2] = v.z; q[4*u+3] = v.w;
    }
  }
  {
    const float4* p4 = (const float4*)(ws + QP_OFF + (size_t)row * 48 + h * 12);
    #pragma unroll
    for (int u = 0; u < 3; ++u) {
      float4 v = p4[u];
      qp[4*u] = v.x; qp[4*u+1] = v.y; qp[4*u+2] = v.z; qp[4*u+3] = v.w;
    }
  }
  const float qsq = ws[QSQ_OFF + (size_t)row * 4 + h];
  const float ci0 = ws[CF_OFF + (size_t)row * 3 + 0];
  const float ci1 = ws[CF_OFF + (size_t)row * 3 + 1];
  const float ci2 = ws[CF_OFF + (size_t)row * 3 + 2];

  // all s >= -1e9 (masked value), so -1e9 init keeps every exp arg in
  // [-2e9, 0] — no 1e30 territory anywhere.
  float m = -1e9f, l = 0.f;
  float acc[28];
  #pragma unroll
  for (int d = 0; d < 28; ++d) acc[d] = 0.f;

  __shared__ __align__(16) float skA[64 * 36];  // k16 | kp12 | cj3 | ksq
  __shared__ __align__(16) float svB[64 * 36];  // v16 | vp12 | pad

  const int j0base = jc * 512;
  for (int jt = 0; jt < 8; ++jt) {
    const int j0 = b * NN + j0base + jt * 64;
    __syncthreads();
    for (int idx = tid; idx < 1024; idx += 256) {
      const int jj = idx >> 4, d = idx & 15;
      skA[jj * 36 + d] = ws[K_OFF + (size_t)(j0 + jj) * 64 + h * 16 + d];
      svB[jj * 36 + d] = ws[V_OFF + (size_t)(j0 + jj) * 64 + h * 16 + d];
    }
    for (int idx = tid; idx < 768; idx += 256) {
      const int jj = idx / 12, e = idx - jj * 12;
      skA[jj * 36 + 16 + e] = ws[KP_OFF + (size_t)(j0 + jj) * 48 + h * 12 + e];
      svB[jj * 36 + 16 + e] = ws[VP_OFF + (size_t)(j0 + jj) * 48 + h * 12 + e];
    }
    {
      const int jj = tid >> 2, x = tid & 3;
      skA[jj * 36 + 28 + x] = (x < 3) ? ws[CF_OFF + (size_t)(j0 + jj) * 3 + x]
                                      : ws[KSQ_OFF + (size_t)(j0 + jj) * 4 + h];
    }
    __syncthreads();

    for (int jj = 0; jj < 64; ++jj) {
      const float4* ra = (const float4*)(skA + jj * 36);
      const float4 k0 = ra[0], k1 = ra[1], k2 = ra[2], k3 = ra[3];
      const float4 p0 = ra[4], p1 = ra[5], p2 = ra[6];
      const float4 cc = ra[7];

      float dot = dot4(q + 12, k3, dot4(q + 8, k2, dot4(q + 4, k1, dot4(q + 0, k0, 0.f))));
      float cr  = dot4(qp + 8, p2, dot4(qp + 4, p1, dot4(qp + 0, p0, 0.f)));
      const float pa = cr - 0.5f * (qsq + cc.w);
      float s = fmaf(wc, pa, wl * dot);

      const float dx = ci0 - cc.x, dy = ci1 - cc.y, dz = ci2 - cc.z;
      const float d2 = fmaf(dx, dx, fmaf(dy, dy, dz * dz));
      s = (d2 > 100.f) ? -1e9f : s;

      if (s > m) {
        const float alpha = __expf(m - s);
        m = s;
        l *= alpha;
        #pragma unroll
        for (int d = 0; d < 28; ++d) acc[d] *= alpha;
      }
      const float p = __expf(s - m);
      l += p;

      const float4* rb = (const float4*)(svB + jj * 36);
      fma4(acc + 0,  rb[0], p); fma4(acc + 4,  rb[1], p);
      fma4(acc + 8,  rb[2], p); fma4(acc + 12, rb[3], p);
      fma4(acc + 16, rb[4], p); fma4(acc + 20, rb[5], p);
      fma4(acc + 24, rb[6], p);
    }
  }

  bool bd = badf(m) || badf(l);
  #pragma unroll
  for (int d = 0; d < 28; ++d) bd = bd || badf(acc[d]);
  if (bd) {
    diag_max(ws, 200000.f);
    m = -1e9f; l = 1.f;
    #pragma unroll
    for (int d = 0; d < 28; ++d) acc[d] = 0.f;
  }

  float* rec = ws + PAR_OFF + (size_t)((bh * 4 + jc) * NN + i) * 32;
  rec[0] = m; rec[1] = l;
  #pragma unroll
  for (int d = 0; d < 28; ++d) rec[2 + d] = acc[d];
}

// ---------------------------------------------------------------------------
// Kernel C: merge 4 partials -> concat[4096][112]
// ---------------------------------------------------------------------------
__global__ __launch_bounds__(256) void combine_kernel(float* ws)
{
  const int g = blockIdx.x * 256 + threadIdx.x;  // (bh, i)
  const int bh = g >> 11;
  const int i = g & 2047;
  const int b = bh >> 2, h = bh & 3;
  const float* base = ws + PAR_OFF + ((size_t)bh * 4 * NN + i) * 32;

  float M = -1e30f;
  #pragma unroll
  for (int c = 0; c < 4; ++c) {
    const float mm = base[(size_t)c * NN * 32];
    if (!badf(mm)) M = fmaxf(M, mm); else diag_max(ws, 100000.f);
  }
  if (M < -1.5e29f) M = 0.f;
  float L = 0.f, o[28];
  #pragma unroll
  for (int d = 0; d < 28; ++d) o[d] = 0.f;
  for (int c = 0; c < 4; ++c) {
    const float* r = base + (size_t)c * NN * 32;
    const float r0 = r[0], ll = r[1];
    if (badf(r0) || badf(ll)) { diag_max(ws, 100000.f); continue; }
    const float w = __expf(r0 - M);
    L = fmaf(ll, w, L);
    #pragma unroll
    for (int d = 0; d < 28; ++d) o[d] = fmaf(r[2 + d], w, o[d]);
  }
  if (!(L > 1e-30f)) { diag_max(ws, 100000.f); L = 1.f; }
  const float inv = 1.f / L;
  float* cat = ws + CAT_OFF + (size_t)(b * NN + i) * 112;
  #pragma unroll
  for (int d = 0; d < 16; ++d) {
    float val = o[d] * inv;
    if (badf(val)) { diag_max(ws, 100000.f); val = 0.f; }
    cat[h * 16 + d] = val;
  }
  #pragma unroll
  for (int e = 0; e < 12; ++e) {
    float val = o[16 + e] * inv;
    if (badf(val)) { diag_max(ws, 100000.f); val = 0.f; }
    cat[64 + h * 12 + e] = val;
  }
}

// ---------------------------------------------------------------------------
// Kernel D: out = concat @ Wo + bo
// ---------------------------------------------------------------------------
template<int MODE>
__global__ __launch_bounds__(256) void out_kernel(
    float* ws, const void* Wo, const void* bo, void* outp)
{
  if (ws[FLAG_OFF] != (float)MODE) return;
  const float diag = ws[DIAG_OFF];
  const int t = threadIdx.x;
  const int blk = blockIdx.x;
  const int lr = t >> 6, c = t & 63;
  const int row = blk * 4 + lr;
  __shared__ float si[4 * 112];
  for (int idx = t; idx < 448; idx += 256)
    si[idx] = ws[CAT_OFF + (size_t)blk * 448 + idx];
  __syncthreads();
  float acc = LD<MODE>(bo, c);
  #pragma unroll 16
  for (int kk = 0; kk < 112; ++kk)
    acc = fmaf(si[lr * 112 + kk], LD<MODE>(Wo, (size_t)kk * 64 + c), acc);
  float val = acc;
  if (badf(val)) { diag_max(ws, 50000.f); val = 50000.f; }
  if (diag > 0.f) val = diag;   // surface stage sentinel via absmax
  const size_t oi = (size_t)row * 64 + c;
  if (MODE) ((float*)outp)[oi] = val;
  else      ((bf16*)outp)[oi] = __float2bfloat16(val);
}

extern "C" void kernel_launch(void* const* d_in, const int* in_sizes, int n_in,
                              void* d_out, int out_size, void* d_ws, size_t ws_size,
                              hipStream_t stream)
{
  float* ws = (float*)d_ws;

  detect_kernel<<<1, 256, 0, stream>>>((const unsigned short*)d_in[0], ws);

  proj_kernel<0><<<BB * NN, 384, 0, stream>>>(d_in[0], d_in[1], d_in[2], d_in[3],
      d_in[4], d_in[5], d_in[6], d_in[7], d_in[8], d_in[9], d_in[10], d_in[11],
      d_in[12], d_in[13], ws);
  proj_kernel<1><<<BB * NN, 384, 0, stream>>>(d_in[0], d_in[1], d_in[2], d_in[3],
      d_in[4], d_in[5], d_in[6], d_in[7], d_in[8], d_in[9], d_in[10], d_in[11],
      d_in[12], d_in[13], ws);

  attn_kernel<0><<<dim3(4, 8, 8), 256, 0, stream>>>(ws, d_in[16], d_in[17]);
  attn_kernel<1><<<dim3(4, 8, 8), 256, 0, stream>>>(ws, d_in[16], d_in[17]);

  combine_kernel<<<64, 256, 0, stream>>>(ws);

  out_kernel<0><<<(BB * NN) / 4, 256, 0, stream>>>(ws, d_in[14], d_in[15], d_out);
  out_kernel<1><<<(BB * NN) / 4, 256, 0, stream>>>(ws, d_in[14], d_in[15], d_out);
}

// Round 6
// 194.447 us; speedup vs baseline: 1.2037x; 1.2037x over previous
//
#include <hip/hip_runtime.h>
#include <hip/hip_bf16.h>

typedef __hip_bfloat16 bf16;

#define BB 2
#define NN 2048

// workspace float offsets — round-2 proven layout. PAR sized by JC at launch:
//   JC=8 : end = 3,977,232 floats = 15.9 MB  (proven fit)
//   JC=16: end = 6,074,384 floats = 24.3 MB  (used only if ws_size allows)
#define DIAG_OFF 0u
#define FLAG_OFF 1u
#define Q_OFF    16u        // [4096][64]
#define K_OFF    262160u    // [4096][64]
#define V_OFF    524304u    // [4096][64]
#define QP_OFF   786448u    // [4096][48]
#define KP_OFF   983056u    // [4096][48]
#define VP_OFF   1179664u   // [4096][48]
#define QSQ_OFF  1376272u   // [4096][4]
#define KSQ_OFF  1392656u   // [4096][4]
#define CF_OFF   1409040u   // [4096][3]
#define CAT_OFF  1421328u   // [4096][112]
#define PAR_OFF  1880080u   // [8 bh][JC][2048][16] (m, l, acc28 bf16-packed)

__device__ __forceinline__ float b2f(bf16 x) { return __bfloat162float(x); }

template<int MODE>
__device__ __forceinline__ float LD(const void* p, size_t i) {
  if (MODE) return ((const float*)p)[i];
  return __bfloat162float(((const bf16*)p)[i]);
}

__device__ __forceinline__ float softplus_f(float x) {
  return (x > 20.f) ? x : log1pf(__expf(x));
}

__device__ __forceinline__ float dot4(const float* a, float4 v, float acc) {
  acc = fmaf(a[0], v.x, acc); acc = fmaf(a[1], v.y, acc);
  acc = fmaf(a[2], v.z, acc); acc = fmaf(a[3], v.w, acc);
  return acc;
}
__device__ __forceinline__ void fma4(float* a, float4 v, float p) {
  a[0] = fmaf(p, v.x, a[0]); a[1] = fmaf(p, v.y, a[1]);
  a[2] = fmaf(p, v.z, a[2]); a[3] = fmaf(p, v.w, a[3]);
}

__device__ __forceinline__ unsigned pk2(float a, float b) {
  union { __hip_bfloat162 v; unsigned u; } cv;
  cv.v.x = __float2bfloat16(a); cv.v.y = __float2bfloat16(b);
  return cv.u;
}
__device__ __forceinline__ float2 upk2(unsigned u) {
  union { unsigned u; __hip_bfloat162 v; } cv; cv.u = u;
  return make_float2(__bfloat162float(cv.v.x), __bfloat162float(cv.v.y));
}

// ---------------------------------------------------------------------------
// dtype detect (verbatim round 2): fp32 low-halves trip exp>=0xC0 ~25% of
// the time; bf16 N(0,1) never does. flag=1 -> fp32 inputs.
// ---------------------------------------------------------------------------
__global__ __launch_bounds__(256) void detect_kernel(const unsigned short* u,
                                                     float* ws) {
  __shared__ int cnt;
  if (threadIdx.x == 0) cnt = 0;
  __syncthreads();
  int local = 0;
  for (int i = threadIdx.x; i < 4096; i += 256) {
    unsigned e = (u[i] >> 7) & 0xFFu;
    local += (e >= 0xC0u) ? 1 : 0;
  }
  atomicAdd(&cnt, local);
  __syncthreads();
  if (threadIdx.x == 0) {
    ws[FLAG_OFF] = (cnt > 64) ? 1.f : 0.f;
    ((int*)ws)[0] = 0;
  }
}

// ---------------------------------------------------------------------------
// Kernel A: projections (round-2 body, sentinels removed).
// ---------------------------------------------------------------------------
template<int MODE>
__global__ __launch_bounds__(384) void proj_kernel(
    const void* feat, const void* coords,
    const void* Wq,  const void* bq,  const void* Wk,  const void* bk,
    const void* Wv,  const void* bv,  const void* Wqp, const void* bqp,
    const void* Wkp, const void* bkp, const void* Wvp, const void* bvp,
    float* ws)
{
  if (ws[FLAG_OFF] != (float)MODE) return;
  const int row = blockIdx.x;
  const int t = threadIdx.x;
  __shared__ float sf[64];
  __shared__ float spp[96];
  if (t < 64) sf[t] = LD<MODE>(feat, (size_t)row * 64 + t);
  __syncthreads();

  if (t < 336) {
    const void *W, *bias; int odim, c, cls;
    if (t < 64)       { W = Wq;  bias = bq;  odim = 64; c = t;       cls = 0; }
    else if (t < 128) { W = Wk;  bias = bk;  odim = 64; c = t - 64;  cls = 1; }
    else if (t < 192) { W = Wv;  bias = bv;  odim = 64; c = t - 128; cls = 2; }
    else if (t < 240) { W = Wqp; bias = bqp; odim = 48; c = t - 192; cls = 3; }
    else if (t < 288) { W = Wkp; bias = bkp; odim = 48; c = t - 240; cls = 4; }
    else              { W = Wvp; bias = bvp; odim = 48; c = t - 288; cls = 5; }
    float acc = LD<MODE>(bias, c);
    #pragma unroll 16
    for (int f = 0; f < 64; ++f)
      acc = fmaf(sf[f], LD<MODE>(W, (size_t)f * odim + c), acc);
    if (cls >= 3) acc += LD<MODE>(coords, (size_t)row * 3 + (c % 3));
    switch (cls) {
      case 0: ws[Q_OFF  + (size_t)row * 64 + c] = acc; break;
      case 1: ws[K_OFF  + (size_t)row * 64 + c] = acc; break;
      case 2: ws[V_OFF  + (size_t)row * 64 + c] = acc; break;
      case 3: ws[QP_OFF + (size_t)row * 48 + c] = acc; spp[c] = acc; break;
      case 4: ws[KP_OFF + (size_t)row * 48 + c] = acc; spp[48 + c] = acc; break;
      default: ws[VP_OFF + (size_t)row * 48 + c] = acc; break;
    }
  } else if (t < 339) {
    ws[CF_OFF + (size_t)row * 3 + (t - 336)] =
        LD<MODE>(coords, (size_t)row * 3 + (t - 336));
  }
  __syncthreads();
  if (t < 8) {
    const int h = t & 3; const int isk = t >> 2;
    const float* p = &spp[isk * 48 + h * 12];
    float s = 0.f;
    #pragma unroll
    for (int e = 0; e < 12; ++e) s = fmaf(p[e], p[e], s);
    ws[(isk ? KSQ_OFF : QSQ_OFF) + (size_t)row * 4 + h] = s;
  }
}

// ---------------------------------------------------------------------------
// Kernel B: fused attention partials (round-2 body verbatim; deltas: JC j-
// chunks for occupancy, bf16-packed 16-float PAR records).
// grid (JC, 8, 8), 256 threads, 1 i-row/thread.
// ---------------------------------------------------------------------------
template<int MODE, int JC>
__global__ __launch_bounds__(256) void attn_kernel(
    float* ws, const void* w_c, const void* w_l)
{
  if (ws[FLAG_OFF] != (float)MODE) return;
  const int tid = threadIdx.x;
  const int jc = blockIdx.x;   // 0..JC-1  (2048/JC j each)
  const int it = blockIdx.y;   // 0..7     (256 i each)
  const int bh = blockIdx.z;   // 0..7
  const int b = bh >> 2, h = bh & 3;
  const int i = it * 256 + tid;
  const int row = b * NN + i;

  const float wl = softplus_f(LD<MODE>(w_l, h)) * 0.25f;   // fold DH^-0.5
  const float wc = softplus_f(LD<MODE>(w_c, h));

  float q[16], qp[12];
  #pragma unroll
  for (int u = 0; u < 4; ++u) {
    float4 v = ((const float4*)(ws + Q_OFF + (size_t)row * 64 + h * 16))[u];
    q[4*u] = v.x; q[4*u+1] = v.y; q[4*u+2] = v.z; q[4*u+3] = v.w;
  }
  #pragma unroll
  for (int u = 0; u < 3; ++u) {
    float4 v = ((const float4*)(ws + QP_OFF + (size_t)row * 48 + h * 12))[u];
    qp[4*u] = v.x; qp[4*u+1] = v.y; qp[4*u+2] = v.z; qp[4*u+3] = v.w;
  }
  const float qsq = ws[QSQ_OFF + (size_t)row * 4 + h];
  const float ci0 = ws[CF_OFF + (size_t)row * 3 + 0];
  const float ci1 = ws[CF_OFF + (size_t)row * 3 + 1];
  const float ci2 = ws[CF_OFF + (size_t)row * 3 + 2];

  float m = -1e9f, l = 0.f;
  float acc[28];
  #pragma unroll
  for (int d = 0; d < 28; ++d) acc[d] = 0.f;

  __shared__ __align__(16) float skA[64 * 36];  // k16 | kp12 | cj3 | ksq
  __shared__ __align__(16) float svB[64 * 36];  // v16 | vp12 | pad

  const int j0base = jc * (2048 / JC);
  for (int jt = 0; jt < 2048 / JC / 64; ++jt) {
    const int j0 = b * NN + j0base + jt * 64;
    __syncthreads();
    for (int idx = tid; idx < 1024; idx += 256) {
      const int jj = idx >> 4, d = idx & 15;
      skA[jj * 36 + d] = ws[K_OFF + (size_t)(j0 + jj) * 64 + h * 16 + d];
      svB[jj * 36 + d] = ws[V_OFF + (size_t)(j0 + jj) * 64 + h * 16 + d];
    }
    for (int idx = tid; idx < 768; idx += 256) {
      const int jj = idx / 12, e = idx - jj * 12;
      skA[jj * 36 + 16 + e] = ws[KP_OFF + (size_t)(j0 + jj) * 48 + h * 12 + e];
      svB[jj * 36 + 16 + e] = ws[VP_OFF + (size_t)(j0 + jj) * 48 + h * 12 + e];
    }
    {
      const int jj = tid >> 2, x = tid & 3;
      skA[jj * 36 + 28 + x] = (x < 3) ? ws[CF_OFF + (size_t)(j0 + jj) * 3 + x]
                                      : ws[KSQ_OFF + (size_t)(j0 + jj) * 4 + h];
    }
    __syncthreads();

    for (int jj = 0; jj < 64; ++jj) {
      const float4* ra = (const float4*)(skA + jj * 36);
      const float4 k0 = ra[0], k1 = ra[1], k2 = ra[2], k3 = ra[3];
      const float4 p0 = ra[4], p1 = ra[5], p2 = ra[6];
      const float4 cc = ra[7];   // cj.x, cj.y, cj.z, ksq

      float dot = (dot4(q, k0, 0.f) + dot4(q + 4, k1, 0.f)) +
                  (dot4(q + 8, k2, 0.f) + dot4(q + 12, k3, 0.f));
      float cr  = (dot4(qp, p0, 0.f) + dot4(qp + 4, p1, 0.f)) + dot4(qp + 8, p2, 0.f);
      const float pa = cr - 0.5f * (qsq + cc.w);
      float s = fmaf(wc, pa, wl * dot);

      const float dx = ci0 - cc.x, dy = ci1 - cc.y, dz = ci2 - cc.z;
      const float d2 = fmaf(dx, dx, fmaf(dy, dy, dz * dz));
      s = (d2 > 100.f) ? -1e9f : s;

      if (s > m) {
        const float alpha = __expf(m - s);
        m = s; l *= alpha;
        #pragma unroll
        for (int d = 0; d < 28; ++d) acc[d] *= alpha;
      }
      const float p = __expf(s - m);
      l += p;

      const float4* rb = (const float4*)(svB + jj * 36);
      fma4(acc + 0,  rb[0], p); fma4(acc + 4,  rb[1], p);
      fma4(acc + 8,  rb[2], p); fma4(acc + 12, rb[3], p);
      fma4(acc + 16, rb[4], p); fma4(acc + 20, rb[5], p);
      fma4(acc + 24, rb[6], p);
    }
  }

  float* rec = ws + PAR_OFF + ((size_t)(bh * JC + jc) * NN + i) * 16;
  rec[0] = m; rec[1] = l;
  unsigned* ru = (unsigned*)(rec + 2);
  #pragma unroll
  for (int d = 0; d < 14; ++d) ru[d] = pk2(acc[2 * d], acc[2 * d + 1]);
}

// ---------------------------------------------------------------------------
// Kernel C: merge JC softmax partials -> concat[4096][112]
// ---------------------------------------------------------------------------
template<int JC>
__global__ __launch_bounds__(128) void combine_kernel(float* ws)
{
  const int g = blockIdx.x * 128 + threadIdx.x;  // (bh, i)
  const int bh = g >> 11;
  const int i = g & 2047;
  const int b = bh >> 2, h = bh & 3;
  const float* base = ws + PAR_OFF + ((size_t)bh * JC * NN + i) * 16;

  float M = -1e9f;
  #pragma unroll
  for (int c = 0; c < JC; ++c) M = fmaxf(M, base[(size_t)c * NN * 16]);
  float L = 0.f, o[28];
  #pragma unroll
  for (int d = 0; d < 28; ++d) o[d] = 0.f;
  for (int c = 0; c < JC; ++c) {
    const float* r = base + (size_t)c * NN * 16;
    const float w = __expf(r[0] - M);
    L = fmaf(r[1], w, L);
    const unsigned* ru = (const unsigned*)(r + 2);
    #pragma unroll
    for (int d = 0; d < 14; ++d) {
      const float2 f = upk2(ru[d]);
      o[2 * d]     = fmaf(f.x, w, o[2 * d]);
      o[2 * d + 1] = fmaf(f.y, w, o[2 * d + 1]);
    }
  }
  const float inv = 1.f / L;
  float* cat = ws + CAT_OFF + (size_t)(b * NN + i) * 112;
  #pragma unroll
  for (int d = 0; d < 16; ++d) cat[h * 16 + d] = o[d] * inv;
  #pragma unroll
  for (int e = 0; e < 12; ++e) cat[64 + h * 12 + e] = o[16 + e] * inv;
}

// ---------------------------------------------------------------------------
// Kernel D: out = concat[4096][112] @ Wo[112][64] + bo
// ---------------------------------------------------------------------------
template<int MODE>
__global__ __launch_bounds__(256) void out_kernel(
    float* ws, const void* Wo, const void* bo, void* outp)
{
  if (ws[FLAG_OFF] != (float)MODE) return;
  const int t = threadIdx.x;
  const int blk = blockIdx.x;
  const int lr = t >> 6, c = t & 63;
  const int row = blk * 4 + lr;
  __shared__ float si[4 * 112];
  for (int idx = t; idx < 448; idx += 256)
    si[idx] = ws[CAT_OFF + (size_t)blk * 448 + idx];
  __syncthreads();
  float acc = LD<MODE>(bo, c);
  #pragma unroll 16
  for (int kk = 0; kk < 112; ++kk)
    acc = fmaf(si[lr * 112 + kk], LD<MODE>(Wo, (size_t)kk * 64 + c), acc);
  const size_t oi = (size_t)row * 64 + c;
  if (MODE) ((float*)outp)[oi] = acc;
  else      ((bf16*)outp)[oi] = __float2bfloat16(acc);
}

extern "C" void kernel_launch(void* const* d_in, const int* in_sizes, int n_in,
                              void* d_out, int out_size, void* d_ws, size_t ws_size,
                              hipStream_t stream)
{
  float* ws = (float*)d_ws;

  detect_kernel<<<1, 256, 0, stream>>>((const unsigned short*)d_in[0], ws);

  proj_kernel<0><<<BB * NN, 384, 0, stream>>>(d_in[0], d_in[1], d_in[2], d_in[3],
      d_in[4], d_in[5], d_in[6], d_in[7], d_in[8], d_in[9], d_in[10], d_in[11],
      d_in[12], d_in[13], ws);
  proj_kernel<1><<<BB * NN, 384, 0, stream>>>(d_in[0], d_in[1], d_in[2], d_in[3],
      d_in[4], d_in[5], d_in[6], d_in[7], d_in[8], d_in[9], d_in[10], d_in[11],
      d_in[12], d_in[13], ws);

  // JC=16 needs 24.3 MB of ws; fall back to proven 15.9 MB JC=8 otherwise.
  const bool big = ws_size >= (size_t)(PAR_OFF + 8u * 16u * NN * 16u) * 4u;
  if (big) {
    attn_kernel<0, 16><<<dim3(16, 8, 8), 256, 0, stream>>>(ws, d_in[16], d_in[17]);
    attn_kernel<1, 16><<<dim3(16, 8, 8), 256, 0, stream>>>(ws, d_in[16], d_in[17]);
    combine_kernel<16><<<128, 128, 0, stream>>>(ws);
  } else {
    attn_kernel<0, 8><<<dim3(8, 8, 8), 256, 0, stream>>>(ws, d_in[16], d_in[17]);
    attn_kernel<1, 8><<<dim3(8, 8, 8), 256, 0, stream>>>(ws, d_in[16], d_in[17]);
    combine_kernel<8><<<128, 128, 0, stream>>>(ws);
  }

  out_kernel<0><<<(BB * NN) / 4, 256, 0, stream>>>(ws, d_in[14], d_in[15], d_out);
  out_kernel<1><<<(BB * NN) / 4, 256, 0, stream>>>(ws, d_in[14], d_in[15], d_out);
}

// Round 7
// 182.987 us; speedup vs baseline: 1.2791x; 1.0626x over previous
//
#include <hip/hip_runtime.h>
#include <hip/hip_bf16.h>

typedef __hip_bfloat16 bf16;

#define BB 2
#define NN 2048

// workspace float offsets — proven layout. PAR sized by JC at launch:
//   JC=8 : end = 3,977,232 floats = 15.9 MB  (proven fit)
//   JC=16: end = 6,074,384 floats = 24.3 MB  (used only if ws_size allows)
#define DIAG_OFF 0u
#define FLAG_OFF 1u
#define Q_OFF    16u        // [4096][64]
#define K_OFF    262160u    // [4096][64]
#define V_OFF    524304u    // [4096][64]
#define QP_OFF   786448u    // [4096][48]
#define KP_OFF   983056u    // [4096][48]
#define VP_OFF   1179664u   // [4096][48]
#define QSQ_OFF  1376272u   // [4096][4]
#define KSQ_OFF  1392656u   // [4096][4]
#define CF_OFF   1409040u   // [4096][3]
#define CAT_OFF  1421328u   // [4096][112]
#define PAR_OFF  1880080u   // [8 bh][JC][2048][16] (m, l, acc28 bf16-packed)

__device__ __forceinline__ float b2f(bf16 x) { return __bfloat162float(x); }

template<int MODE>
__device__ __forceinline__ float LD(const void* p, size_t i) {
  if (MODE) return ((const float*)p)[i];
  return __bfloat162float(((const bf16*)p)[i]);
}

__device__ __forceinline__ float softplus_f(float x) {
  return (x > 20.f) ? x : log1pf(__expf(x));
}

__device__ __forceinline__ float dot4(const float* a, float4 v, float acc) {
  acc = fmaf(a[0], v.x, acc); acc = fmaf(a[1], v.y, acc);
  acc = fmaf(a[2], v.z, acc); acc = fmaf(a[3], v.w, acc);
  return acc;
}
__device__ __forceinline__ void fma4(float* a, float4 v, float p) {
  a[0] = fmaf(p, v.x, a[0]); a[1] = fmaf(p, v.y, a[1]);
  a[2] = fmaf(p, v.z, a[2]); a[3] = fmaf(p, v.w, a[3]);
}

__device__ __forceinline__ unsigned pk2(float a, float b) {
  union { __hip_bfloat162 v; unsigned u; } cv;
  cv.v.x = __float2bfloat16(a); cv.v.y = __float2bfloat16(b);
  return cv.u;
}
__device__ __forceinline__ float2 upk2(unsigned u) {
  union { unsigned u; __hip_bfloat162 v; } cv; cv.u = u;
  return make_float2(__bfloat162float(cv.v.x), __bfloat162float(cv.v.y));
}

// ---------------------------------------------------------------------------
// dtype detect (verbatim): fp32 low-halves trip exp>=0xC0 ~25% of the time;
// bf16 N(0,1) never does. flag=1 -> fp32 inputs.
// ---------------------------------------------------------------------------
__global__ __launch_bounds__(256) void detect_kernel(const unsigned short* u,
                                                     float* ws) {
  __shared__ int cnt;
  if (threadIdx.x == 0) cnt = 0;
  __syncthreads();
  int local = 0;
  for (int i = threadIdx.x; i < 4096; i += 256) {
    unsigned e = (u[i] >> 7) & 0xFFu;
    local += (e >= 0xC0u) ? 1 : 0;
  }
  atomicAdd(&cnt, local);
  __syncthreads();
  if (threadIdx.x == 0) {
    ws[FLAG_OFF] = (cnt > 64) ? 1.f : 0.f;
    ((int*)ws)[0] = 0;
  }
}

// ---------------------------------------------------------------------------
// Kernel A: projections (verbatim from passing round 6).
// ---------------------------------------------------------------------------
template<int MODE>
__global__ __launch_bounds__(384) void proj_kernel(
    const void* feat, const void* coords,
    const void* Wq,  const void* bq,  const void* Wk,  const void* bk,
    const void* Wv,  const void* bv,  const void* Wqp, const void* bqp,
    const void* Wkp, const void* bkp, const void* Wvp, const void* bvp,
    float* ws)
{
  if (ws[FLAG_OFF] != (float)MODE) return;
  const int row = blockIdx.x;
  const int t = threadIdx.x;
  __shared__ float sf[64];
  __shared__ float spp[96];
  if (t < 64) sf[t] = LD<MODE>(feat, (size_t)row * 64 + t);
  __syncthreads();

  if (t < 336) {
    const void *W, *bias; int odim, c, cls;
    if (t < 64)       { W = Wq;  bias = bq;  odim = 64; c = t;       cls = 0; }
    else if (t < 128) { W = Wk;  bias = bk;  odim = 64; c = t - 64;  cls = 1; }
    else if (t < 192) { W = Wv;  bias = bv;  odim = 64; c = t - 128; cls = 2; }
    else if (t < 240) { W = Wqp; bias = bqp; odim = 48; c = t - 192; cls = 3; }
    else if (t < 288) { W = Wkp; bias = bkp; odim = 48; c = t - 240; cls = 4; }
    else              { W = Wvp; bias = bvp; odim = 48; c = t - 288; cls = 5; }
    float acc = LD<MODE>(bias, c);
    #pragma unroll 16
    for (int f = 0; f < 64; ++f)
      acc = fmaf(sf[f], LD<MODE>(W, (size_t)f * odim + c), acc);
    if (cls >= 3) acc += LD<MODE>(coords, (size_t)row * 3 + (c % 3));
    switch (cls) {
      case 0: ws[Q_OFF  + (size_t)row * 64 + c] = acc; break;
      case 1: ws[K_OFF  + (size_t)row * 64 + c] = acc; break;
      case 2: ws[V_OFF  + (size_t)row * 64 + c] = acc; break;
      case 3: ws[QP_OFF + (size_t)row * 48 + c] = acc; spp[c] = acc; break;
      case 4: ws[KP_OFF + (size_t)row * 48 + c] = acc; spp[48 + c] = acc; break;
      default: ws[VP_OFF + (size_t)row * 48 + c] = acc; break;
    }
  } else if (t < 339) {
    ws[CF_OFF + (size_t)row * 3 + (t - 336)] =
        LD<MODE>(coords, (size_t)row * 3 + (t - 336));
  }
  __syncthreads();
  if (t < 8) {
    const int h = t & 3; const int isk = t >> 2;
    const float* p = &spp[isk * 48 + h * 12];
    float s = 0.f;
    #pragma unroll
    for (int e = 0; e < 12; ++e) s = fmaf(p[e], p[e], s);
    ws[(isk ? KSQ_OFF : QSQ_OFF) + (size_t)row * 4 + h] = s;
  }
}

// ---------------------------------------------------------------------------
// Kernel B: fused attention partials. Deltas from passing round 6:
//   * 2 i-rows per thread (i0, i0+256): 15 LDS b128 reads serve 2 pairs
//   * defer-max rescale (THR=8): rescale body becomes rare
//   * wl folded into q, wc into qp, -0.5*wc into staged ksq; qsq dropped
//     (per-row constant, cancels in softmax)
//   * disjoint __restrict__ region pointers
// grid (JC, 4, 8), 256 threads.
// ---------------------------------------------------------------------------
template<int MODE, int JC>
__global__ __launch_bounds__(256) void attn_kernel(
    const float* __restrict__ qbuf,  const float* __restrict__ qpbuf,
    const float* __restrict__ kbuf,  const float* __restrict__ kpbuf,
    const float* __restrict__ vbuf,  const float* __restrict__ vpbuf,
    const float* __restrict__ cfbuf, const float* __restrict__ ksqbuf,
    float* __restrict__ parbuf, const float* flagp,
    const void* w_c, const void* w_l)
{
  if (*flagp != (float)MODE) return;
  const int tid = threadIdx.x;
  const int jc = blockIdx.x;   // 0..JC-1  (2048/JC j each)
  const int it = blockIdx.y;   // 0..3     (512 i each)
  const int bh = blockIdx.z;   // 0..7
  const int b = bh >> 2, h = bh & 3;
  const int i0 = it * 512 + tid;
  const int r0 = b * NN + i0;
  const int r1 = r0 + 256;

  const float wl = softplus_f(LD<MODE>(w_l, h)) * 0.25f;   // fold DH^-0.5
  const float wc = softplus_f(LD<MODE>(w_c, h));

  float qA[16], qB[16], pA[12], pB[12];
  #pragma unroll
  for (int u = 0; u < 4; ++u) {
    float4 va = ((const float4*)(qbuf + (size_t)r0 * 64 + h * 16))[u];
    float4 vb = ((const float4*)(qbuf + (size_t)r1 * 64 + h * 16))[u];
    qA[4*u] = wl*va.x; qA[4*u+1] = wl*va.y; qA[4*u+2] = wl*va.z; qA[4*u+3] = wl*va.w;
    qB[4*u] = wl*vb.x; qB[4*u+1] = wl*vb.y; qB[4*u+2] = wl*vb.z; qB[4*u+3] = wl*vb.w;
  }
  #pragma unroll
  for (int u = 0; u < 3; ++u) {
    float4 va = ((const float4*)(qpbuf + (size_t)r0 * 48 + h * 12))[u];
    float4 vb = ((const float4*)(qpbuf + (size_t)r1 * 48 + h * 12))[u];
    pA[4*u] = wc*va.x; pA[4*u+1] = wc*va.y; pA[4*u+2] = wc*va.z; pA[4*u+3] = wc*va.w;
    pB[4*u] = wc*vb.x; pB[4*u+1] = wc*vb.y; pB[4*u+2] = wc*vb.z; pB[4*u+3] = wc*vb.w;
  }
  const float ciA0 = cfbuf[(size_t)r0 * 3 + 0];
  const float ciA1 = cfbuf[(size_t)r0 * 3 + 1];
  const float ciA2 = cfbuf[(size_t)r0 * 3 + 2];
  const float ciB0 = cfbuf[(size_t)r1 * 3 + 0];
  const float ciB1 = cfbuf[(size_t)r1 * 3 + 1];
  const float ciB2 = cfbuf[(size_t)r1 * 3 + 2];

  float mA = -1e9f, lA = 0.f, mB = -1e9f, lB = 0.f;
  float accA[28], accB[28];
  #pragma unroll
  for (int d = 0; d < 28; ++d) { accA[d] = 0.f; accB[d] = 0.f; }

  __shared__ __align__(16) float skA[64 * 36];  // k16 | kp12 | cj3 | -0.5*wc*ksq
  __shared__ __align__(16) float svB[64 * 36];  // v16 | vp12 | pad

  const int j0base = jc * (2048 / JC);
  for (int jt = 0; jt < 2048 / JC / 64; ++jt) {
    const int j0 = b * NN + j0base + jt * 64;
    __syncthreads();
    for (int idx = tid; idx < 1024; idx += 256) {
      const int jj = idx >> 4, d = idx & 15;
      skA[jj * 36 + d] = kbuf[(size_t)(j0 + jj) * 64 + h * 16 + d];
      svB[jj * 36 + d] = vbuf[(size_t)(j0 + jj) * 64 + h * 16 + d];
    }
    for (int idx = tid; idx < 768; idx += 256) {
      const int jj = idx / 12, e = idx - jj * 12;
      skA[jj * 36 + 16 + e] = kpbuf[(size_t)(j0 + jj) * 48 + h * 12 + e];
      svB[jj * 36 + 16 + e] = vpbuf[(size_t)(j0 + jj) * 48 + h * 12 + e];
    }
    {
      const int jj = tid >> 2, x = tid & 3;
      skA[jj * 36 + 28 + x] = (x < 3)
          ? cfbuf[(size_t)(j0 + jj) * 3 + x]
          : -0.5f * wc * ksqbuf[(size_t)(j0 + jj) * 4 + h];
    }
    __syncthreads();

    for (int jj = 0; jj < 64; ++jj) {
      const float4* ra = (const float4*)(skA + jj * 36);
      const float4 k0 = ra[0], k1 = ra[1], k2 = ra[2], k3 = ra[3];
      const float4 p0 = ra[4], p1 = ra[5], p2 = ra[6];
      const float4 cc = ra[7];   // cj.x, cj.y, cj.z, -0.5*wc*ksq

      float dA = (dot4(qA, k0, 0.f) + dot4(qA + 4, k1, 0.f)) +
                 (dot4(qA + 8, k2, 0.f) + dot4(qA + 12, k3, 0.f));
      float dB = (dot4(qB, k0, 0.f) + dot4(qB + 4, k1, 0.f)) +
                 (dot4(qB + 8, k2, 0.f) + dot4(qB + 12, k3, 0.f));
      float cA = (dot4(pA, p0, cc.w) + dot4(pA + 4, p1, 0.f)) + dot4(pA + 8, p2, 0.f);
      float cB = (dot4(pB, p0, cc.w) + dot4(pB + 4, p1, 0.f)) + dot4(pB + 8, p2, 0.f);

      float sA = dA + cA;
      float sB = dB + cB;

      float dx = ciA0 - cc.x, dy = ciA1 - cc.y, dz = ciA2 - cc.z;
      float d2 = fmaf(dx, dx, fmaf(dy, dy, dz * dz));
      sA = (d2 > 100.f) ? -1e9f : sA;
      dx = ciB0 - cc.x; dy = ciB1 - cc.y; dz = ciB2 - cc.z;
      d2 = fmaf(dx, dx, fmaf(dy, dy, dz * dz));
      sB = (d2 > 100.f) ? -1e9f : sB;

      // defer-max: rescale only when the running max grows by > 8.
      // p <= e^8 — fp32/bf16-safe; exact softmax factorization preserved.
      if (sA > mA + 8.f) {
        const float alpha = __expf(mA - sA);
        mA = sA; lA *= alpha;
        #pragma unroll
        for (int d = 0; d < 28; ++d) accA[d] *= alpha;
      }
      if (sB > mB + 8.f) {
        const float alpha = __expf(mB - sB);
        mB = sB; lB *= alpha;
        #pragma unroll
        for (int d = 0; d < 28; ++d) accB[d] *= alpha;
      }
      const float pa = __expf(sA - mA);
      const float pb = __expf(sB - mB);
      lA += pa; lB += pb;

      const float4* rb = (const float4*)(svB + jj * 36);
      const float4 v0 = rb[0], v1 = rb[1], v2 = rb[2], v3 = rb[3];
      const float4 v4 = rb[4], v5 = rb[5], v6 = rb[6];
      fma4(accA + 0, v0, pa);  fma4(accB + 0, v0, pb);
      fma4(accA + 4, v1, pa);  fma4(accB + 4, v1, pb);
      fma4(accA + 8, v2, pa);  fma4(accB + 8, v2, pb);
      fma4(accA + 12, v3, pa); fma4(accB + 12, v3, pb);
      fma4(accA + 16, v4, pa); fma4(accB + 16, v4, pb);
      fma4(accA + 20, v5, pa); fma4(accB + 20, v5, pb);
      fma4(accA + 24, v6, pa); fma4(accB + 24, v6, pb);
    }
  }

  {
    float* rec = parbuf + ((size_t)(bh * JC + jc) * NN + i0) * 16;
    rec[0] = mA; rec[1] = lA;
    unsigned* ru = (unsigned*)(rec + 2);
    #pragma unroll
    for (int d = 0; d < 14; ++d) ru[d] = pk2(accA[2 * d], accA[2 * d + 1]);
  }
  {
    float* rec = parbuf + ((size_t)(bh * JC + jc) * NN + i0 + 256) * 16;
    rec[0] = mB; rec[1] = lB;
    unsigned* ru = (unsigned*)(rec + 2);
    #pragma unroll
    for (int d = 0; d < 14; ++d) ru[d] = pk2(accB[2 * d], accB[2 * d + 1]);
  }
}

// ---------------------------------------------------------------------------
// Kernel C: merge JC softmax partials -> concat[4096][112]  (verbatim)
// ---------------------------------------------------------------------------
template<int JC>
__global__ __launch_bounds__(128) void combine_kernel(float* ws)
{
  const int g = blockIdx.x * 128 + threadIdx.x;  // (bh, i)
  const int bh = g >> 11;
  const int i = g & 2047;
  const int b = bh >> 2, h = bh & 3;
  const float* base = ws + PAR_OFF + ((size_t)bh * JC * NN + i) * 16;

  float M = -1e9f;
  #pragma unroll
  for (int c = 0; c < JC; ++c) M = fmaxf(M, base[(size_t)c * NN * 16]);
  float L = 0.f, o[28];
  #pragma unroll
  for (int d = 0; d < 28; ++d) o[d] = 0.f;
  for (int c = 0; c < JC; ++c) {
    const float* r = base + (size_t)c * NN * 16;
    const float w = __expf(r[0] - M);
    L = fmaf(r[1], w, L);
    const unsigned* ru = (const unsigned*)(r + 2);
    #pragma unroll
    for (int d = 0; d < 14; ++d) {
      const float2 f = upk2(ru[d]);
      o[2 * d]     = fmaf(f.x, w, o[2 * d]);
      o[2 * d + 1] = fmaf(f.y, w, o[2 * d + 1]);
    }
  }
  const float inv = 1.f / L;
  float* cat = ws + CAT_OFF + (size_t)(b * NN + i) * 112;
  #pragma unroll
  for (int d = 0; d < 16; ++d) cat[h * 16 + d] = o[d] * inv;
  #pragma unroll
  for (int e = 0; e < 12; ++e) cat[64 + h * 12 + e] = o[16 + e] * inv;
}

// ---------------------------------------------------------------------------
// Kernel D: out = concat[4096][112] @ Wo[112][64] + bo  (verbatim)
// ---------------------------------------------------------------------------
template<int MODE>
__global__ __launch_bounds__(256) void out_kernel(
    float* ws, const void* Wo, const void* bo, void* outp)
{
  if (ws[FLAG_OFF] != (float)MODE) return;
  const int t = threadIdx.x;
  const int blk = blockIdx.x;
  const int lr = t >> 6, c = t & 63;
  const int row = blk * 4 + lr;
  __shared__ float si[4 * 112];
  for (int idx = t; idx < 448; idx += 256)
    si[idx] = ws[CAT_OFF + (size_t)blk * 448 + idx];
  __syncthreads();
  float acc = LD<MODE>(bo, c);
  #pragma unroll 16
  for (int kk = 0; kk < 112; ++kk)
    acc = fmaf(si[lr * 112 + kk], LD<MODE>(Wo, (size_t)kk * 64 + c), acc);
  const size_t oi = (size_t)row * 64 + c;
  if (MODE) ((float*)outp)[oi] = acc;
  else      ((bf16*)outp)[oi] = __float2bfloat16(acc);
}

extern "C" void kernel_launch(void* const* d_in, const int* in_sizes, int n_in,
                              void* d_out, int out_size, void* d_ws, size_t ws_size,
                              hipStream_t stream)
{
  float* ws = (float*)d_ws;

  detect_kernel<<<1, 256, 0, stream>>>((const unsigned short*)d_in[0], ws);

  proj_kernel<0><<<BB * NN, 384, 0, stream>>>(d_in[0], d_in[1], d_in[2], d_in[3],
      d_in[4], d_in[5], d_in[6], d_in[7], d_in[8], d_in[9], d_in[10], d_in[11],
      d_in[12], d_in[13], ws);
  proj_kernel<1><<<BB * NN, 384, 0, stream>>>(d_in[0], d_in[1], d_in[2], d_in[3],
      d_in[4], d_in[5], d_in[6], d_in[7], d_in[8], d_in[9], d_in[10], d_in[11],
      d_in[12], d_in[13], ws);

  const float* qb  = ws + Q_OFF;   const float* qpb = ws + QP_OFF;
  const float* kb  = ws + K_OFF;   const float* kpb = ws + KP_OFF;
  const float* vb  = ws + V_OFF;   const float* vpb = ws + VP_OFF;
  const float* cfb = ws + CF_OFF;  const float* ksb = ws + KSQ_OFF;
  float* parb = ws + PAR_OFF;      const float* flagp = ws + FLAG_OFF;

  // JC=16 needs 24.3 MB of ws; fall back to proven 15.9 MB JC=8 otherwise.
  const bool big = ws_size >= (size_t)(PAR_OFF + 8u * 16u * NN * 16u) * 4u;
  if (big) {
    attn_kernel<0, 16><<<dim3(16, 4, 8), 256, 0, stream>>>(
        qb, qpb, kb, kpb, vb, vpb, cfb, ksb, parb, flagp, d_in[16], d_in[17]);
    attn_kernel<1, 16><<<dim3(16, 4, 8), 256, 0, stream>>>(
        qb, qpb, kb, kpb, vb, vpb, cfb, ksb, parb, flagp, d_in[16], d_in[17]);
    combine_kernel<16><<<128, 128, 0, stream>>>(ws);
  } else {
    attn_kernel<0, 8><<<dim3(8, 4, 8), 256, 0, stream>>>(
        qb, qpb, kb, kpb, vb, vpb, cfb, ksb, parb, flagp, d_in[16], d_in[17]);
    attn_kernel<1, 8><<<dim3(8, 4, 8), 256, 0, stream>>>(
        qb, qpb, kb, kpb, vb, vpb, cfb, ksb, parb, flagp, d_in[16], d_in[17]);
    combine_kernel<8><<<128, 128, 0, stream>>>(ws);
  }

  out_kernel<0><<<(BB * NN) / 4, 256, 0, stream>>>(ws, d_in[14], d_in[15], d_out);
  out_kernel<1><<<(BB * NN) / 4, 256, 0, stream>>>(ws, d_in[14], d_in[15], d_out);
}

// Round 8
// 182.501 us; speedup vs baseline: 1.2825x; 1.0027x over previous
//
#include <hip/hip_runtime.h>
#include <hip/hip_bf16.h>

typedef __hip_bfloat16 bf16;

#define BB 2
#define NN 2048

// workspace float offsets — proven layout. PAR sized by JC at launch:
//   JC=8 : end = 3,977,232 floats = 15.9 MB  (proven fit)
//   JC=16: end = 6,074,384 floats = 24.3 MB  (proven fit in rounds 6/7)
#define DIAG_OFF 0u
#define FLAG_OFF 1u
#define Q_OFF    16u        // [4096][64]
#define K_OFF    262160u    // [4096][64]
#define V_OFF    524304u    // [4096][64]
#define QP_OFF   786448u    // [4096][48]
#define KP_OFF   983056u    // [4096][48]
#define VP_OFF   1179664u   // [4096][48]
#define QSQ_OFF  1376272u   // [4096][4]
#define KSQ_OFF  1392656u   // [4096][4]
#define CF_OFF   1409040u   // [4096][3]
#define CAT_OFF  1421328u   // [4096][112]
#define PAR_OFF  1880080u   // [8 bh][JC][2048][16] (m, l, acc28 bf16-packed)

__device__ __forceinline__ float b2f(bf16 x) { return __bfloat162float(x); }

template<int MODE>
__device__ __forceinline__ float LD(const void* p, size_t i) {
  if (MODE) return ((const float*)p)[i];
  return __bfloat162float(((const bf16*)p)[i]);
}

__device__ __forceinline__ float softplus_f(float x) {
  return (x > 20.f) ? x : log1pf(__expf(x));
}

__device__ __forceinline__ float dot4(const float* a, float4 v, float acc) {
  acc = fmaf(a[0], v.x, acc); acc = fmaf(a[1], v.y, acc);
  acc = fmaf(a[2], v.z, acc); acc = fmaf(a[3], v.w, acc);
  return acc;
}
__device__ __forceinline__ void fma4(float* a, float4 v, float p) {
  a[0] = fmaf(p, v.x, a[0]); a[1] = fmaf(p, v.y, a[1]);
  a[2] = fmaf(p, v.z, a[2]); a[3] = fmaf(p, v.w, a[3]);
}

__device__ __forceinline__ unsigned pk2(float a, float b) {
  union { __hip_bfloat162 v; unsigned u; } cv;
  cv.v.x = __float2bfloat16(a); cv.v.y = __float2bfloat16(b);
  return cv.u;
}
__device__ __forceinline__ float2 upk2(unsigned u) {
  union { unsigned u; __hip_bfloat162 v; } cv; cv.u = u;
  return make_float2(__bfloat162float(cv.v.x), __bfloat162float(cv.v.y));
}

// ---------------------------------------------------------------------------
// dtype detect (verbatim): fp32 low-halves trip exp>=0xC0 ~25% of the time;
// bf16 N(0,1) never does. flag=1 -> fp32 inputs.
// ---------------------------------------------------------------------------
__global__ __launch_bounds__(256) void detect_kernel(const unsigned short* u,
                                                     float* ws) {
  __shared__ int cnt;
  if (threadIdx.x == 0) cnt = 0;
  __syncthreads();
  int local = 0;
  for (int i = threadIdx.x; i < 4096; i += 256) {
    unsigned e = (u[i] >> 7) & 0xFFu;
    local += (e >= 0xC0u) ? 1 : 0;
  }
  atomicAdd(&cnt, local);
  __syncthreads();
  if (threadIdx.x == 0) {
    ws[FLAG_OFF] = (cnt > 64) ? 1.f : 0.f;
    ((int*)ws)[0] = 0;
  }
}

// ---------------------------------------------------------------------------
// Kernel A: projections (verbatim from passing rounds 6/7).
// ---------------------------------------------------------------------------
template<int MODE>
__global__ __launch_bounds__(384) void proj_kernel(
    const void* feat, const void* coords,
    const void* Wq,  const void* bq,  const void* Wk,  const void* bk,
    const void* Wv,  const void* bv,  const void* Wqp, const void* bqp,
    const void* Wkp, const void* bkp, const void* Wvp, const void* bvp,
    float* ws)
{
  if (ws[FLAG_OFF] != (float)MODE) return;
  const int row = blockIdx.x;
  const int t = threadIdx.x;
  __shared__ float sf[64];
  __shared__ float spp[96];
  if (t < 64) sf[t] = LD<MODE>(feat, (size_t)row * 64 + t);
  __syncthreads();

  if (t < 336) {
    const void *W, *bias; int odim, c, cls;
    if (t < 64)       { W = Wq;  bias = bq;  odim = 64; c = t;       cls = 0; }
    else if (t < 128) { W = Wk;  bias = bk;  odim = 64; c = t - 64;  cls = 1; }
    else if (t < 192) { W = Wv;  bias = bv;  odim = 64; c = t - 128; cls = 2; }
    else if (t < 240) { W = Wqp; bias = bqp; odim = 48; c = t - 192; cls = 3; }
    else if (t < 288) { W = Wkp; bias = bkp; odim = 48; c = t - 240; cls = 4; }
    else              { W = Wvp; bias = bvp; odim = 48; c = t - 288; cls = 5; }
    float acc = LD<MODE>(bias, c);
    #pragma unroll 16
    for (int f = 0; f < 64; ++f)
      acc = fmaf(sf[f], LD<MODE>(W, (size_t)f * odim + c), acc);
    if (cls >= 3) acc += LD<MODE>(coords, (size_t)row * 3 + (c % 3));
    switch (cls) {
      case 0: ws[Q_OFF  + (size_t)row * 64 + c] = acc; break;
      case 1: ws[K_OFF  + (size_t)row * 64 + c] = acc; break;
      case 2: ws[V_OFF  + (size_t)row * 64 + c] = acc; break;
      case 3: ws[QP_OFF + (size_t)row * 48 + c] = acc; spp[c] = acc; break;
      case 4: ws[KP_OFF + (size_t)row * 48 + c] = acc; spp[48 + c] = acc; break;
      default: ws[VP_OFF + (size_t)row * 48 + c] = acc; break;
    }
  } else if (t < 339) {
    ws[CF_OFF + (size_t)row * 3 + (t - 336)] =
        LD<MODE>(coords, (size_t)row * 3 + (t - 336));
  }
  __syncthreads();
  if (t < 8) {
    const int h = t & 3; const int isk = t >> 2;
    const float* p = &spp[isk * 48 + h * 12];
    float s = 0.f;
    #pragma unroll
    for (int e = 0; e < 12; ++e) s = fmaf(p[e], p[e], s);
    ws[(isk ? KSQ_OFF : QSQ_OFF) + (size_t)row * 4 + h] = s;
  }
}

// ---------------------------------------------------------------------------
// Kernel B: fused attention partials — byte-identical to passing round 7
// EXCEPT __launch_bounds__(256, 1): relax the register allocator so the
// ~140 live values (2x acc28 + 2x q16 + 2x qp12 + state) get architected
// VGPRs instead of AGPR round-trips (VGPR_Count was 92 < live set; each
// acc FMA was costing accvgpr_read+fma+accvgpr_write = 3 VALU insts).
// grid (JC, 4, 8), 256 threads, 2 i-rows/thread.
// ---------------------------------------------------------------------------
template<int MODE, int JC>
__global__ __launch_bounds__(256, 1) void attn_kernel(
    const float* __restrict__ qbuf,  const float* __restrict__ qpbuf,
    const float* __restrict__ kbuf,  const float* __restrict__ kpbuf,
    const float* __restrict__ vbuf,  const float* __restrict__ vpbuf,
    const float* __restrict__ cfbuf, const float* __restrict__ ksqbuf,
    float* __restrict__ parbuf, const float* flagp,
    const void* w_c, const void* w_l)
{
  if (*flagp != (float)MODE) return;
  const int tid = threadIdx.x;
  const int jc = blockIdx.x;   // 0..JC-1  (2048/JC j each)
  const int it = blockIdx.y;   // 0..3     (512 i each)
  const int bh = blockIdx.z;   // 0..7
  const int b = bh >> 2, h = bh & 3;
  const int i0 = it * 512 + tid;
  const int r0 = b * NN + i0;
  const int r1 = r0 + 256;

  const float wl = softplus_f(LD<MODE>(w_l, h)) * 0.25f;   // fold DH^-0.5
  const float wc = softplus_f(LD<MODE>(w_c, h));

  float qA[16], qB[16], pA[12], pB[12];
  #pragma unroll
  for (int u = 0; u < 4; ++u) {
    float4 va = ((const float4*)(qbuf + (size_t)r0 * 64 + h * 16))[u];
    float4 vb = ((const float4*)(qbuf + (size_t)r1 * 64 + h * 16))[u];
    qA[4*u] = wl*va.x; qA[4*u+1] = wl*va.y; qA[4*u+2] = wl*va.z; qA[4*u+3] = wl*va.w;
    qB[4*u] = wl*vb.x; qB[4*u+1] = wl*vb.y; qB[4*u+2] = wl*vb.z; qB[4*u+3] = wl*vb.w;
  }
  #pragma unroll
  for (int u = 0; u < 3; ++u) {
    float4 va = ((const float4*)(qpbuf + (size_t)r0 * 48 + h * 12))[u];
    float4 vb = ((const float4*)(qpbuf + (size_t)r1 * 48 + h * 12))[u];
    pA[4*u] = wc*va.x; pA[4*u+1] = wc*va.y; pA[4*u+2] = wc*va.z; pA[4*u+3] = wc*va.w;
    pB[4*u] = wc*vb.x; pB[4*u+1] = wc*vb.y; pB[4*u+2] = wc*vb.z; pB[4*u+3] = wc*vb.w;
  }
  const float ciA0 = cfbuf[(size_t)r0 * 3 + 0];
  const float ciA1 = cfbuf[(size_t)r0 * 3 + 1];
  const float ciA2 = cfbuf[(size_t)r0 * 3 + 2];
  const float ciB0 = cfbuf[(size_t)r1 * 3 + 0];
  const float ciB1 = cfbuf[(size_t)r1 * 3 + 1];
  const float ciB2 = cfbuf[(size_t)r1 * 3 + 2];

  float mA = -1e9f, lA = 0.f, mB = -1e9f, lB = 0.f;
  float accA[28], accB[28];
  #pragma unroll
  for (int d = 0; d < 28; ++d) { accA[d] = 0.f; accB[d] = 0.f; }

  __shared__ __align__(16) float skA[64 * 36];  // k16 | kp12 | cj3 | -0.5*wc*ksq
  __shared__ __align__(16) float svB[64 * 36];  // v16 | vp12 | pad

  const int j0base = jc * (2048 / JC);
  for (int jt = 0; jt < 2048 / JC / 64; ++jt) {
    const int j0 = b * NN + j0base + jt * 64;
    __syncthreads();
    for (int idx = tid; idx < 1024; idx += 256) {
      const int jj = idx >> 4, d = idx & 15;
      skA[jj * 36 + d] = kbuf[(size_t)(j0 + jj) * 64 + h * 16 + d];
      svB[jj * 36 + d] = vbuf[(size_t)(j0 + jj) * 64 + h * 16 + d];
    }
    for (int idx = tid; idx < 768; idx += 256) {
      const int jj = idx / 12, e = idx - jj * 12;
      skA[jj * 36 + 16 + e] = kpbuf[(size_t)(j0 + jj) * 48 + h * 12 + e];
      svB[jj * 36 + 16 + e] = vpbuf[(size_t)(j0 + jj) * 48 + h * 12 + e];
    }
    {
      const int jj = tid >> 2, x = tid & 3;
      skA[jj * 36 + 28 + x] = (x < 3)
          ? cfbuf[(size_t)(j0 + jj) * 3 + x]
          : -0.5f * wc * ksqbuf[(size_t)(j0 + jj) * 4 + h];
    }
    __syncthreads();

    for (int jj = 0; jj < 64; ++jj) {
      const float4* ra = (const float4*)(skA + jj * 36);
      const float4 k0 = ra[0], k1 = ra[1], k2 = ra[2], k3 = ra[3];
      const float4 p0 = ra[4], p1 = ra[5], p2 = ra[6];
      const float4 cc = ra[7];   // cj.x, cj.y, cj.z, -0.5*wc*ksq

      float dA = (dot4(qA, k0, 0.f) + dot4(qA + 4, k1, 0.f)) +
                 (dot4(qA + 8, k2, 0.f) + dot4(qA + 12, k3, 0.f));
      float dB = (dot4(qB, k0, 0.f) + dot4(qB + 4, k1, 0.f)) +
                 (dot4(qB + 8, k2, 0.f) + dot4(qB + 12, k3, 0.f));
      float cA = (dot4(pA, p0, cc.w) + dot4(pA + 4, p1, 0.f)) + dot4(pA + 8, p2, 0.f);
      float cB = (dot4(pB, p0, cc.w) + dot4(pB + 4, p1, 0.f)) + dot4(pB + 8, p2, 0.f);

      float sA = dA + cA;
      float sB = dB + cB;

      float dx = ciA0 - cc.x, dy = ciA1 - cc.y, dz = ciA2 - cc.z;
      float d2 = fmaf(dx, dx, fmaf(dy, dy, dz * dz));
      sA = (d2 > 100.f) ? -1e9f : sA;
      dx = ciB0 - cc.x; dy = ciB1 - cc.y; dz = ciB2 - cc.z;
      d2 = fmaf(dx, dx, fmaf(dy, dy, dz * dz));
      sB = (d2 > 100.f) ? -1e9f : sB;

      // defer-max: rescale only when the running max grows by > 8.
      if (sA > mA + 8.f) {
        const float alpha = __expf(mA - sA);
        mA = sA; lA *= alpha;
        #pragma unroll
        for (int d = 0; d < 28; ++d) accA[d] *= alpha;
      }
      if (sB > mB + 8.f) {
        const float alpha = __expf(mB - sB);
        mB = sB; lB *= alpha;
        #pragma unroll
        for (int d = 0; d < 28; ++d) accB[d] *= alpha;
      }
      const float pa = __expf(sA - mA);
      const float pb = __expf(sB - mB);
      lA += pa; lB += pb;

      const float4* rb = (const float4*)(svB + jj * 36);
      const float4 v0 = rb[0], v1 = rb[1], v2 = rb[2], v3 = rb[3];
      const float4 v4 = rb[4], v5 = rb[5], v6 = rb[6];
      fma4(accA + 0, v0, pa);  fma4(accB + 0, v0, pb);
      fma4(accA + 4, v1, pa);  fma4(accB + 4, v1, pb);
      fma4(accA + 8, v2, pa);  fma4(accB + 8, v2, pb);
      fma4(accA + 12, v3, pa); fma4(accB + 12, v3, pb);
      fma4(accA + 16, v4, pa); fma4(accB + 16, v4, pb);
      fma4(accA + 20, v5, pa); fma4(accB + 20, v5, pb);
      fma4(accA + 24, v6, pa); fma4(accB + 24, v6, pb);
    }
  }

  {
    float* rec = parbuf + ((size_t)(bh * JC + jc) * NN + i0) * 16;
    rec[0] = mA; rec[1] = lA;
    unsigned* ru = (unsigned*)(rec + 2);
    #pragma unroll
    for (int d = 0; d < 14; ++d) ru[d] = pk2(accA[2 * d], accA[2 * d + 1]);
  }
  {
    float* rec = parbuf + ((size_t)(bh * JC + jc) * NN + i0 + 256) * 16;
    rec[0] = mB; rec[1] = lB;
    unsigned* ru = (unsigned*)(rec + 2);
    #pragma unroll
    for (int d = 0; d < 14; ++d) ru[d] = pk2(accB[2 * d], accB[2 * d + 1]);
  }
}

// ---------------------------------------------------------------------------
// Kernel C: merge JC softmax partials -> concat[4096][112]  (verbatim)
// ---------------------------------------------------------------------------
template<int JC>
__global__ __launch_bounds__(128) void combine_kernel(float* ws)
{
  const int g = blockIdx.x * 128 + threadIdx.x;  // (bh, i)
  const int bh = g >> 11;
  const int i = g & 2047;
  const int b = bh >> 2, h = bh & 3;
  const float* base = ws + PAR_OFF + ((size_t)bh * JC * NN + i) * 16;

  float M = -1e9f;
  #pragma unroll
  for (int c = 0; c < JC; ++c) M = fmaxf(M, base[(size_t)c * NN * 16]);
  float L = 0.f, o[28];
  #pragma unroll
  for (int d = 0; d < 28; ++d) o[d] = 0.f;
  for (int c = 0; c < JC; ++c) {
    const float* r = base + (size_t)c * NN * 16;
    const float w = __expf(r[0] - M);
    L = fmaf(r[1], w, L);
    const unsigned* ru = (const unsigned*)(r + 2);
    #pragma unroll
    for (int d = 0; d < 14; ++d) {
      const float2 f = upk2(ru[d]);
      o[2 * d]     = fmaf(f.x, w, o[2 * d]);
      o[2 * d + 1] = fmaf(f.y, w, o[2 * d + 1]);
    }
  }
  const float inv = 1.f / L;
  float* cat = ws + CAT_OFF + (size_t)(b * NN + i) * 112;
  #pragma unroll
  for (int d = 0; d < 16; ++d) cat[h * 16 + d] = o[d] * inv;
  #pragma unroll
  for (int e = 0; e < 12; ++e) cat[64 + h * 12 + e] = o[16 + e] * inv;
}

// ---------------------------------------------------------------------------
// Kernel D: out = concat[4096][112] @ Wo[112][64] + bo  (verbatim)
// ---------------------------------------------------------------------------
template<int MODE>
__global__ __launch_bounds__(256) void out_kernel(
    float* ws, const void* Wo, const void* bo, void* outp)
{
  if (ws[FLAG_OFF] != (float)MODE) return;
  const int t = threadIdx.x;
  const int blk = blockIdx.x;
  const int lr = t >> 6, c = t & 63;
  const int row = blk * 4 + lr;
  __shared__ float si[4 * 112];
  for (int idx = t; idx < 448; idx += 256)
    si[idx] = ws[CAT_OFF + (size_t)blk * 448 + idx];
  __syncthreads();
  float acc = LD<MODE>(bo, c);
  #pragma unroll 16
  for (int kk = 0; kk < 112; ++kk)
    acc = fmaf(si[lr * 112 + kk], LD<MODE>(Wo, (size_t)kk * 64 + c), acc);
  const size_t oi = (size_t)row * 64 + c;
  if (MODE) ((float*)outp)[oi] = acc;
  else      ((bf16*)outp)[oi] = __float2bfloat16(acc);
}

extern "C" void kernel_launch(void* const* d_in, const int* in_sizes, int n_in,
                              void* d_out, int out_size, void* d_ws, size_t ws_size,
                              hipStream_t stream)
{
  float* ws = (float*)d_ws;

  detect_kernel<<<1, 256, 0, stream>>>((const unsigned short*)d_in[0], ws);

  proj_kernel<0><<<BB * NN, 384, 0, stream>>>(d_in[0], d_in[1], d_in[2], d_in[3],
      d_in[4], d_in[5], d_in[6], d_in[7], d_in[8], d_in[9], d_in[10], d_in[11],
      d_in[12], d_in[13], ws);
  proj_kernel<1><<<BB * NN, 384, 0, stream>>>(d_in[0], d_in[1], d_in[2], d_in[3],
      d_in[4], d_in[5], d_in[6], d_in[7], d_in[8], d_in[9], d_in[10], d_in[11],
      d_in[12], d_in[13], ws);

  const float* qb  = ws + Q_OFF;   const float* qpb = ws + QP_OFF;
  const float* kb  = ws + K_OFF;   const float* kpb = ws + KP_OFF;
  const float* vb  = ws + V_OFF;   const float* vpb = ws + VP_OFF;
  const float* cfb = ws + CF_OFF;  const float* ksb = ws + KSQ_OFF;
  float* parb = ws + PAR_OFF;      const float* flagp = ws + FLAG_OFF;

  // JC=16 needs 24.3 MB of ws; fall back to proven 15.9 MB JC=8 otherwise.
  const bool big = ws_size >= (size_t)(PAR_OFF + 8u * 16u * NN * 16u) * 4u;
  if (big) {
    attn_kernel<0, 16><<<dim3(16, 4, 8), 256, 0, stream>>>(
        qb, qpb, kb, kpb, vb, vpb, cfb, ksb, parb, flagp, d_in[16], d_in[17]);
    attn_kernel<1, 16><<<dim3(16, 4, 8), 256, 0, stream>>>(
        qb, qpb, kb, kpb, vb, vpb, cfb, ksb, parb, flagp, d_in[16], d_in[17]);
    combine_kernel<16><<<128, 128, 0, stream>>>(ws);
  } else {
    attn_kernel<0, 8><<<dim3(8, 4, 8), 256, 0, stream>>>(
        qb, qpb, kb, kpb, vb, vpb, cfb, ksb, parb, flagp, d_in[16], d_in[17]);
    attn_kernel<1, 8><<<dim3(8, 4, 8), 256, 0, stream>>>(
        qb, qpb, kb, kpb, vb, vpb, cfb, ksb, parb, flagp, d_in[16], d_in[17]);
    combine_kernel<8><<<128, 128, 0, stream>>>(ws);
  }

  out_kernel<0><<<(BB * NN) / 4, 256, 0, stream>>>(ws, d_in[14], d_in[15], d_out);
  out_kernel<1><<<(BB * NN) / 4, 256, 0, stream>>>(ws, d_in[14], d_in[15], d_out);
}

// Round 9
// 108.341 us; speedup vs baseline: 2.1604x; 1.6845x over previous
//
#include <hip/hip_runtime.h>
#include <hip/hip_bf16.h>

typedef __hip_bfloat16 bf16;
typedef unsigned int uint32;
typedef unsigned short ushort16;
typedef __attribute__((ext_vector_type(8))) short bf16x8;
typedef __attribute__((ext_vector_type(4))) float f32x4;

#define BB 2
#define NN 2048
#define CENTER 15.0f

// workspace float offsets (end = 3,330,064 f32 = 13.3 MB; 15.9 MB proven fit)
#define DIAG_OFF 0u
#define FLAG_OFF 1u
#define QT_OFF   16u       // u32 view [8 bh][2048 i][48]  (96 bf16 slots)
#define KT_OFF   786448u   // u32 view [8 bh][2048 j][48]
#define VT_OFF   1572880u  // u16 view [8 bh][28 d][2048 j]
#define CQ_OFF   1802256u  // f32 [4096]         |c-15|^2
#define SB_OFF   1806352u  // f32 [8 bh][2048]   -0.5*wc*|kp_c|^2
#define CAT_OFF  1822736u  // f32 [4096][112]
#define PAR_OFF  2281488u  // f32 [8 bh][4 jc][2048][16]

__device__ __forceinline__ float b2f(bf16 x) { return __bfloat162float(x); }

template<int MODE>
__device__ __forceinline__ float LD(const void* p, size_t i) {
  if (MODE) return ((const float*)p)[i];
  return __bfloat162float(((const bf16*)p)[i]);
}

__device__ __forceinline__ float softplus_f(float x) {
  return (x > 20.f) ? x : log1pf(__expf(x));
}

__device__ __forceinline__ unsigned pk2(float a, float b) {
  union { __hip_bfloat162 v; unsigned u; } cv;
  cv.v.x = __float2bfloat16(a); cv.v.y = __float2bfloat16(b);
  return cv.u;
}
__device__ __forceinline__ float2 upk2(unsigned u) {
  union { unsigned u; __hip_bfloat162 v; } cv; cv.u = u;
  return make_float2(__bfloat162float(cv.v.x), __bfloat162float(cv.v.y));
}
__device__ __forceinline__ unsigned short f2bu(float x) {
  union { bf16 b; unsigned short u; } c; c.b = __float2bfloat16(x); return c.u;
}
__device__ __forceinline__ float lo_part(float x) {
  return x - __bfloat162float(__float2bfloat16(x));
}

// ---------------------------------------------------------------------------
// dtype detect (proven): fp32 low-halves trip exp>=0xC0 ~25%; bf16 never.
// ---------------------------------------------------------------------------
__global__ __launch_bounds__(256) void detect_kernel(const unsigned short* u,
                                                     float* ws) {
  __shared__ int cnt;
  if (threadIdx.x == 0) cnt = 0;
  __syncthreads();
  int local = 0;
  for (int i = threadIdx.x; i < 4096; i += 256) {
    unsigned e = (u[i] >> 7) & 0xFFu;
    local += (e >= 0xC0u) ? 1 : 0;
  }
  atomicAdd(&cnt, local);
  __syncthreads();
  if (threadIdx.x == 0) {
    ws[FLAG_OFF] = (cnt > 64) ? 1.f : 0.f;
    ((int*)ws)[0] = 0;
  }
}

// MFMA table slot builders. Q-side pairs with K-side over K=32 slots so that
// mfma#1 = wl*q.k + xh.kph ; mfma#2 = xh.kpl + xl.kph ; mfma#3 = ci.cj hi/lo.
__device__ float qslot(int h, int s, const float* spro, const float* cc,
                       float wl, float wc) {
  if (s < 16) return wl * spro[h * 16 + s];
  if (s < 28) return wc * spro[192 + h * 12 + (s - 16)];   // -> xh
  if (s < 32) return 0.f;
  if (s < 44) return wc * spro[192 + h * 12 + (s - 32)];   // -> xh
  if (s < 56) return lo_part(wc * spro[192 + h * 12 + (s - 44)]);  // xl
  if (s < 64) return 0.f;
  if (s < 67) return cc[s - 64];            // cih
  if (s < 70) return cc[s - 67];            // cih
  if (s < 73) return lo_part(cc[s - 70]);   // cil
  return 0.f;
}
__device__ float kslot(int h, int s, const float* spro, const float* cc) {
  if (s < 16) return spro[64 + h * 16 + s];
  if (s < 28) return spro[240 + h * 12 + (s - 16)];        // kph
  if (s < 32) return 0.f;
  if (s < 44) return lo_part(spro[240 + h * 12 + (s - 32)]); // kpl
  if (s < 56) return spro[240 + h * 12 + (s - 44)];        // kph
  if (s < 64) return 0.f;
  if (s < 67) return cc[s - 64];            // cjh
  if (s < 70) return lo_part(cc[s - 67]);   // cjl
  if (s < 73) return cc[s - 70];            // cjh
  return 0.f;
}

// ---------------------------------------------------------------------------
// Kernel A: projections + MFMA table packing. 4096 blocks x 512 threads.
// spro: q[0..63] k[64..127] v[128..191] qp_c[192..239] kp_c[240..287]
//       vp[288..335]   (qp/kp centered by CENTER; vp raw)
// ---------------------------------------------------------------------------
template<int MODE>
__global__ __launch_bounds__(512) void proj_kernel(
    const void* feat, const void* coords,
    const void* Wq,  const void* bq,  const void* Wk,  const void* bk,
    const void* Wv,  const void* bv,  const void* Wqp, const void* bqp,
    const void* Wkp, const void* bkp, const void* Wvp, const void* bvp,
    const void* w_c, const void* w_l, float* ws)
{
  if (ws[FLAG_OFF] != (float)MODE) return;
  const int row = blockIdx.x;       // b*NN + i
  const int b = row >> 11, i = row & 2047;
  const int t = threadIdx.x;
  __shared__ float sf[64];
  __shared__ float spro[336];
  if (t < 64) sf[t] = LD<MODE>(feat, (size_t)row * 64 + t);
  __syncthreads();

  if (t < 336) {
    const void *W, *bias; int odim, c, cls, ofs;
    if (t < 64)       { W = Wq;  bias = bq;  odim = 64; c = t;       cls = 0; ofs = 0; }
    else if (t < 128) { W = Wk;  bias = bk;  odim = 64; c = t - 64;  cls = 1; ofs = 64; }
    else if (t < 192) { W = Wv;  bias = bv;  odim = 64; c = t - 128; cls = 2; ofs = 128; }
    else if (t < 240) { W = Wqp; bias = bqp; odim = 48; c = t - 192; cls = 3; ofs = 192; }
    else if (t < 288) { W = Wkp; bias = bkp; odim = 48; c = t - 240; cls = 4; ofs = 240; }
    else              { W = Wvp; bias = bvp; odim = 48; c = t - 288; cls = 5; ofs = 288; }
    float acc = LD<MODE>(bias, c);
    #pragma unroll 16
    for (int f = 0; f < 64; ++f)
      acc = fmaf(sf[f], LD<MODE>(W, (size_t)f * odim + c), acc);
    if (cls >= 3) {
      acc += LD<MODE>(coords, (size_t)row * 3 + (c % 3));
      if (cls == 3 || cls == 4) acc -= CENTER;   // center qp,kp (shift-inv)
    }
    spro[ofs + c] = acc;
  }
  __syncthreads();

  float cc[3];
  cc[0] = LD<MODE>(coords, (size_t)row * 3 + 0) - CENTER;
  cc[1] = LD<MODE>(coords, (size_t)row * 3 + 1) - CENTER;
  cc[2] = LD<MODE>(coords, (size_t)row * 3 + 2) - CENTER;

  if (t < 384) {
    const bool isq = (t < 192);
    const int per = isq ? t : t - 192;
    const int h = per / 48, w = per - h * 48;
    float wl = softplus_f(LD<MODE>(w_l, h)) * 0.25f;
    float wc = softplus_f(LD<MODE>(w_c, h));
    float a0, a1;
    if (isq) { a0 = qslot(h, 2 * w, spro, cc, wl, wc);
               a1 = qslot(h, 2 * w + 1, spro, cc, wl, wc); }
    else     { a0 = kslot(h, 2 * w, spro, cc);
               a1 = kslot(h, 2 * w + 1, spro, cc); }
    uint32* tab = (uint32*)(ws + (isq ? QT_OFF : KT_OFF));
    tab[((size_t)(b * 4 + h) * NN + i) * 48 + w] = pk2(a0, a1);
  } else if (t < 496) {
    const int tt = t - 384;
    const int h = tt / 28, d = tt - h * 28;
    const float val = (d < 16) ? spro[128 + h * 16 + d]
                               : spro[288 + h * 12 + (d - 16)];
    unsigned short* VTu = (unsigned short*)(ws + VT_OFF);
    VTu[((size_t)((b * 4 + h) * 28 + d)) * NN + i] = f2bu(val);
  } else if (t < 500) {
    const int h = t - 496;
    float wc = softplus_f(LD<MODE>(w_c, h));
    float s = 0.f;
    #pragma unroll
    for (int e = 0; e < 12; ++e) {
      const float y = spro[240 + h * 12 + e];
      s = fmaf(y, y, s);
    }
    ws[SB_OFF + (size_t)(b * 4 + h) * NN + i] = -0.5f * wc * s;
  } else if (t == 500) {
    ws[CQ_OFF + row] = fmaf(cc[0], cc[0], fmaf(cc[1], cc[1], cc[2] * cc[2]));
  }
}

// ---------------------------------------------------------------------------
// Kernel B: MFMA flash attention partials. grid (jc=4, it=32, bh=8), 256 thr.
// Wave = 16 i-rows; j-tiles of 32; S^T & d2 via 3 mfma_16x16x32_bf16 (hi/lo
// packed), PV via 2 mfma; online softmax with 4-lane shfl m-sync; per-wave
// P^T LDS round-trip (no barrier: same-wave produce/consume).
// ---------------------------------------------------------------------------
__global__ __launch_bounds__(256) void attn_kernel(
    const uint32* __restrict__ QTg, const uint32* __restrict__ KTg,
    const uint32* __restrict__ VTg, const float* __restrict__ CQ,
    const float* __restrict__ SBt, float* __restrict__ parb)
{
  const int tid = threadIdx.x;
  const int w = tid >> 6, lane = tid & 63;
  const int li = lane & 15, g = lane >> 4;
  const int jc = blockIdx.x;        // 0..3   (512 j)
  const int it = blockIdx.y;        // 0..31  (64 i)
  const int bh = blockIdx.z;        // 0..7
  const int b = bh >> 2;
  const int iloc = it * 64 + w * 16 + li;

  // Q-side B-frags (per-wave constant)
  const uint32* qrow = QTg + ((size_t)bh * NN + iloc) * 48;
  const bf16x8 B1 = *(const bf16x8*)(qrow + 4 * g);
  const bf16x8 B2 = *(const bf16x8*)(qrow + 16 + 4 * g);
  const bf16x8 B3 = *(const bf16x8*)(qrow + 32 + 4 * g);
  const float ciq = CQ[(size_t)b * NN + iloc];

  float m = -1e9f, l = 0.f;
  f32x4 acc0 = {0.f, 0.f, 0.f, 0.f};
  f32x4 acc1 = {0.f, 0.f, 0.f, 0.f};

  __shared__ uint32 sKT[32 * 52];   // [32 j][104 bf16] padded rows
  __shared__ uint32 sVT[32 * 20];   // [32 d][40 bf16]
  __shared__ float  sCS[64];        // [32 j][cjq, sbias]
  __shared__ uint32 sPT[4][16 * 20];// per-wave P^T [16 i][40 bf16]

  if (tid < 80) sVT[560 + tid] = 0;   // zero d=28..31 rows

  #pragma unroll 1
  for (int jt = 0; jt < 16; ++jt) {
    const int j0 = jc * 512 + jt * 32;
    __syncthreads();
    for (int idx = tid; idx < 1536; idx += 256) {
      const int j = idx / 48, ww = idx - j * 48;
      sKT[j * 52 + ww] = KTg[((size_t)bh * NN + j0 + j) * 48 + ww];
    }
    for (int idx = tid; idx < 448; idx += 256) {
      const int d = idx >> 4, ww = idx & 15;
      sVT[d * 20 + ww] = VTg[(size_t)(bh * 28 + d) * 1024 + (j0 >> 1) + ww];
    }
    if (tid < 64) {
      const int jj = tid >> 1;
      sCS[tid] = (tid & 1) ? SBt[(size_t)bh * NN + j0 + jj]
                           : CQ[(size_t)b * NN + j0 + jj];
    }
    __syncthreads();

    float s[8];
    const f32x4 z = {0.f, 0.f, 0.f, 0.f};
    #pragma unroll
    for (int h2 = 0; h2 < 2; ++h2) {
      const uint32* arow = sKT + (h2 * 16 + li) * 52;
      const bf16x8 A1 = *(const bf16x8*)(arow + 4 * g);
      const bf16x8 A2 = *(const bf16x8*)(arow + 16 + 4 * g);
      const bf16x8 A3 = *(const bf16x8*)(arow + 32 + 4 * g);
      f32x4 Cs = __builtin_amdgcn_mfma_f32_16x16x32_bf16(A1, B1, z, 0, 0, 0);
      Cs = __builtin_amdgcn_mfma_f32_16x16x32_bf16(A2, B2, Cs, 0, 0, 0);
      const f32x4 Cd = __builtin_amdgcn_mfma_f32_16x16x32_bf16(A3, B3, z, 0, 0, 0);
      #pragma unroll
      for (int r = 0; r < 4; ++r) {
        const int jj = h2 * 16 + g * 4 + r;
        const float cjq = sCS[jj * 2], sb = sCS[jj * 2 + 1];
        const float d2 = fmaf(-2.f, Cd[r], ciq + cjq);
        const float sv = Cs[r] + sb;
        s[h2 * 4 + r] = (d2 > 100.f) ? -1e30f : sv;
      }
    }

    // online softmax, branchless, 4-lane group sync (lanes share i)
    float smax = fmaxf(fmaxf(fmaxf(s[0], s[1]), fmaxf(s[2], s[3])),
                       fmaxf(fmaxf(s[4], s[5]), fmaxf(s[6], s[7])));
    smax = fmaxf(smax, __shfl_xor(smax, 16));
    smax = fmaxf(smax, __shfl_xor(smax, 32));
    const float mnew = fmaxf(m, smax);
    const float alpha = __expf(m - mnew);
    m = mnew;
    l *= alpha; acc0 *= alpha; acc1 *= alpha;
    float p[8];
    #pragma unroll
    for (int k = 0; k < 8; ++k) p[k] = __expf(s[k] - m);
    l += ((p[0] + p[1]) + (p[2] + p[3])) + ((p[4] + p[5]) + (p[6] + p[7]));

    // P^T write (per-wave buffer; same-wave read below — lgkmcnt ordered)
    uint32* prow = sPT[w] + li * 20;
    prow[2 * g]     = pk2(p[0], p[1]);
    prow[2 * g + 1] = pk2(p[2], p[3]);
    prow[8 + 2 * g]     = pk2(p[4], p[5]);
    prow[8 + 2 * g + 1] = pk2(p[6], p[7]);

    const bf16x8 Bp  = *(const bf16x8*)(sPT[w] + li * 20 + 4 * g);
    const bf16x8 Av0 = *(const bf16x8*)(sVT + li * 20 + 4 * g);
    const bf16x8 Av1 = *(const bf16x8*)(sVT + (16 + li) * 20 + 4 * g);
    acc0 = __builtin_amdgcn_mfma_f32_16x16x32_bf16(Av0, Bp, acc0, 0, 0, 0);
    acc1 = __builtin_amdgcn_mfma_f32_16x16x32_bf16(Av1, Bp, acc1, 0, 0, 0);
  }

  l += __shfl_xor(l, 16);
  l += __shfl_xor(l, 32);

  float* rec = parb + ((size_t)(bh * 4 + jc) * NN + iloc) * 16;
  rec[0] = m; rec[1] = l;                    // 4 lanes write same values
  uint32* ru = (uint32*)(rec + 2);
  ru[2 * g]     = pk2(acc0[0], acc0[1]);     // slot s holds acc[2s],acc[2s+1]
  ru[2 * g + 1] = pk2(acc0[2], acc0[3]);
  if (g < 3) {
    ru[8 + 2 * g]     = pk2(acc1[0], acc1[1]);
    ru[8 + 2 * g + 1] = pk2(acc1[2], acc1[3]);
  }
}

// ---------------------------------------------------------------------------
// Kernel C: merge JC softmax partials -> concat[4096][112]
// ---------------------------------------------------------------------------
template<int JC>
__global__ __launch_bounds__(128) void combine_kernel(float* ws)
{
  const int gg = blockIdx.x * 128 + threadIdx.x;  // (bh, i)
  const int bh = gg >> 11;
  const int i = gg & 2047;
  const int b = bh >> 2, h = bh & 3;
  const float* base = ws + PAR_OFF + ((size_t)bh * JC * NN + i) * 16;

  float M = -1e9f;
  #pragma unroll
  for (int c = 0; c < JC; ++c) M = fmaxf(M, base[(size_t)c * NN * 16]);
  float L = 0.f, o[28];
  #pragma unroll
  for (int d = 0; d < 28; ++d) o[d] = 0.f;
  for (int c = 0; c < JC; ++c) {
    const float* r = base + (size_t)c * NN * 16;
    const float wgt = __expf(r[0] - M);
    L = fmaf(r[1], wgt, L);
    const unsigned* ru = (const unsigned*)(r + 2);
    #pragma unroll
    for (int d = 0; d < 14; ++d) {
      const float2 f = upk2(ru[d]);
      o[2 * d]     = fmaf(f.x, wgt, o[2 * d]);
      o[2 * d + 1] = fmaf(f.y, wgt, o[2 * d + 1]);
    }
  }
  const float inv = 1.f / L;
  float* cat = ws + CAT_OFF + (size_t)(b * NN + i) * 112;
  #pragma unroll
  for (int d = 0; d < 16; ++d) cat[h * 16 + d] = o[d] * inv;
  #pragma unroll
  for (int e = 0; e < 12; ++e) cat[64 + h * 12 + e] = o[16 + e] * inv;
}

// ---------------------------------------------------------------------------
// Kernel D: out = concat[4096][112] @ Wo[112][64] + bo
// ---------------------------------------------------------------------------
template<int MODE>
__global__ __launch_bounds__(256) void out_kernel(
    float* ws, const void* Wo, const void* bo, void* outp)
{
  if (ws[FLAG_OFF] != (float)MODE) return;
  const int t = threadIdx.x;
  const int blk = blockIdx.x;
  const int lr = t >> 6, c = t & 63;
  const int row = blk * 4 + lr;
  __shared__ float si[4 * 112];
  for (int idx = t; idx < 448; idx += 256)
    si[idx] = ws[CAT_OFF + (size_t)blk * 448 + idx];
  __syncthreads();
  float acc = LD<MODE>(bo, c);
  #pragma unroll 16
  for (int kk = 0; kk < 112; ++kk)
    acc = fmaf(si[lr * 112 + kk], LD<MODE>(Wo, (size_t)kk * 64 + c), acc);
  const size_t oi = (size_t)row * 64 + c;
  if (MODE) ((float*)outp)[oi] = acc;
  else      ((bf16*)outp)[oi] = __float2bfloat16(acc);
}

extern "C" void kernel_launch(void* const* d_in, const int* in_sizes, int n_in,
                              void* d_out, int out_size, void* d_ws, size_t ws_size,
                              hipStream_t stream)
{
  float* ws = (float*)d_ws;

  detect_kernel<<<1, 256, 0, stream>>>((const unsigned short*)d_in[0], ws);

  proj_kernel<0><<<BB * NN, 512, 0, stream>>>(d_in[0], d_in[1], d_in[2], d_in[3],
      d_in[4], d_in[5], d_in[6], d_in[7], d_in[8], d_in[9], d_in[10], d_in[11],
      d_in[12], d_in[13], d_in[16], d_in[17], ws);
  proj_kernel<1><<<BB * NN, 512, 0, stream>>>(d_in[0], d_in[1], d_in[2], d_in[3],
      d_in[4], d_in[5], d_in[6], d_in[7], d_in[8], d_in[9], d_in[10], d_in[11],
      d_in[12], d_in[13], d_in[16], d_in[17], ws);

  attn_kernel<<<dim3(4, 32, 8), 256, 0, stream>>>(
      (const uint32*)(ws + QT_OFF), (const uint32*)(ws + KT_OFF),
      (const uint32*)(ws + VT_OFF), ws + CQ_OFF, ws + SB_OFF, ws + PAR_OFF);

  combine_kernel<4><<<128, 128, 0, stream>>>(ws);

  out_kernel<0><<<(BB * NN) / 4, 256, 0, stream>>>(ws, d_in[14], d_in[15], d_out);
  out_kernel<1><<<(BB * NN) / 4, 256, 0, stream>>>(ws, d_in[14], d_in[15], d_out);
}

// Round 10
// 107.722 us; speedup vs baseline: 2.1729x; 1.0058x over previous
//
#include <hip/hip_runtime.h>
#include <hip/hip_bf16.h>

typedef __hip_bfloat16 bf16;
typedef unsigned int uint32;
typedef unsigned short ushort16;
typedef __attribute__((ext_vector_type(8))) short bf16x8;
typedef __attribute__((ext_vector_type(4))) float f32x4;

#define BB 2
#define NN 2048
#define CENTER 15.0f

// workspace float offsets (end = 3,330,064 f32 = 13.3 MB; 15.9 MB proven fit)
#define DIAG_OFF 0u
#define FLAG_OFF 1u
#define QT_OFF   16u       // u32 view [8 bh][2048 i][48]  (96 bf16 slots)
#define KT_OFF   786448u   // u32 view [8 bh][2048 j][48]
#define VT_OFF   1572880u  // u16 view [8 bh][28 d][2048 j]
#define CQ_OFF   1802256u  // f32 [4096]         |c-15|^2
#define SB_OFF   1806352u  // f32 [8 bh][2048]   -0.5*wc*|kp_c|^2
#define CAT_OFF  1822736u  // f32 [4096][112]
#define PAR_OFF  2281488u  // f32 [8 bh][4 jc][2048][16]

__device__ __forceinline__ float b2f(bf16 x) { return __bfloat162float(x); }

template<int MODE>
__device__ __forceinline__ float LD(const void* p, size_t i) {
  if (MODE) return ((const float*)p)[i];
  return __bfloat162float(((const bf16*)p)[i]);
}

__device__ __forceinline__ float softplus_f(float x) {
  return (x > 20.f) ? x : log1pf(__expf(x));
}

__device__ __forceinline__ unsigned pk2(float a, float b) {
  union { __hip_bfloat162 v; unsigned u; } cv;
  cv.v.x = __float2bfloat16(a); cv.v.y = __float2bfloat16(b);
  return cv.u;
}
__device__ __forceinline__ float2 upk2(unsigned u) {
  union { unsigned u; __hip_bfloat162 v; } cv; cv.u = u;
  return make_float2(__bfloat162float(cv.v.x), __bfloat162float(cv.v.y));
}
__device__ __forceinline__ unsigned short f2bu(float x) {
  union { bf16 b; unsigned short u; } c; c.b = __float2bfloat16(x); return c.u;
}
__device__ __forceinline__ float lo_part(float x) {
  return x - __bfloat162float(__float2bfloat16(x));
}

// ---------------------------------------------------------------------------
// dtype detect (proven): fp32 low-halves trip exp>=0xC0 ~25%; bf16 never.
// ---------------------------------------------------------------------------
__global__ __launch_bounds__(256) void detect_kernel(const unsigned short* u,
                                                     float* ws) {
  __shared__ int cnt;
  if (threadIdx.x == 0) cnt = 0;
  __syncthreads();
  int local = 0;
  for (int i = threadIdx.x; i < 4096; i += 256) {
    unsigned e = (u[i] >> 7) & 0xFFu;
    local += (e >= 0xC0u) ? 1 : 0;
  }
  atomicAdd(&cnt, local);
  __syncthreads();
  if (threadIdx.x == 0) {
    ws[FLAG_OFF] = (cnt > 64) ? 1.f : 0.f;
    ((int*)ws)[0] = 0;
  }
}

// MFMA table slot builders. Q-side pairs with K-side over K=32 slots so that
// mfma#1 = wl*q.k + xh.kph ; mfma#2 = xh.kpl + xl.kph ; mfma#3 = ci.cj hi/lo.
__device__ float qslot(int h, int s, const float* spro, const float* cc,
                       float wl, float wc) {
  if (s < 16) return wl * spro[h * 16 + s];
  if (s < 28) return wc * spro[192 + h * 12 + (s - 16)];   // -> xh
  if (s < 32) return 0.f;
  if (s < 44) return wc * spro[192 + h * 12 + (s - 32)];   // -> xh
  if (s < 56) return lo_part(wc * spro[192 + h * 12 + (s - 44)]);  // xl
  if (s < 64) return 0.f;
  if (s < 67) return cc[s - 64];            // cih
  if (s < 70) return cc[s - 67];            // cih
  if (s < 73) return lo_part(cc[s - 70]);   // cil
  return 0.f;
}
__device__ float kslot(int h, int s, const float* spro, const float* cc) {
  if (s < 16) return spro[64 + h * 16 + s];
  if (s < 28) return spro[240 + h * 12 + (s - 16)];        // kph
  if (s < 32) return 0.f;
  if (s < 44) return lo_part(spro[240 + h * 12 + (s - 32)]); // kpl
  if (s < 56) return spro[240 + h * 12 + (s - 44)];        // kph
  if (s < 64) return 0.f;
  if (s < 67) return cc[s - 64];            // cjh
  if (s < 70) return lo_part(cc[s - 67]);   // cjl
  if (s < 73) return cc[s - 70];            // cjh
  return 0.f;
}

// ---------------------------------------------------------------------------
// Kernel A: projections + MFMA table packing. 4096 blocks x 512 threads.
// spro: q[0..63] k[64..127] v[128..191] qp_c[192..239] kp_c[240..287]
//       vp[288..335]   (qp/kp centered by CENTER; vp raw)
// ---------------------------------------------------------------------------
template<int MODE>
__global__ __launch_bounds__(512) void proj_kernel(
    const void* feat, const void* coords,
    const void* Wq,  const void* bq,  const void* Wk,  const void* bk,
    const void* Wv,  const void* bv,  const void* Wqp, const void* bqp,
    const void* Wkp, const void* bkp, const void* Wvp, const void* bvp,
    const void* w_c, const void* w_l, float* ws)
{
  if (ws[FLAG_OFF] != (float)MODE) return;
  const int row = blockIdx.x;       // b*NN + i
  const int b = row >> 11, i = row & 2047;
  const int t = threadIdx.x;
  __shared__ float sf[64];
  __shared__ float spro[336];
  if (t < 64) sf[t] = LD<MODE>(feat, (size_t)row * 64 + t);
  __syncthreads();

  if (t < 336) {
    const void *W, *bias; int odim, c, cls, ofs;
    if (t < 64)       { W = Wq;  bias = bq;  odim = 64; c = t;       cls = 0; ofs = 0; }
    else if (t < 128) { W = Wk;  bias = bk;  odim = 64; c = t - 64;  cls = 1; ofs = 64; }
    else if (t < 192) { W = Wv;  bias = bv;  odim = 64; c = t - 128; cls = 2; ofs = 128; }
    else if (t < 240) { W = Wqp; bias = bqp; odim = 48; c = t - 192; cls = 3; ofs = 192; }
    else if (t < 288) { W = Wkp; bias = bkp; odim = 48; c = t - 240; cls = 4; ofs = 240; }
    else              { W = Wvp; bias = bvp; odim = 48; c = t - 288; cls = 5; ofs = 288; }
    float acc = LD<MODE>(bias, c);
    #pragma unroll 16
    for (int f = 0; f < 64; ++f)
      acc = fmaf(sf[f], LD<MODE>(W, (size_t)f * odim + c), acc);
    if (cls >= 3) {
      acc += LD<MODE>(coords, (size_t)row * 3 + (c % 3));
      if (cls == 3 || cls == 4) acc -= CENTER;   // center qp,kp (shift-inv)
    }
    spro[ofs + c] = acc;
  }
  __syncthreads();

  float cc[3];
  cc[0] = LD<MODE>(coords, (size_t)row * 3 + 0) - CENTER;
  cc[1] = LD<MODE>(coords, (size_t)row * 3 + 1) - CENTER;
  cc[2] = LD<MODE>(coords, (size_t)row * 3 + 2) - CENTER;

  if (t < 384) {
    const bool isq = (t < 192);
    const int per = isq ? t : t - 192;
    const int h = per / 48, w = per - h * 48;
    float wl = softplus_f(LD<MODE>(w_l, h)) * 0.25f;
    float wc = softplus_f(LD<MODE>(w_c, h));
    float a0, a1;
    if (isq) { a0 = qslot(h, 2 * w, spro, cc, wl, wc);
               a1 = qslot(h, 2 * w + 1, spro, cc, wl, wc); }
    else     { a0 = kslot(h, 2 * w, spro, cc);
               a1 = kslot(h, 2 * w + 1, spro, cc); }
    uint32* tab = (uint32*)(ws + (isq ? QT_OFF : KT_OFF));
    tab[((size_t)(b * 4 + h) * NN + i) * 48 + w] = pk2(a0, a1);
  } else if (t < 496) {
    const int tt = t - 384;
    const int h = tt / 28, d = tt - h * 28;
    const float val = (d < 16) ? spro[128 + h * 16 + d]
                               : spro[288 + h * 12 + (d - 16)];
    unsigned short* VTu = (unsigned short*)(ws + VT_OFF);
    VTu[((size_t)((b * 4 + h) * 28 + d)) * NN + i] = f2bu(val);
  } else if (t < 500) {
    const int h = t - 496;
    float wc = softplus_f(LD<MODE>(w_c, h));
    float s = 0.f;
    #pragma unroll
    for (int e = 0; e < 12; ++e) {
      const float y = spro[240 + h * 12 + e];
      s = fmaf(y, y, s);
    }
    ws[SB_OFF + (size_t)(b * 4 + h) * NN + i] = -0.5f * wc * s;
  } else if (t == 500) {
    ws[CQ_OFF + row] = fmaf(cc[0], cc[0], fmaf(cc[1], cc[1], cc[2] * cc[2]));
  }
}

// ---------------------------------------------------------------------------
// Kernel B: MFMA flash attention partials. grid (jc=4, it=32, bh=8), 256 thr.
// Wave = 16 i-rows; j-tiles of 32; S^T & d2 via 3 mfma_16x16x32_bf16 (hi/lo
// packed), PV via 2 mfma; online softmax with 4-lane shfl m-sync; per-wave
// P^T LDS round-trip (no barrier: same-wave produce/consume).
// ---------------------------------------------------------------------------
__global__ __launch_bounds__(256) void attn_kernel(
    const uint32* __restrict__ QTg, const uint32* __restrict__ KTg,
    const uint32* __restrict__ VTg, const float* __restrict__ CQ,
    const float* __restrict__ SBt, float* __restrict__ parb)
{
  const int tid = threadIdx.x;
  const int w = tid >> 6, lane = tid & 63;
  const int li = lane & 15, g = lane >> 4;
  const int jc = blockIdx.x;        // 0..3   (512 j)
  const int it = blockIdx.y;        // 0..31  (64 i)
  const int bh = blockIdx.z;        // 0..7
  const int b = bh >> 2;
  const int iloc = it * 64 + w * 16 + li;

  // Q-side B-frags (per-wave constant)
  const uint32* qrow = QTg + ((size_t)bh * NN + iloc) * 48;
  const bf16x8 B1 = *(const bf16x8*)(qrow + 4 * g);
  const bf16x8 B2 = *(const bf16x8*)(qrow + 16 + 4 * g);
  const bf16x8 B3 = *(const bf16x8*)(qrow + 32 + 4 * g);
  const float ciq = CQ[(size_t)b * NN + iloc];

  float m = -1e9f, l = 0.f;
  f32x4 acc0 = {0.f, 0.f, 0.f, 0.f};
  f32x4 acc1 = {0.f, 0.f, 0.f, 0.f};

  __shared__ uint32 sKT[32 * 52];   // [32 j][104 bf16] padded rows
  __shared__ uint32 sVT[32 * 20];   // [32 d][40 bf16]
  __shared__ float  sCS[64];        // [32 j][cjq, sbias]
  __shared__ uint32 sPT[4][16 * 20];// per-wave P^T [16 i][40 bf16]

  if (tid < 80) sVT[560 + tid] = 0;   // zero d=28..31 rows

  #pragma unroll 1
  for (int jt = 0; jt < 16; ++jt) {
    const int j0 = jc * 512 + jt * 32;
    __syncthreads();
    for (int idx = tid; idx < 1536; idx += 256) {
      const int j = idx / 48, ww = idx - j * 48;
      sKT[j * 52 + ww] = KTg[((size_t)bh * NN + j0 + j) * 48 + ww];
    }
    for (int idx = tid; idx < 448; idx += 256) {
      const int d = idx >> 4, ww = idx & 15;
      sVT[d * 20 + ww] = VTg[(size_t)(bh * 28 + d) * 1024 + (j0 >> 1) + ww];
    }
    if (tid < 64) {
      const int jj = tid >> 1;
      sCS[tid] = (tid & 1) ? SBt[(size_t)bh * NN + j0 + jj]
                           : CQ[(size_t)b * NN + j0 + jj];
    }
    __syncthreads();

    float s[8];
    const f32x4 z = {0.f, 0.f, 0.f, 0.f};
    #pragma unroll
    for (int h2 = 0; h2 < 2; ++h2) {
      const uint32* arow = sKT + (h2 * 16 + li) * 52;
      const bf16x8 A1 = *(const bf16x8*)(arow + 4 * g);
      const bf16x8 A2 = *(const bf16x8*)(arow + 16 + 4 * g);
      const bf16x8 A3 = *(const bf16x8*)(arow + 32 + 4 * g);
      f32x4 Cs = __builtin_amdgcn_mfma_f32_16x16x32_bf16(A1, B1, z, 0, 0, 0);
      Cs = __builtin_amdgcn_mfma_f32_16x16x32_bf16(A2, B2, Cs, 0, 0, 0);
      const f32x4 Cd = __builtin_amdgcn_mfma_f32_16x16x32_bf16(A3, B3, z, 0, 0, 0);
      #pragma unroll
      for (int r = 0; r < 4; ++r) {
        const int jj = h2 * 16 + g * 4 + r;
        const float cjq = sCS[jj * 2], sb = sCS[jj * 2 + 1];
        const float d2 = fmaf(-2.f, Cd[r], ciq + cjq);
        const float sv = Cs[r] + sb;
        s[h2 * 4 + r] = (d2 > 100.f) ? -1e30f : sv;
      }
    }

    // online softmax, branchless, 4-lane group sync (lanes share i)
    float smax = fmaxf(fmaxf(fmaxf(s[0], s[1]), fmaxf(s[2], s[3])),
                       fmaxf(fmaxf(s[4], s[5]), fmaxf(s[6], s[7])));
    smax = fmaxf(smax, __shfl_xor(smax, 16));
    smax = fmaxf(smax, __shfl_xor(smax, 32));
    const float mnew = fmaxf(m, smax);
    const float alpha = __expf(m - mnew);
    m = mnew;
    l *= alpha; acc0 *= alpha; acc1 *= alpha;
    float p[8];
    #pragma unroll
    for (int k = 0; k < 8; ++k) p[k] = __expf(s[k] - m);
    l += ((p[0] + p[1]) + (p[2] + p[3])) + ((p[4] + p[5]) + (p[6] + p[7]));

    // P^T write (per-wave buffer; same-wave read below — lgkmcnt ordered)
    uint32* prow = sPT[w] + li * 20;
    prow[2 * g]     = pk2(p[0], p[1]);
    prow[2 * g + 1] = pk2(p[2], p[3]);
    prow[8 + 2 * g]     = pk2(p[4], p[5]);
    prow[8 + 2 * g + 1] = pk2(p[6], p[7]);

    const bf16x8 Bp  = *(const bf16x8*)(sPT[w] + li * 20 + 4 * g);
    const bf16x8 Av0 = *(const bf16x8*)(sVT + li * 20 + 4 * g);
    const bf16x8 Av1 = *(const bf16x8*)(sVT + (16 + li) * 20 + 4 * g);
    acc0 = __builtin_amdgcn_mfma_f32_16x16x32_bf16(Av0, Bp, acc0, 0, 0, 0);
    acc1 = __builtin_amdgcn_mfma_f32_16x16x32_bf16(Av1, Bp, acc1, 0, 0, 0);
  }

  l += __shfl_xor(l, 16);
  l += __shfl_xor(l, 32);

  float* rec = parb + ((size_t)(bh * 4 + jc) * NN + iloc) * 16;
  rec[0] = m; rec[1] = l;                    // 4 lanes write same values
  uint32* ru = (uint32*)(rec + 2);
  ru[2 * g]     = pk2(acc0[0], acc0[1]);     // slot s holds acc[2s],acc[2s+1]
  ru[2 * g + 1] = pk2(acc0[2], acc0[3]);
  if (g < 3) {
    ru[8 + 2 * g]     = pk2(acc1[0], acc1[1]);
    ru[8 + 2 * g + 1] = pk2(acc1[2], acc1[3]);
  }
}

// ---------------------------------------------------------------------------
// Kernel C: merge JC softmax partials -> concat[4096][112]
// ---------------------------------------------------------------------------
template<int JC>
__global__ __launch_bounds__(128) void combine_kernel(float* ws)
{
  const int gg = blockIdx.x * 128 + threadIdx.x;  // (bh, i)
  const int bh = gg >> 11;
  const int i = gg & 2047;
  const int b = bh >> 2, h = bh & 3;
  const float* base = ws + PAR_OFF + ((size_t)bh * JC * NN + i) * 16;

  float M = -1e9f;
  #pragma unroll
  for (int c = 0; c < JC; ++c) M = fmaxf(M, base[(size_t)c * NN * 16]);
  float L = 0.f, o[28];
  #pragma unroll
  for (int d = 0; d < 28; ++d) o[d] = 0.f;
  for (int c = 0; c < JC; ++c) {
    const float* r = base + (size_t)c * NN * 16;
    const float wgt = __expf(r[0] - M);
    L = fmaf(r[1], wgt, L);
    const unsigned* ru = (const unsigned*)(r + 2);
    #pragma unroll
    for (int d = 0; d < 14; ++d) {
      const float2 f = upk2(ru[d]);
      o[2 * d]     = fmaf(f.x, wgt, o[2 * d]);
      o[2 * d + 1] = fmaf(f.y, wgt, o[2 * d + 1]);
    }
  }
  const float inv = 1.f / L;
  float* cat = ws + CAT_OFF + (size_t)(b * NN + i) * 112;
  #pragma unroll
  for (int d = 0; d < 16; ++d) cat[h * 16 + d] = o[d] * inv;
  #pragma unroll
  for (int e = 0; e < 12; ++e) cat[64 + h * 12 + e] = o[16 + e] * inv;
}

// ---------------------------------------------------------------------------
// Kernel D: out = concat[4096][112] @ Wo[112][64] + bo
// ---------------------------------------------------------------------------
template<int MODE>
__global__ __launch_bounds__(256) void out_kernel(
    float* ws, const void* Wo, const void* bo, void* outp)
{
  if (ws[FLAG_OFF] != (float)MODE) return;
  const int t = threadIdx.x;
  const int blk = blockIdx.x;
  const int lr = t >> 6, c = t & 63;
  const int row = blk * 4 + lr;
  __shared__ float si[4 * 112];
  for (int idx = t; idx < 448; idx += 256)
    si[idx] = ws[CAT_OFF + (size_t)blk * 448 + idx];
  __syncthreads();
  float acc = LD<MODE>(bo, c);
  #pragma unroll 16
  for (int kk = 0; kk < 112; ++kk)
    acc = fmaf(si[lr * 112 + kk], LD<MODE>(Wo, (size_t)kk * 64 + c), acc);
  const size_t oi = (size_t)row * 64 + c;
  if (MODE) ((float*)outp)[oi] = acc;
  else      ((bf16*)outp)[oi] = __float2bfloat16(acc);
}

extern "C" void kernel_launch(void* const* d_in, const int* in_sizes, int n_in,
                              void* d_out, int out_size, void* d_ws, size_t ws_size,
                              hipStream_t stream)
{
  float* ws = (float*)d_ws;

  detect_kernel<<<1, 256, 0, stream>>>((const unsigned short*)d_in[0], ws);

  proj_kernel<0><<<BB * NN, 512, 0, stream>>>(d_in[0], d_in[1], d_in[2], d_in[3],
      d_in[4], d_in[5], d_in[6], d_in[7], d_in[8], d_in[9], d_in[10], d_in[11],
      d_in[12], d_in[13], d_in[16], d_in[17], ws);
  proj_kernel<1><<<BB * NN, 512, 0, stream>>>(d_in[0], d_in[1], d_in[2], d_in[3],
      d_in[4], d_in[5], d_in[6], d_in[7], d_in[8], d_in[9], d_in[10], d_in[11],
      d_in[12], d_in[13], d_in[16], d_in[17], ws);

  attn_kernel<<<dim3(4, 32, 8), 256, 0, stream>>>(
      (const uint32*)(ws + QT_OFF), (const uint32*)(ws + KT_OFF),
      (const uint32*)(ws + VT_OFF), ws + CQ_OFF, ws + SB_OFF, ws + PAR_OFF);

  combine_kernel<4><<<128, 128, 0, stream>>>(ws);

  out_kernel<0><<<(BB * NN) / 4, 256, 0, stream>>>(ws, d_in[14], d_in[15], d_out);
  out_kernel<1><<<(BB * NN) / 4, 256, 0, stream>>>(ws, d_in[14], d_in[15], d_out);
}

// Round 11
// 107.387 us; speedup vs baseline: 2.1796x; 1.0031x over previous
//
#include <hip/hip_runtime.h>
#include <hip/hip_bf16.h>

typedef __hip_bfloat16 bf16;
typedef unsigned int uint32;
typedef unsigned short ushort16;
typedef __attribute__((ext_vector_type(8))) short bf16x8;
typedef __attribute__((ext_vector_type(4))) float f32x4;

#define BB 2
#define NN 2048
#define CENTER 15.0f

// workspace float offsets (end = 3,330,064 f32 = 13.3 MB; 15.9 MB proven fit)
#define DIAG_OFF 0u
#define FLAG_OFF 1u
#define QT_OFF   16u       // u32 view [8 bh][2048 i][48]  (96 bf16 slots)
#define KT_OFF   786448u   // u32 view [8 bh][2048 j][48]
#define VT_OFF   1572880u  // u16 view [8 bh][28 d][2048 j]
#define CQ_OFF   1802256u  // f32 [4096]         |c-15|^2
#define SB_OFF   1806352u  // f32 [8 bh][2048]   -0.5*wc*|kp_c|^2
#define CAT_OFF  1822736u  // f32 [4096][112]
#define PAR_OFF  2281488u  // f32 [8 bh][4 jc][2048][16]

__device__ __forceinline__ float b2f(bf16 x) { return __bfloat162float(x); }

template<int MODE>
__device__ __forceinline__ float LD(const void* p, size_t i) {
  if (MODE) return ((const float*)p)[i];
  return __bfloat162float(((const bf16*)p)[i]);
}

__device__ __forceinline__ float softplus_f(float x) {
  return (x > 20.f) ? x : log1pf(__expf(x));
}

__device__ __forceinline__ unsigned pk2(float a, float b) {
  union { __hip_bfloat162 v; unsigned u; } cv;
  cv.v.x = __float2bfloat16(a); cv.v.y = __float2bfloat16(b);
  return cv.u;
}
__device__ __forceinline__ float2 upk2(unsigned u) {
  union { unsigned u; __hip_bfloat162 v; } cv; cv.u = u;
  return make_float2(__bfloat162float(cv.v.x), __bfloat162float(cv.v.y));
}
__device__ __forceinline__ unsigned short f2bu(float x) {
  union { bf16 b; unsigned short u; } c; c.b = __float2bfloat16(x); return c.u;
}
__device__ __forceinline__ float lo_part(float x) {
  return x - __bfloat162float(__float2bfloat16(x));
}

// ---------------------------------------------------------------------------
// dtype detect (proven): fp32 low-halves trip exp>=0xC0 ~25%; bf16 never.
// ---------------------------------------------------------------------------
__global__ __launch_bounds__(256) void detect_kernel(const unsigned short* u,
                                                     float* ws) {
  __shared__ int cnt;
  if (threadIdx.x == 0) cnt = 0;
  __syncthreads();
  int local = 0;
  for (int i = threadIdx.x; i < 4096; i += 256) {
    unsigned e = (u[i] >> 7) & 0xFFu;
    local += (e >= 0xC0u) ? 1 : 0;
  }
  atomicAdd(&cnt, local);
  __syncthreads();
  if (threadIdx.x == 0) {
    ws[FLAG_OFF] = (cnt > 64) ? 1.f : 0.f;
    ((int*)ws)[0] = 0;
  }
}

// MFMA table slot builders. Q-side pairs with K-side over K=32 slots so that
// mfma#1 = wl*q.k + xh.kph ; mfma#2 = xh.kpl + xl.kph ; mfma#3 = ci.cj hi/lo.
__device__ float qslot(int h, int s, const float* spro, const float* cc,
                       float wl, float wc) {
  if (s < 16) return wl * spro[h * 16 + s];
  if (s < 28) return wc * spro[192 + h * 12 + (s - 16)];   // -> xh
  if (s < 32) return 0.f;
  if (s < 44) return wc * spro[192 + h * 12 + (s - 32)];   // -> xh
  if (s < 56) return lo_part(wc * spro[192 + h * 12 + (s - 44)]);  // xl
  if (s < 64) return 0.f;
  if (s < 67) return cc[s - 64];            // cih
  if (s < 70) return cc[s - 67];            // cih
  if (s < 73) return lo_part(cc[s - 70]);   // cil
  return 0.f;
}
__device__ float kslot(int h, int s, const float* spro, const float* cc) {
  if (s < 16) return spro[64 + h * 16 + s];
  if (s < 28) return spro[240 + h * 12 + (s - 16)];        // kph
  if (s < 32) return 0.f;
  if (s < 44) return lo_part(spro[240 + h * 12 + (s - 32)]); // kpl
  if (s < 56) return spro[240 + h * 12 + (s - 44)];        // kph
  if (s < 64) return 0.f;
  if (s < 67) return cc[s - 64];            // cjh
  if (s < 70) return lo_part(cc[s - 67]);   // cjl
  if (s < 73) return cc[s - 70];            // cjh
  return 0.f;
}

// ---------------------------------------------------------------------------
// Kernel A: projections + MFMA table packing. 4096 blocks x 512 threads.
// spro: q[0..63] k[64..127] v[128..191] qp_c[192..239] kp_c[240..287]
//       vp[288..335]   (qp/kp centered by CENTER; vp raw)
// ---------------------------------------------------------------------------
template<int MODE>
__global__ __launch_bounds__(512) void proj_kernel(
    const void* feat, const void* coords,
    const void* Wq,  const void* bq,  const void* Wk,  const void* bk,
    const void* Wv,  const void* bv,  const void* Wqp, const void* bqp,
    const void* Wkp, const void* bkp, const void* Wvp, const void* bvp,
    const void* w_c, const void* w_l, float* ws)
{
  if (ws[FLAG_OFF] != (float)MODE) return;
  const int row = blockIdx.x;       // b*NN + i
  const int b = row >> 11, i = row & 2047;
  const int t = threadIdx.x;
  __shared__ float sf[64];
  __shared__ float spro[336];
  if (t < 64) sf[t] = LD<MODE>(feat, (size_t)row * 64 + t);
  __syncthreads();

  if (t < 336) {
    const void *W, *bias; int odim, c, cls, ofs;
    if (t < 64)       { W = Wq;  bias = bq;  odim = 64; c = t;       cls = 0; ofs = 0; }
    else if (t < 128) { W = Wk;  bias = bk;  odim = 64; c = t - 64;  cls = 1; ofs = 64; }
    else if (t < 192) { W = Wv;  bias = bv;  odim = 64; c = t - 128; cls = 2; ofs = 128; }
    else if (t < 240) { W = Wqp; bias = bqp; odim = 48; c = t - 192; cls = 3; ofs = 192; }
    else if (t < 288) { W = Wkp; bias = bkp; odim = 48; c = t - 240; cls = 4; ofs = 240; }
    else              { W = Wvp; bias = bvp; odim = 48; c = t - 288; cls = 5; ofs = 288; }
    float acc = LD<MODE>(bias, c);
    #pragma unroll 16
    for (int f = 0; f < 64; ++f)
      acc = fmaf(sf[f], LD<MODE>(W, (size_t)f * odim + c), acc);
    if (cls >= 3) {
      acc += LD<MODE>(coords, (size_t)row * 3 + (c % 3));
      if (cls == 3 || cls == 4) acc -= CENTER;   // center qp,kp (shift-inv)
    }
    spro[ofs + c] = acc;
  }
  __syncthreads();

  float cc[3];
  cc[0] = LD<MODE>(coords, (size_t)row * 3 + 0) - CENTER;
  cc[1] = LD<MODE>(coords, (size_t)row * 3 + 1) - CENTER;
  cc[2] = LD<MODE>(coords, (size_t)row * 3 + 2) - CENTER;

  if (t < 384) {
    const bool isq = (t < 192);
    const int per = isq ? t : t - 192;
    const int h = per / 48, w = per - h * 48;
    float wl = softplus_f(LD<MODE>(w_l, h)) * 0.25f;
    float wc = softplus_f(LD<MODE>(w_c, h));
    float a0, a1;
    if (isq) { a0 = qslot(h, 2 * w, spro, cc, wl, wc);
               a1 = qslot(h, 2 * w + 1, spro, cc, wl, wc); }
    else     { a0 = kslot(h, 2 * w, spro, cc);
               a1 = kslot(h, 2 * w + 1, spro, cc); }
    uint32* tab = (uint32*)(ws + (isq ? QT_OFF : KT_OFF));
    tab[((size_t)(b * 4 + h) * NN + i) * 48 + w] = pk2(a0, a1);
  } else if (t < 496) {
    const int tt = t - 384;
    const int h = tt / 28, d = tt - h * 28;
    const float val = (d < 16) ? spro[128 + h * 16 + d]
                               : spro[288 + h * 12 + (d - 16)];
    unsigned short* VTu = (unsigned short*)(ws + VT_OFF);
    VTu[((size_t)((b * 4 + h) * 28 + d)) * NN + i] = f2bu(val);
  } else if (t < 500) {
    const int h = t - 496;
    float wc = softplus_f(LD<MODE>(w_c, h));
    float s = 0.f;
    #pragma unroll
    for (int e = 0; e < 12; ++e) {
      const float y = spro[240 + h * 12 + e];
      s = fmaf(y, y, s);
    }
    ws[SB_OFF + (size_t)(b * 4 + h) * NN + i] = -0.5f * wc * s;
  } else if (t == 500) {
    ws[CQ_OFF + row] = fmaf(cc[0], cc[0], fmaf(cc[1], cc[1], cc[2] * cc[2]));
  }
}

// ---------------------------------------------------------------------------
// Kernel B: MFMA flash attention partials. grid (jc=4, it=32, bh=8), 256 thr.
// Wave = 16 i-rows; j-tiles of 32; S^T & d2 via 3 mfma_16x16x32_bf16 (hi/lo
// packed), PV via 2 mfma; online softmax with 4-lane shfl m-sync; per-wave
// P^T LDS round-trip (no barrier: same-wave produce/consume).
// ---------------------------------------------------------------------------
__global__ __launch_bounds__(256) void attn_kernel(
    const uint32* __restrict__ QTg, const uint32* __restrict__ KTg,
    const uint32* __restrict__ VTg, const float* __restrict__ CQ,
    const float* __restrict__ SBt, float* __restrict__ parb)
{
  const int tid = threadIdx.x;
  const int w = tid >> 6, lane = tid & 63;
  const int li = lane & 15, g = lane >> 4;
  const int jc = blockIdx.x;        // 0..3   (512 j)
  const int it = blockIdx.y;        // 0..31  (64 i)
  const int bh = blockIdx.z;        // 0..7
  const int b = bh >> 2;
  const int iloc = it * 64 + w * 16 + li;

  // Q-side B-frags (per-wave constant)
  const uint32* qrow = QTg + ((size_t)bh * NN + iloc) * 48;
  const bf16x8 B1 = *(const bf16x8*)(qrow + 4 * g);
  const bf16x8 B2 = *(const bf16x8*)(qrow + 16 + 4 * g);
  const bf16x8 B3 = *(const bf16x8*)(qrow + 32 + 4 * g);
  const float ciq = CQ[(size_t)b * NN + iloc];

  float m = -1e9f, l = 0.f;
  f32x4 acc0 = {0.f, 0.f, 0.f, 0.f};
  f32x4 acc1 = {0.f, 0.f, 0.f, 0.f};

  __shared__ uint32 sKT[32 * 52];   // [32 j][104 bf16] padded rows
  __shared__ uint32 sVT[32 * 20];   // [32 d][40 bf16]
  __shared__ float  sCS[64];        // [32 j][cjq, sbias]
  __shared__ uint32 sPT[4][16 * 20];// per-wave P^T [16 i][40 bf16]

  if (tid < 80) sVT[560 + tid] = 0;   // zero d=28..31 rows

  #pragma unroll 1
  for (int jt = 0; jt < 16; ++jt) {
    const int j0 = jc * 512 + jt * 32;
    __syncthreads();
    for (int idx = tid; idx < 1536; idx += 256) {
      const int j = idx / 48, ww = idx - j * 48;
      sKT[j * 52 + ww] = KTg[((size_t)bh * NN + j0 + j) * 48 + ww];
    }
    for (int idx = tid; idx < 448; idx += 256) {
      const int d = idx >> 4, ww = idx & 15;
      sVT[d * 20 + ww] = VTg[(size_t)(bh * 28 + d) * 1024 + (j0 >> 1) + ww];
    }
    if (tid < 64) {
      const int jj = tid >> 1;
      sCS[tid] = (tid & 1) ? SBt[(size_t)bh * NN + j0 + jj]
                           : CQ[(size_t)b * NN + j0 + jj];
    }
    __syncthreads();

    float s[8];
    const f32x4 z = {0.f, 0.f, 0.f, 0.f};
    #pragma unroll
    for (int h2 = 0; h2 < 2; ++h2) {
      const uint32* arow = sKT + (h2 * 16 + li) * 52;
      const bf16x8 A1 = *(const bf16x8*)(arow + 4 * g);
      const bf16x8 A2 = *(const bf16x8*)(arow + 16 + 4 * g);
      const bf16x8 A3 = *(const bf16x8*)(arow + 32 + 4 * g);
      f32x4 Cs = __builtin_amdgcn_mfma_f32_16x16x32_bf16(A1, B1, z, 0, 0, 0);
      Cs = __builtin_amdgcn_mfma_f32_16x16x32_bf16(A2, B2, Cs, 0, 0, 0);
      const f32x4 Cd = __builtin_amdgcn_mfma_f32_16x16x32_bf16(A3, B3, z, 0, 0, 0);
      #pragma unroll
      for (int r = 0; r < 4; ++r) {
        const int jj = h2 * 16 + g * 4 + r;
        const float cjq = sCS[jj * 2], sb = sCS[jj * 2 + 1];
        const float d2 = fmaf(-2.f, Cd[r], ciq + cjq);
        const float sv = Cs[r] + sb;
        s[h2 * 4 + r] = (d2 > 100.f) ? -1e30f : sv;
      }
    }

    // online softmax, branchless, 4-lane group sync (lanes share i)
    float smax = fmaxf(fmaxf(fmaxf(s[0], s[1]), fmaxf(s[2], s[3])),
                       fmaxf(fmaxf(s[4], s[5]), fmaxf(s[6], s[7])));
    smax = fmaxf(smax, __shfl_xor(smax, 16));
    smax = fmaxf(smax, __shfl_xor(smax, 32));
    const float mnew = fmaxf(m, smax);
    const float alpha = __expf(m - mnew);
    m = mnew;
    l *= alpha; acc0 *= alpha; acc1 *= alpha;
    float p[8];
    #pragma unroll
    for (int k = 0; k < 8; ++k) p[k] = __expf(s[k] - m);
    l += ((p[0] + p[1]) + (p[2] + p[3])) + ((p[4] + p[5]) + (p[6] + p[7]));

    // P^T write (per-wave buffer; same-wave read below — lgkmcnt ordered)
    uint32* prow = sPT[w] + li * 20;
    prow[2 * g]     = pk2(p[0], p[1]);
    prow[2 * g + 1] = pk2(p[2], p[3]);
    prow[8 + 2 * g]     = pk2(p[4], p[5]);
    prow[8 + 2 * g + 1] = pk2(p[6], p[7]);

    const bf16x8 Bp  = *(const bf16x8*)(sPT[w] + li * 20 + 4 * g);
    const bf16x8 Av0 = *(const bf16x8*)(sVT + li * 20 + 4 * g);
    const bf16x8 Av1 = *(const bf16x8*)(sVT + (16 + li) * 20 + 4 * g);
    acc0 = __builtin_amdgcn_mfma_f32_16x16x32_bf16(Av0, Bp, acc0, 0, 0, 0);
    acc1 = __builtin_amdgcn_mfma_f32_16x16x32_bf16(Av1, Bp, acc1, 0, 0, 0);
  }

  l += __shfl_xor(l, 16);
  l += __shfl_xor(l, 32);

  float* rec = parb + ((size_t)(bh * 4 + jc) * NN + iloc) * 16;
  rec[0] = m; rec[1] = l;                    // 4 lanes write same values
  uint32* ru = (uint32*)(rec + 2);
  ru[2 * g]     = pk2(acc0[0], acc0[1]);     // slot s holds acc[2s],acc[2s+1]
  ru[2 * g + 1] = pk2(acc0[2], acc0[3]);
  if (g < 3) {
    ru[8 + 2 * g]     = pk2(acc1[0], acc1[1]);
    ru[8 + 2 * g + 1] = pk2(acc1[2], acc1[3]);
  }
}

// ---------------------------------------------------------------------------
// Kernel C: merge JC softmax partials -> concat[4096][112]
// ---------------------------------------------------------------------------
template<int JC>
__global__ __launch_bounds__(128) void combine_kernel(float* ws)
{
  const int gg = blockIdx.x * 128 + threadIdx.x;  // (bh, i)
  const int bh = gg >> 11;
  const int i = gg & 2047;
  const int b = bh >> 2, h = bh & 3;
  const float* base = ws + PAR_OFF + ((size_t)bh * JC * NN + i) * 16;

  float M = -1e9f;
  #pragma unroll
  for (int c = 0; c < JC; ++c) M = fmaxf(M, base[(size_t)c * NN * 16]);
  float L = 0.f, o[28];
  #pragma unroll
  for (int d = 0; d < 28; ++d) o[d] = 0.f;
  for (int c = 0; c < JC; ++c) {
    const float* r = base + (size_t)c * NN * 16;
    const float wgt = __expf(r[0] - M);
    L = fmaf(r[1], wgt, L);
    const unsigned* ru = (const unsigned*)(r + 2);
    #pragma unroll
    for (int d = 0; d < 14; ++d) {
      const float2 f = upk2(ru[d]);
      o[2 * d]     = fmaf(f.x, wgt, o[2 * d]);
      o[2 * d + 1] = fmaf(f.y, wgt, o[2 * d + 1]);
    }
  }
  const float inv = 1.f / L;
  float* cat = ws + CAT_OFF + (size_t)(b * NN + i) * 112;
  #pragma unroll
  for (int d = 0; d < 16; ++d) cat[h * 16 + d] = o[d] * inv;
  #pragma unroll
  for (int e = 0; e < 12; ++e) cat[64 + h * 12 + e] = o[16 + e] * inv;
}

// ---------------------------------------------------------------------------
// Kernel D: out = concat[4096][112] @ Wo[112][64] + bo
// ---------------------------------------------------------------------------
template<int MODE>
__global__ __launch_bounds__(256) void out_kernel(
    float* ws, const void* Wo, const void* bo, void* outp)
{
  if (ws[FLAG_OFF] != (float)MODE) return;
  const int t = threadIdx.x;
  const int blk = blockIdx.x;
  const int lr = t >> 6, c = t & 63;
  const int row = blk * 4 + lr;
  __shared__ float si[4 * 112];
  for (int idx = t; idx < 448; idx += 256)
    si[idx] = ws[CAT_OFF + (size_t)blk * 448 + idx];
  __syncthreads();
  float acc = LD<MODE>(bo, c);
  #pragma unroll 16
  for (int kk = 0; kk < 112; ++kk)
    acc = fmaf(si[lr * 112 + kk], LD<MODE>(Wo, (size_t)kk * 64 + c), acc);
  const size_t oi = (size_t)row * 64 + c;
  if (MODE) ((float*)outp)[oi] = acc;
  else      ((bf16*)outp)[oi] = __float2bfloat16(acc);
}

extern "C" void kernel_launch(void* const* d_in, const int* in_sizes, int n_in,
                              void* d_out, int out_size, void* d_ws, size_t ws_size,
                              hipStream_t stream)
{
  float* ws = (float*)d_ws;

  detect_kernel<<<1, 256, 0, stream>>>((const unsigned short*)d_in[0], ws);

  proj_kernel<0><<<BB * NN, 512, 0, stream>>>(d_in[0], d_in[1], d_in[2], d_in[3],
      d_in[4], d_in[5], d_in[6], d_in[7], d_in[8], d_in[9], d_in[10], d_in[11],
      d_in[12], d_in[13], d_in[16], d_in[17], ws);
  proj_kernel<1><<<BB * NN, 512, 0, stream>>>(d_in[0], d_in[1], d_in[2], d_in[3],
      d_in[4], d_in[5], d_in[6], d_in[7], d_in[8], d_in[9], d_in[10], d_in[11],
      d_in[12], d_in[13], d_in[16], d_in[17], ws);

  attn_kernel<<<dim3(4, 32, 8), 256, 0, stream>>>(
      (const uint32*)(ws + QT_OFF), (const uint32*)(ws + KT_OFF),
      (const uint32*)(ws + VT_OFF), ws + CQ_OFF, ws + SB_OFF, ws + PAR_OFF);

  combine_kernel<4><<<128, 128, 0, stream>>>(ws);

  out_kernel<0><<<(BB * NN) / 4, 256, 0, stream>>>(ws, d_in[14], d_in[15], d_out);
  out_kernel<1><<<(BB * NN) / 4, 256, 0, stream>>>(ws, d_in[14], d_in[15], d_out);
}

// Round 12
// 76.298 us; speedup vs baseline: 3.0678x; 1.4075x over previous
//
#include <hip/hip_runtime.h>
#include <hip/hip_bf16.h>

typedef __hip_bfloat16 bf16;
typedef unsigned int uint32;
typedef __attribute__((ext_vector_type(8))) short bf16x8;
typedef __attribute__((ext_vector_type(4))) float f32x4;

#define BB 2
#define NN 2048
#define CENTER 15.0f

// workspace float offsets (end = 3,330,064 f32 = 13.3 MB; 15.9 MB proven fit)
#define DIAG_OFF 0u
#define FLAG_OFF 1u
#define QT_OFF   16u       // u32 view [8 bh][2048 i][48]  (96 bf16 slots)
#define KT_OFF   786448u   // u32 view [8 bh][2048 j][48]
#define VT_OFF   1572880u  // u16 view [8 bh][28 d][2048 j]
#define CQ_OFF   1802256u  // f32 [4096]         |c-15|^2
#define SB_OFF   1806352u  // f32 [8 bh][2048]   -0.5*wc*|kp_c|^2
#define CAT_OFF  1822736u  // f32 [4096][112]
#define PAR_OFF  2281488u  // f32 [8 bh][4 jc][2048][16]

__device__ __forceinline__ float b2f(bf16 x) { return __bfloat162float(x); }

template<int MODE>
__device__ __forceinline__ float LD(const void* p, size_t i) {
  if (MODE) return ((const float*)p)[i];
  return __bfloat162float(((const bf16*)p)[i]);
}

__device__ __forceinline__ float softplus_f(float x) {
  return (x > 20.f) ? x : log1pf(__expf(x));
}

__device__ __forceinline__ unsigned pk2(float a, float b) {
  union { __hip_bfloat162 v; unsigned u; } cv;
  cv.v.x = __float2bfloat16(a); cv.v.y = __float2bfloat16(b);
  return cv.u;
}
__device__ __forceinline__ float2 upk2(unsigned u) {
  union { unsigned u; __hip_bfloat162 v; } cv; cv.u = u;
  return make_float2(__bfloat162float(cv.v.x), __bfloat162float(cv.v.y));
}
__device__ __forceinline__ unsigned short f2bu(float x) {
  union { bf16 b; unsigned short u; } c; c.b = __float2bfloat16(x); return c.u;
}
__device__ __forceinline__ float lo_part(float x) {
  return x - __bfloat162float(__float2bfloat16(x));
}

// ---------------------------------------------------------------------------
// dtype detect (proven): fp32 low-halves trip exp>=0xC0 ~25%; bf16 never.
// ---------------------------------------------------------------------------
__global__ __launch_bounds__(256) void detect_kernel(const unsigned short* u,
                                                     float* ws) {
  __shared__ int cnt;
  if (threadIdx.x == 0) cnt = 0;
  __syncthreads();
  int local = 0;
  for (int i = threadIdx.x; i < 4096; i += 256) {
    unsigned e = (u[i] >> 7) & 0xFFu;
    local += (e >= 0xC0u) ? 1 : 0;
  }
  atomicAdd(&cnt, local);
  __syncthreads();
  if (threadIdx.x == 0) {
    ws[FLAG_OFF] = (cnt > 64) ? 1.f : 0.f;
    ((int*)ws)[0] = 0;
  }
}

// MFMA table slot builders. Q-side pairs with K-side over K=32 slots so that
// mfma#1 = wl*q.k + xh.kph ; mfma#2 = xh.kpl + xl.kph ; mfma#3 = ci.cj hi/lo.
__device__ float qslot(int h, int s, const float* spro, const float* cc,
                       float wl, float wc) {
  if (s < 16) return wl * spro[h * 16 + s];
  if (s < 28) return wc * spro[192 + h * 12 + (s - 16)];   // -> xh
  if (s < 32) return 0.f;
  if (s < 44) return wc * spro[192 + h * 12 + (s - 32)];   // -> xh
  if (s < 56) return lo_part(wc * spro[192 + h * 12 + (s - 44)]);  // xl
  if (s < 64) return 0.f;
  if (s < 67) return cc[s - 64];            // cih
  if (s < 70) return cc[s - 67];            // cih
  if (s < 73) return lo_part(cc[s - 70]);   // cil
  return 0.f;
}
__device__ float kslot(int h, int s, const float* spro, const float* cc) {
  if (s < 16) return spro[64 + h * 16 + s];
  if (s < 28) return spro[240 + h * 12 + (s - 16)];        // kph
  if (s < 32) return 0.f;
  if (s < 44) return lo_part(spro[240 + h * 12 + (s - 32)]); // kpl
  if (s < 56) return spro[240 + h * 12 + (s - 44)];        // kph
  if (s < 64) return 0.f;
  if (s < 67) return cc[s - 64];            // cjh
  if (s < 70) return lo_part(cc[s - 67]);   // cjl
  if (s < 73) return cc[s - 70];            // cjh
  return 0.f;
}

// ---------------------------------------------------------------------------
// Kernel A: projections + MFMA table packing (verbatim from passing round).
// ---------------------------------------------------------------------------
template<int MODE>
__global__ __launch_bounds__(512) void proj_kernel(
    const void* feat, const void* coords,
    const void* Wq,  const void* bq,  const void* Wk,  const void* bk,
    const void* Wv,  const void* bv,  const void* Wqp, const void* bqp,
    const void* Wkp, const void* bkp, const void* Wvp, const void* bvp,
    const void* w_c, const void* w_l, float* ws)
{
  if (ws[FLAG_OFF] != (float)MODE) return;
  const int row = blockIdx.x;       // b*NN + i
  const int b = row >> 11, i = row & 2047;
  const int t = threadIdx.x;
  __shared__ float sf[64];
  __shared__ float spro[336];
  if (t < 64) sf[t] = LD<MODE>(feat, (size_t)row * 64 + t);
  __syncthreads();

  if (t < 336) {
    const void *W, *bias; int odim, c, cls, ofs;
    if (t < 64)       { W = Wq;  bias = bq;  odim = 64; c = t;       cls = 0; ofs = 0; }
    else if (t < 128) { W = Wk;  bias = bk;  odim = 64; c = t - 64;  cls = 1; ofs = 64; }
    else if (t < 192) { W = Wv;  bias = bv;  odim = 64; c = t - 128; cls = 2; ofs = 128; }
    else if (t < 240) { W = Wqp; bias = bqp; odim = 48; c = t - 192; cls = 3; ofs = 192; }
    else if (t < 288) { W = Wkp; bias = bkp; odim = 48; c = t - 240; cls = 4; ofs = 240; }
    else              { W = Wvp; bias = bvp; odim = 48; c = t - 288; cls = 5; ofs = 288; }
    float acc = LD<MODE>(bias, c);
    #pragma unroll 16
    for (int f = 0; f < 64; ++f)
      acc = fmaf(sf[f], LD<MODE>(W, (size_t)f * odim + c), acc);
    if (cls >= 3) {
      acc += LD<MODE>(coords, (size_t)row * 3 + (c % 3));
      if (cls == 3 || cls == 4) acc -= CENTER;   // center qp,kp (shift-inv)
    }
    spro[ofs + c] = acc;
  }
  __syncthreads();

  float cc[3];
  cc[0] = LD<MODE>(coords, (size_t)row * 3 + 0) - CENTER;
  cc[1] = LD<MODE>(coords, (size_t)row * 3 + 1) - CENTER;
  cc[2] = LD<MODE>(coords, (size_t)row * 3 + 2) - CENTER;

  if (t < 384) {
    const bool isq = (t < 192);
    const int per = isq ? t : t - 192;
    const int h = per / 48, w = per - h * 48;
    float wl = softplus_f(LD<MODE>(w_l, h)) * 0.25f;
    float wc = softplus_f(LD<MODE>(w_c, h));
    float a0, a1;
    if (isq) { a0 = qslot(h, 2 * w, spro, cc, wl, wc);
               a1 = qslot(h, 2 * w + 1, spro, cc, wl, wc); }
    else     { a0 = kslot(h, 2 * w, spro, cc);
               a1 = kslot(h, 2 * w + 1, spro, cc); }
    uint32* tab = (uint32*)(ws + (isq ? QT_OFF : KT_OFF));
    tab[((size_t)(b * 4 + h) * NN + i) * 48 + w] = pk2(a0, a1);
  } else if (t < 496) {
    const int tt = t - 384;
    const int h = tt / 28, d = tt - h * 28;
    const float val = (d < 16) ? spro[128 + h * 16 + d]
                               : spro[288 + h * 12 + (d - 16)];
    unsigned short* VTu = (unsigned short*)(ws + VT_OFF);
    VTu[((size_t)((b * 4 + h) * 28 + d)) * NN + i] = f2bu(val);
  } else if (t < 500) {
    const int h = t - 496;
    float wc = softplus_f(LD<MODE>(w_c, h));
    float s = 0.f;
    #pragma unroll
    for (int e = 0; e < 12; ++e) {
      const float y = spro[240 + h * 12 + e];
      s = fmaf(y, y, s);
    }
    ws[SB_OFF + (size_t)(b * 4 + h) * NN + i] = -0.5f * wc * s;
  } else if (t == 500) {
    ws[CQ_OFF + row] = fmaf(cc[0], cc[0], fmaf(cc[1], cc[1], cc[2] * cc[2]));
  }
}

// ---------------------------------------------------------------------------
// Kernel B: MFMA flash attention. Deltas from passing round 11:
//   * 512 threads / 8 waves / 128 i-rows per block (staging per i halved)
//   * async-STAGE split: issue tile jt+1 global loads (float4, into regs)
//     right after the staging barrier; write to LDS next iteration — HBM/L2
//     latency hides under current tile's MFMA+softmax.
// grid (jc=4, it=16, bh=8), 512 threads.
// ---------------------------------------------------------------------------
__global__ __launch_bounds__(512) void attn_kernel(
    const uint32* __restrict__ QTg, const uint32* __restrict__ KTg,
    const uint32* __restrict__ VTg, const float* __restrict__ CQ,
    const float* __restrict__ SBt, float* __restrict__ parb)
{
  const int tid = threadIdx.x;
  const int w = tid >> 6, lane = tid & 63;
  const int li = lane & 15, g = lane >> 4;
  const int jc = blockIdx.x;        // 0..3   (512 j)
  const int it = blockIdx.y;        // 0..15  (128 i)
  const int bh = blockIdx.z;        // 0..7
  const int b = bh >> 2;
  const int iloc = it * 128 + w * 16 + li;
  const int j0base = jc * 512;

  // Q-side B-frags (per-wave constant)
  const uint32* qrow = QTg + ((size_t)bh * NN + iloc) * 48;
  const bf16x8 B1 = *(const bf16x8*)(qrow + 4 * g);
  const bf16x8 B2 = *(const bf16x8*)(qrow + 16 + 4 * g);
  const bf16x8 B3 = *(const bf16x8*)(qrow + 32 + 4 * g);
  const float ciq = CQ[(size_t)b * NN + iloc];

  float m = -1e9f, l = 0.f;
  f32x4 acc0 = {0.f, 0.f, 0.f, 0.f};
  f32x4 acc1 = {0.f, 0.f, 0.f, 0.f};

  __shared__ uint32 sKT[32 * 52];    // [32 j][104 bf16] padded rows
  __shared__ uint32 sVT[32 * 20];    // [32 d][40 bf16]
  __shared__ float  sCS[64];         // [32 j][cjq, sbias]
  __shared__ uint32 sPT[8][16 * 20]; // per-wave P^T [16 i][40 bf16]

  if (tid < 80) sVT[560 + tid] = 0;  // zero d=28..31 rows (disjoint from staging)

  // staging bases (float4 views; all 16B-aligned by construction)
  const float4* KT4 = (const float4*)(KTg + ((size_t)bh * NN + j0base) * 48);
  const float4* VT4 = (const float4*)VTg;
  const size_t vbase = (size_t)(bh * 28) * 256 + (j0base >> 3);

  float4 kreg = {0.f, 0.f, 0.f, 0.f};
  float4 vreg = {0.f, 0.f, 0.f, 0.f};
  float  creg = 0.f;
  const int kj = tid / 12, kq = tid - kj * 12;     // tid<384 role
  const int vd = tid >> 2, vq = tid & 3;           // tid<112 role
  const int cx = tid - 448, cj = cx & 31;          // tid>=448 role

  auto issue = [&](int jt) {
    if (tid < 384) kreg = KT4[(size_t)jt * 384 + kj * 12 + kq];
    if (tid < 112) vreg = VT4[vbase + (size_t)vd * 256 + jt * 4 + vq];
    if (tid >= 448) {
      const int jg = j0base + jt * 32 + cj;
      creg = (cx < 32) ? CQ[(size_t)b * NN + jg] : SBt[(size_t)bh * NN + jg];
    }
  };

  issue(0);

  #pragma unroll 1
  for (int jt = 0; jt < 16; ++jt) {
    // write staged regs -> LDS
    if (tid < 384) *(float4*)(sKT + kj * 52 + kq * 4) = kreg;
    if (tid < 112) *(float4*)(sVT + vd * 20 + vq * 4) = vreg;
    if (tid >= 448) sCS[(cj << 1) | (cx >> 5)] = creg;
    __syncthreads();
    if (jt < 15) issue(jt + 1);    // async: latency hides under compute below

    float s[8];
    const f32x4 z = {0.f, 0.f, 0.f, 0.f};
    #pragma unroll
    for (int h2 = 0; h2 < 2; ++h2) {
      const uint32* arow = sKT + (h2 * 16 + li) * 52;
      const bf16x8 A1 = *(const bf16x8*)(arow + 4 * g);
      const bf16x8 A2 = *(const bf16x8*)(arow + 16 + 4 * g);
      const bf16x8 A3 = *(const bf16x8*)(arow + 32 + 4 * g);
      f32x4 Cs = __builtin_amdgcn_mfma_f32_16x16x32_bf16(A1, B1, z, 0, 0, 0);
      Cs = __builtin_amdgcn_mfma_f32_16x16x32_bf16(A2, B2, Cs, 0, 0, 0);
      const f32x4 Cd = __builtin_amdgcn_mfma_f32_16x16x32_bf16(A3, B3, z, 0, 0, 0);
      #pragma unroll
      for (int r = 0; r < 4; ++r) {
        const int jj = h2 * 16 + g * 4 + r;
        const float cjq = sCS[jj * 2], sb = sCS[jj * 2 + 1];
        const float d2 = fmaf(-2.f, Cd[r], ciq + cjq);
        const float sv = Cs[r] + sb;
        s[h2 * 4 + r] = (d2 > 100.f) ? -1e30f : sv;
      }
    }

    // online softmax, branchless, 4-lane group sync (lanes share i)
    float smax = fmaxf(fmaxf(fmaxf(s[0], s[1]), fmaxf(s[2], s[3])),
                       fmaxf(fmaxf(s[4], s[5]), fmaxf(s[6], s[7])));
    smax = fmaxf(smax, __shfl_xor(smax, 16));
    smax = fmaxf(smax, __shfl_xor(smax, 32));
    const float mnew = fmaxf(m, smax);
    const float alpha = __expf(m - mnew);
    m = mnew;
    l *= alpha; acc0 *= alpha; acc1 *= alpha;
    float p[8];
    #pragma unroll
    for (int k = 0; k < 8; ++k) p[k] = __expf(s[k] - m);
    l += ((p[0] + p[1]) + (p[2] + p[3])) + ((p[4] + p[5]) + (p[6] + p[7]));

    // P^T write (per-wave buffer; same-wave read below — lgkmcnt ordered)
    uint32* prow = sPT[w] + li * 20;
    prow[2 * g]     = pk2(p[0], p[1]);
    prow[2 * g + 1] = pk2(p[2], p[3]);
    prow[8 + 2 * g]     = pk2(p[4], p[5]);
    prow[8 + 2 * g + 1] = pk2(p[6], p[7]);

    const bf16x8 Bp  = *(const bf16x8*)(sPT[w] + li * 20 + 4 * g);
    const bf16x8 Av0 = *(const bf16x8*)(sVT + li * 20 + 4 * g);
    const bf16x8 Av1 = *(const bf16x8*)(sVT + (16 + li) * 20 + 4 * g);
    acc0 = __builtin_amdgcn_mfma_f32_16x16x32_bf16(Av0, Bp, acc0, 0, 0, 0);
    acc1 = __builtin_amdgcn_mfma_f32_16x16x32_bf16(Av1, Bp, acc1, 0, 0, 0);
    __syncthreads();
  }

  l += __shfl_xor(l, 16);
  l += __shfl_xor(l, 32);

  float* rec = parb + ((size_t)(bh * 4 + jc) * NN + iloc) * 16;
  rec[0] = m; rec[1] = l;                    // 4 lanes write same values
  uint32* ru = (uint32*)(rec + 2);
  ru[2 * g]     = pk2(acc0[0], acc0[1]);     // slot s holds acc[2s],acc[2s+1]
  ru[2 * g + 1] = pk2(acc0[2], acc0[3]);
  if (g < 3) {
    ru[8 + 2 * g]     = pk2(acc1[0], acc1[1]);
    ru[8 + 2 * g + 1] = pk2(acc1[2], acc1[3]);
  }
}

// ---------------------------------------------------------------------------
// Kernel C: merge JC softmax partials -> concat[4096][112]  (verbatim)
// ---------------------------------------------------------------------------
template<int JC>
__global__ __launch_bounds__(128) void combine_kernel(float* ws)
{
  const int gg = blockIdx.x * 128 + threadIdx.x;  // (bh, i)
  const int bh = gg >> 11;
  const int i = gg & 2047;
  const int b = bh >> 2, h = bh & 3;
  const float* base = ws + PAR_OFF + ((size_t)bh * JC * NN + i) * 16;

  float M = -1e9f;
  #pragma unroll
  for (int c = 0; c < JC; ++c) M = fmaxf(M, base[(size_t)c * NN * 16]);
  float L = 0.f, o[28];
  #pragma unroll
  for (int d = 0; d < 28; ++d) o[d] = 0.f;
  for (int c = 0; c < JC; ++c) {
    const float* r = base + (size_t)c * NN * 16;
    const float wgt = __expf(r[0] - M);
    L = fmaf(r[1], wgt, L);
    const unsigned* ru = (const unsigned*)(r + 2);
    #pragma unroll
    for (int d = 0; d < 14; ++d) {
      const float2 f = upk2(ru[d]);
      o[2 * d]     = fmaf(f.x, wgt, o[2 * d]);
      o[2 * d + 1] = fmaf(f.y, wgt, o[2 * d + 1]);
    }
  }
  const float inv = 1.f / L;
  float* cat = ws + CAT_OFF + (size_t)(b * NN + i) * 112;
  #pragma unroll
  for (int d = 0; d < 16; ++d) cat[h * 16 + d] = o[d] * inv;
  #pragma unroll
  for (int e = 0; e < 12; ++e) cat[64 + h * 12 + e] = o[16 + e] * inv;
}

// ---------------------------------------------------------------------------
// Kernel D: out = concat[4096][112] @ Wo[112][64] + bo  (verbatim)
// ---------------------------------------------------------------------------
template<int MODE>
__global__ __launch_bounds__(256) void out_kernel(
    float* ws, const void* Wo, const void* bo, void* outp)
{
  if (ws[FLAG_OFF] != (float)MODE) return;
  const int t = threadIdx.x;
  const int blk = blockIdx.x;
  const int lr = t >> 6, c = t & 63;
  const int row = blk * 4 + lr;
  __shared__ float si[4 * 112];
  for (int idx = t; idx < 448; idx += 256)
    si[idx] = ws[CAT_OFF + (size_t)blk * 448 + idx];
  __syncthreads();
  float acc = LD<MODE>(bo, c);
  #pragma unroll 16
  for (int kk = 0; kk < 112; ++kk)
    acc = fmaf(si[lr * 112 + kk], LD<MODE>(Wo, (size_t)kk * 64 + c), acc);
  const size_t oi = (size_t)row * 64 + c;
  if (MODE) ((float*)outp)[oi] = acc;
  else      ((bf16*)outp)[oi] = __float2bfloat16(acc);
}

extern "C" void kernel_launch(void* const* d_in, const int* in_sizes, int n_in,
                              void* d_out, int out_size, void* d_ws, size_t ws_size,
                              hipStream_t stream)
{
  float* ws = (float*)d_ws;

  detect_kernel<<<1, 256, 0, stream>>>((const unsigned short*)d_in[0], ws);

  proj_kernel<0><<<BB * NN, 512, 0, stream>>>(d_in[0], d_in[1], d_in[2], d_in[3],
      d_in[4], d_in[5], d_in[6], d_in[7], d_in[8], d_in[9], d_in[10], d_in[11],
      d_in[12], d_in[13], d_in[16], d_in[17], ws);
  proj_kernel<1><<<BB * NN, 512, 0, stream>>>(d_in[0], d_in[1], d_in[2], d_in[3],
      d_in[4], d_in[5], d_in[6], d_in[7], d_in[8], d_in[9], d_in[10], d_in[11],
      d_in[12], d_in[13], d_in[16], d_in[17], ws);

  attn_kernel<<<dim3(4, 16, 8), 512, 0, stream>>>(
      (const uint32*)(ws + QT_OFF), (const uint32*)(ws + KT_OFF),
      (const uint32*)(ws + VT_OFF), ws + CQ_OFF, ws + SB_OFF, ws + PAR_OFF);

  combine_kernel<4><<<128, 128, 0, stream>>>(ws);

  out_kernel<0><<<(BB * NN) / 4, 256, 0, stream>>>(ws, d_in[14], d_in[15], d_out);
  out_kernel<1><<<(BB * NN) / 4, 256, 0, stream>>>(ws, d_in[14], d_in[15], d_out);
}

// Round 13
// 70.648 us; speedup vs baseline: 3.3131x; 1.0800x over previous
//
#include <hip/hip_runtime.h>
#include <hip/hip_bf16.h>

typedef __hip_bfloat16 bf16;
typedef unsigned int uint32;
typedef __attribute__((ext_vector_type(8))) short bf16x8;
typedef __attribute__((ext_vector_type(4))) float f32x4;

#define BB 2
#define NN 2048
#define CENTER 15.0f

// workspace float offsets (end = 3,330,064 f32 = 13.3 MB)
#define DIAG_OFF 0u
#define FLAG_OFF 1u
#define QT_OFF   16u       // u32 view [8 bh][2048 i][48]  (96 bf16 slots)
#define KT_OFF   786448u   // u32 view [8 bh][2048 j][48]
#define VT_OFF   1572880u  // u16 view [8 bh][28 d][2048 j]
#define CQ_OFF   1802256u  // f32 [4096]         |c-15|^2
#define SB_OFF   1806352u  // f32 [8 bh][2048]   -0.5*wc*|kp_c|^2
#define PAR_OFF  2281488u  // f32 [8 bh][4 jc][2048][16]

__device__ __forceinline__ float b2f(bf16 x) { return __bfloat162float(x); }

__device__ __forceinline__ float ldm(const void* p, size_t i, int mode) {
  return mode ? ((const float*)p)[i] : b2f(((const bf16*)p)[i]);
}

__device__ __forceinline__ float softplus_f(float x) {
  return (x > 20.f) ? x : log1pf(__expf(x));
}

__device__ __forceinline__ unsigned pk2(float a, float b) {
  union { __hip_bfloat162 v; unsigned u; } cv;
  cv.v.x = __float2bfloat16(a); cv.v.y = __float2bfloat16(b);
  return cv.u;
}
__device__ __forceinline__ float2 upk2(unsigned u) {
  union { unsigned u; __hip_bfloat162 v; } cv; cv.u = u;
  return make_float2(__bfloat162float(cv.v.x), __bfloat162float(cv.v.y));
}
__device__ __forceinline__ unsigned short f2bu(float x) {
  union { bf16 b; unsigned short u; } c; c.b = __float2bfloat16(x); return c.u;
}
__device__ __forceinline__ float lo_part(float x) {
  return x - __bfloat162float(__float2bfloat16(x));
}

// ---------------------------------------------------------------------------
// dtype detect (proven): fp32 low-halves trip exp>=0xC0 ~25%; bf16 never.
// ---------------------------------------------------------------------------
__global__ __launch_bounds__(256) void detect_kernel(const unsigned short* u,
                                                     float* ws) {
  __shared__ int cnt;
  if (threadIdx.x == 0) cnt = 0;
  __syncthreads();
  int local = 0;
  for (int i = threadIdx.x; i < 4096; i += 256) {
    unsigned e = (u[i] >> 7) & 0xFFu;
    local += (e >= 0xC0u) ? 1 : 0;
  }
  atomicAdd(&cnt, local);
  __syncthreads();
  if (threadIdx.x == 0) {
    ws[FLAG_OFF] = (cnt > 64) ? 1.f : 0.f;
    ((int*)ws)[0] = 0;
  }
}

// MFMA table slot builders (proven round 11/12).
__device__ float qslot(int h, int s, const float* spro, const float* cc,
                       float wl, float wc) {
  if (s < 16) return wl * spro[h * 16 + s];
  if (s < 28) return wc * spro[192 + h * 12 + (s - 16)];
  if (s < 32) return 0.f;
  if (s < 44) return wc * spro[192 + h * 12 + (s - 32)];
  if (s < 56) return lo_part(wc * spro[192 + h * 12 + (s - 44)]);
  if (s < 64) return 0.f;
  if (s < 67) return cc[s - 64];
  if (s < 70) return cc[s - 67];
  if (s < 73) return lo_part(cc[s - 70]);
  return 0.f;
}
__device__ float kslot(int h, int s, const float* spro, const float* cc) {
  if (s < 16) return spro[64 + h * 16 + s];
  if (s < 28) return spro[240 + h * 12 + (s - 16)];
  if (s < 32) return 0.f;
  if (s < 44) return lo_part(spro[240 + h * 12 + (s - 32)]);
  if (s < 56) return spro[240 + h * 12 + (s - 44)];
  if (s < 64) return 0.f;
  if (s < 67) return cc[s - 64];
  if (s < 70) return lo_part(cc[s - 67]);
  if (s < 73) return cc[s - 70];
  return 0.f;
}

// ---------------------------------------------------------------------------
// Kernel A: projections + MFMA table packing — proven body, runtime MODE
// (uniform flag read; both load-loops compiled, scalar branch selects).
// ---------------------------------------------------------------------------
__global__ __launch_bounds__(512) void proj_kernel(
    const void* feat, const void* coords,
    const void* Wq,  const void* bq,  const void* Wk,  const void* bk,
    const void* Wv,  const void* bv,  const void* Wqp, const void* bqp,
    const void* Wkp, const void* bkp, const void* Wvp, const void* bvp,
    const void* w_c, const void* w_l, float* ws)
{
  const int mode = (int)ws[FLAG_OFF];
  const int row = blockIdx.x;       // b*NN + i
  const int b = row >> 11, i = row & 2047;
  const int t = threadIdx.x;
  __shared__ float sf[64];
  __shared__ float spro[336];
  if (t < 64) sf[t] = ldm(feat, (size_t)row * 64 + t, mode);
  __syncthreads();

  if (t < 336) {
    const void *W, *bias; int odim, c, cls, ofs;
    if (t < 64)       { W = Wq;  bias = bq;  odim = 64; c = t;       cls = 0; ofs = 0; }
    else if (t < 128) { W = Wk;  bias = bk;  odim = 64; c = t - 64;  cls = 1; ofs = 64; }
    else if (t < 192) { W = Wv;  bias = bv;  odim = 64; c = t - 128; cls = 2; ofs = 128; }
    else if (t < 240) { W = Wqp; bias = bqp; odim = 48; c = t - 192; cls = 3; ofs = 192; }
    else if (t < 288) { W = Wkp; bias = bkp; odim = 48; c = t - 240; cls = 4; ofs = 240; }
    else              { W = Wvp; bias = bvp; odim = 48; c = t - 288; cls = 5; ofs = 288; }
    float acc = ldm(bias, c, mode);
    if (mode) {
      const float* Wf = (const float*)W;
      #pragma unroll 16
      for (int f = 0; f < 64; ++f)
        acc = fmaf(sf[f], Wf[(size_t)f * odim + c], acc);
    } else {
      const bf16* Wb = (const bf16*)W;
      #pragma unroll 16
      for (int f = 0; f < 64; ++f)
        acc = fmaf(sf[f], b2f(Wb[(size_t)f * odim + c]), acc);
    }
    if (cls >= 3) {
      acc += ldm(coords, (size_t)row * 3 + (c % 3), mode);
      if (cls == 3 || cls == 4) acc -= CENTER;   // center qp,kp (shift-inv)
    }
    spro[ofs + c] = acc;
  }
  __syncthreads();

  float cc[3];
  cc[0] = ldm(coords, (size_t)row * 3 + 0, mode) - CENTER;
  cc[1] = ldm(coords, (size_t)row * 3 + 1, mode) - CENTER;
  cc[2] = ldm(coords, (size_t)row * 3 + 2, mode) - CENTER;

  if (t < 384) {
    const bool isq = (t < 192);
    const int per = isq ? t : t - 192;
    const int h = per / 48, w = per - h * 48;
    float wl = softplus_f(ldm(w_l, h, mode)) * 0.25f;
    float wc = softplus_f(ldm(w_c, h, mode));
    float a0, a1;
    if (isq) { a0 = qslot(h, 2 * w, spro, cc, wl, wc);
               a1 = qslot(h, 2 * w + 1, spro, cc, wl, wc); }
    else     { a0 = kslot(h, 2 * w, spro, cc);
               a1 = kslot(h, 2 * w + 1, spro, cc); }
    uint32* tab = (uint32*)(ws + (isq ? QT_OFF : KT_OFF));
    tab[((size_t)(b * 4 + h) * NN + i) * 48 + w] = pk2(a0, a1);
  } else if (t < 496) {
    const int tt = t - 384;
    const int h = tt / 28, d = tt - h * 28;
    const float val = (d < 16) ? spro[128 + h * 16 + d]
                               : spro[288 + h * 12 + (d - 16)];
    unsigned short* VTu = (unsigned short*)(ws + VT_OFF);
    VTu[((size_t)((b * 4 + h) * 28 + d)) * NN + i] = f2bu(val);
  } else if (t < 500) {
    const int h = t - 496;
    float wc = softplus_f(ldm(w_c, h, mode));
    float s = 0.f;
    #pragma unroll
    for (int e = 0; e < 12; ++e) {
      const float y = spro[240 + h * 12 + e];
      s = fmaf(y, y, s);
    }
    ws[SB_OFF + (size_t)(b * 4 + h) * NN + i] = -0.5f * wc * s;
  } else if (t == 500) {
    ws[CQ_OFF + row] = fmaf(cc[0], cc[0], fmaf(cc[1], cc[1], cc[2] * cc[2]));
  }
}

// ---------------------------------------------------------------------------
// Kernel B: MFMA flash attention — byte-identical to passing round 12 except
// s_setprio(1/0) wrapped around the MFMA clusters (T5; phase-split present).
// grid (jc=4, it=16, bh=8), 512 threads.
// ---------------------------------------------------------------------------
__global__ __launch_bounds__(512) void attn_kernel(
    const uint32* __restrict__ QTg, const uint32* __restrict__ KTg,
    const uint32* __restrict__ VTg, const float* __restrict__ CQ,
    const float* __restrict__ SBt, float* __restrict__ parb)
{
  const int tid = threadIdx.x;
  const int w = tid >> 6, lane = tid & 63;
  const int li = lane & 15, g = lane >> 4;
  const int jc = blockIdx.x;        // 0..3   (512 j)
  const int it = blockIdx.y;        // 0..15  (128 i)
  const int bh = blockIdx.z;        // 0..7
  const int b = bh >> 2;
  const int iloc = it * 128 + w * 16 + li;
  const int j0base = jc * 512;

  const uint32* qrow = QTg + ((size_t)bh * NN + iloc) * 48;
  const bf16x8 B1 = *(const bf16x8*)(qrow + 4 * g);
  const bf16x8 B2 = *(const bf16x8*)(qrow + 16 + 4 * g);
  const bf16x8 B3 = *(const bf16x8*)(qrow + 32 + 4 * g);
  const float ciq = CQ[(size_t)b * NN + iloc];

  float m = -1e9f, l = 0.f;
  f32x4 acc0 = {0.f, 0.f, 0.f, 0.f};
  f32x4 acc1 = {0.f, 0.f, 0.f, 0.f};

  __shared__ uint32 sKT[32 * 52];    // [32 j][104 bf16] padded rows
  __shared__ uint32 sVT[32 * 20];    // [32 d][40 bf16]
  __shared__ float  sCS[64];         // [32 j][cjq, sbias]
  __shared__ uint32 sPT[8][16 * 20]; // per-wave P^T [16 i][40 bf16]

  if (tid < 80) sVT[560 + tid] = 0;  // zero d=28..31 rows

  const float4* KT4 = (const float4*)(KTg + ((size_t)bh * NN + j0base) * 48);
  const float4* VT4 = (const float4*)VTg;
  const size_t vbase = (size_t)(bh * 28) * 256 + (j0base >> 3);

  float4 kreg = {0.f, 0.f, 0.f, 0.f};
  float4 vreg = {0.f, 0.f, 0.f, 0.f};
  float  creg = 0.f;
  const int kj = tid / 12, kq = tid - kj * 12;     // tid<384 role
  const int vd = tid >> 2, vq = tid & 3;           // tid<112 role
  const int cx = tid - 448, cj = cx & 31;          // tid>=448 role

  auto issue = [&](int jt) {
    if (tid < 384) kreg = KT4[(size_t)jt * 384 + kj * 12 + kq];
    if (tid < 112) vreg = VT4[vbase + (size_t)vd * 256 + jt * 4 + vq];
    if (tid >= 448) {
      const int jg = j0base + jt * 32 + cj;
      creg = (cx < 32) ? CQ[(size_t)b * NN + jg] : SBt[(size_t)bh * NN + jg];
    }
  };

  issue(0);

  #pragma unroll 1
  for (int jt = 0; jt < 16; ++jt) {
    if (tid < 384) *(float4*)(sKT + kj * 52 + kq * 4) = kreg;
    if (tid < 112) *(float4*)(sVT + vd * 20 + vq * 4) = vreg;
    if (tid >= 448) sCS[(cj << 1) | (cx >> 5)] = creg;
    __syncthreads();
    if (jt < 15) issue(jt + 1);    // async: latency hides under compute below

    float s[8];
    const f32x4 z = {0.f, 0.f, 0.f, 0.f};
    __builtin_amdgcn_s_setprio(1);
    #pragma unroll
    for (int h2 = 0; h2 < 2; ++h2) {
      const uint32* arow = sKT + (h2 * 16 + li) * 52;
      const bf16x8 A1 = *(const bf16x8*)(arow + 4 * g);
      const bf16x8 A2 = *(const bf16x8*)(arow + 16 + 4 * g);
      const bf16x8 A3 = *(const bf16x8*)(arow + 32 + 4 * g);
      f32x4 Cs = __builtin_amdgcn_mfma_f32_16x16x32_bf16(A1, B1, z, 0, 0, 0);
      Cs = __builtin_amdgcn_mfma_f32_16x16x32_bf16(A2, B2, Cs, 0, 0, 0);
      const f32x4 Cd = __builtin_amdgcn_mfma_f32_16x16x32_bf16(A3, B3, z, 0, 0, 0);
      #pragma unroll
      for (int r = 0; r < 4; ++r) {
        const int jj = h2 * 16 + g * 4 + r;
        const float cjq = sCS[jj * 2], sb = sCS[jj * 2 + 1];
        const float d2 = fmaf(-2.f, Cd[r], ciq + cjq);
        const float sv = Cs[r] + sb;
        s[h2 * 4 + r] = (d2 > 100.f) ? -1e30f : sv;
      }
    }
    __builtin_amdgcn_s_setprio(0);

    float smax = fmaxf(fmaxf(fmaxf(s[0], s[1]), fmaxf(s[2], s[3])),
                       fmaxf(fmaxf(s[4], s[5]), fmaxf(s[6], s[7])));
    smax = fmaxf(smax, __shfl_xor(smax, 16));
    smax = fmaxf(smax, __shfl_xor(smax, 32));
    const float mnew = fmaxf(m, smax);
    const float alpha = __expf(m - mnew);
    m = mnew;
    l *= alpha; acc0 *= alpha; acc1 *= alpha;
    float p[8];
    #pragma unroll
    for (int k = 0; k < 8; ++k) p[k] = __expf(s[k] - m);
    l += ((p[0] + p[1]) + (p[2] + p[3])) + ((p[4] + p[5]) + (p[6] + p[7]));

    uint32* prow = sPT[w] + li * 20;
    prow[2 * g]     = pk2(p[0], p[1]);
    prow[2 * g + 1] = pk2(p[2], p[3]);
    prow[8 + 2 * g]     = pk2(p[4], p[5]);
    prow[8 + 2 * g + 1] = pk2(p[6], p[7]);

    const bf16x8 Bp  = *(const bf16x8*)(sPT[w] + li * 20 + 4 * g);
    const bf16x8 Av0 = *(const bf16x8*)(sVT + li * 20 + 4 * g);
    const bf16x8 Av1 = *(const bf16x8*)(sVT + (16 + li) * 20 + 4 * g);
    __builtin_amdgcn_s_setprio(1);
    acc0 = __builtin_amdgcn_mfma_f32_16x16x32_bf16(Av0, Bp, acc0, 0, 0, 0);
    acc1 = __builtin_amdgcn_mfma_f32_16x16x32_bf16(Av1, Bp, acc1, 0, 0, 0);
    __builtin_amdgcn_s_setprio(0);
    __syncthreads();
  }

  l += __shfl_xor(l, 16);
  l += __shfl_xor(l, 32);

  float* rec = parb + ((size_t)(bh * 4 + jc) * NN + iloc) * 16;
  rec[0] = m; rec[1] = l;                    // 4 lanes write same values
  uint32* ru = (uint32*)(rec + 2);
  ru[2 * g]     = pk2(acc0[0], acc0[1]);     // slot s holds acc[2s],acc[2s+1]
  ru[2 * g + 1] = pk2(acc0[2], acc0[3]);
  if (g < 3) {
    ru[8 + 2 * g]     = pk2(acc1[0], acc1[1]);
    ru[8 + 2 * g + 1] = pk2(acc1[2], acc1[3]);
  }
}

// ---------------------------------------------------------------------------
// Kernel C: fused combine + output GEMM. 1024 blocks x 256 threads; block =
// 4 rows. Phase A (16 thr): merged M, 1/L per (row,h) from 4 PAR chunks.
// Phase B (224 thr): one packed acc-pair each -> si[4][112]. Phase C: GEMM.
// Merge math identical to the proven combine_kernel.
// ---------------------------------------------------------------------------
__global__ __launch_bounds__(256) void out_kernel(
    const float* __restrict__ parb, const void* Wo, const void* bo,
    const float* __restrict__ flagp, void* outp)
{
  const int mode = (int)(*flagp);
  const int t = threadIdx.x;
  const int blk = blockIdx.x;
  __shared__ float si[4 * 112];
  __shared__ float sM[16], sIL[16];

  if (t < 16) {
    const int lr = t >> 2, h = t & 3;
    const int row = blk * 4 + lr, b = row >> 11, i = row & 2047;
    const int bh = b * 4 + h;
    const float* base = parb + ((size_t)(bh * 4) * NN + i) * 16;
    float M = -1e9f;
    #pragma unroll
    for (int c = 0; c < 4; ++c) M = fmaxf(M, base[(size_t)c * NN * 16]);
    float L = 0.f;
    #pragma unroll
    for (int c = 0; c < 4; ++c) {
      const float* r = base + (size_t)c * NN * 16;
      L = fmaf(r[1], __expf(r[0] - M), L);
    }
    sM[t] = M; sIL[t] = 1.f / L;
  }
  __syncthreads();

  if (t < 224) {
    const int u = t / 14, pr = t - u * 14;   // u: (lr,h) 0..15, pr: pair 0..13
    const int lr = u >> 2, h = u & 3;
    const int row = blk * 4 + lr, b = row >> 11, i = row & 2047;
    const int bh = b * 4 + h;
    const float* base = parb + ((size_t)(bh * 4) * NN + i) * 16;
    const float M = sM[u], iL = sIL[u];
    float o0 = 0.f, o1 = 0.f;
    #pragma unroll
    for (int c = 0; c < 4; ++c) {
      const float* r = base + (size_t)c * NN * 16;
      const float wgt = __expf(r[0] - M);
      const float2 f = upk2(((const unsigned*)(r + 2))[pr]);
      o0 = fmaf(f.x, wgt, o0); o1 = fmaf(f.y, wgt, o1);
    }
    const int d = 2 * pr;
    const int col = (d < 16) ? (h * 16 + d) : (64 + h * 12 + (d - 16));
    si[lr * 112 + col]     = o0 * iL;
    si[lr * 112 + col + 1] = o1 * iL;
  }
  __syncthreads();

  const int lr = t >> 6, c = t & 63;
  float acc = mode ? ((const float*)bo)[c] : b2f(((const bf16*)bo)[c]);
  if (mode) {
    const float* Wf = (const float*)Wo;
    #pragma unroll 16
    for (int kk = 0; kk < 112; ++kk)
      acc = fmaf(si[lr * 112 + kk], Wf[(size_t)kk * 64 + c], acc);
  } else {
    const bf16* Wb = (const bf16*)Wo;
    #pragma unroll 16
    for (int kk = 0; kk < 112; ++kk)
      acc = fmaf(si[lr * 112 + kk], b2f(Wb[(size_t)kk * 64 + c]), acc);
  }
  const size_t oi = (size_t)(blk * 4 + lr) * 64 + c;
  if (mode) ((float*)outp)[oi] = acc;
  else      ((bf16*)outp)[oi] = __float2bfloat16(acc);
}

extern "C" void kernel_launch(void* const* d_in, const int* in_sizes, int n_in,
                              void* d_out, int out_size, void* d_ws, size_t ws_size,
                              hipStream_t stream)
{
  float* ws = (float*)d_ws;

  detect_kernel<<<1, 256, 0, stream>>>((const unsigned short*)d_in[0], ws);

  proj_kernel<<<BB * NN, 512, 0, stream>>>(d_in[0], d_in[1], d_in[2], d_in[3],
      d_in[4], d_in[5], d_in[6], d_in[7], d_in[8], d_in[9], d_in[10], d_in[11],
      d_in[12], d_in[13], d_in[16], d_in[17], ws);

  attn_kernel<<<dim3(4, 16, 8), 512, 0, stream>>>(
      (const uint32*)(ws + QT_OFF), (const uint32*)(ws + KT_OFF),
      (const uint32*)(ws + VT_OFF), ws + CQ_OFF, ws + SB_OFF, ws + PAR_OFF);

  out_kernel<<<(BB * NN) / 4, 256, 0, stream>>>(
      ws + PAR_OFF, d_in[14], d_in[15], ws + FLAG_OFF, d_out);
}

// Round 14
// 55.684 us; speedup vs baseline: 4.2034x; 1.2687x over previous
//
#include <hip/hip_runtime.h>
#include <hip/hip_bf16.h>

typedef __hip_bfloat16 bf16;
typedef unsigned int uint32;
typedef __attribute__((ext_vector_type(8))) short bf16x8;
typedef __attribute__((ext_vector_type(4))) float f32x4;

#define BB 2
#define NN 2048
#define CENTER 15.0f

// workspace float offsets (end = 3,330,064 f32 = 13.3 MB)
#define QT_OFF   16u       // u32 view [8 bh][2048 i][48]  (96 bf16 slots)
#define KT_OFF   786448u   // u32 view [8 bh][2048 j][48]
#define VT_OFF   1572880u  // u16 view [8 bh][28 d][2048 j]
#define CQ_OFF   1802256u  // f32 [4096]         |c-15|^2
#define SB_OFF   1806352u  // f32 [8 bh][2048]   -0.5*wc*|kp_c|^2
#define PAR_OFF  2281488u  // f32 [8 bh][4 jc][2048][16]

__device__ __forceinline__ float b2f(bf16 x) { return __bfloat162float(x); }

__device__ __forceinline__ float ldm(const void* p, size_t i, int mode) {
  return mode ? ((const float*)p)[i] : b2f(((const bf16*)p)[i]);
}

__device__ __forceinline__ float softplus_f(float x) {
  return (x > 20.f) ? x : log1pf(__expf(x));
}

__device__ __forceinline__ unsigned pk2(float a, float b) {
  union { __hip_bfloat162 v; unsigned u; } cv;
  cv.v.x = __float2bfloat16(a); cv.v.y = __float2bfloat16(b);
  return cv.u;
}
__device__ __forceinline__ float2 upk2(unsigned u) {
  union { unsigned u; __hip_bfloat162 v; } cv; cv.u = u;
  return make_float2(__bfloat162float(cv.v.x), __bfloat162float(cv.v.y));
}
__device__ __forceinline__ unsigned short f2bu(float x) {
  union { bf16 b; unsigned short u; } c; c.b = __float2bfloat16(x); return c.u;
}
__device__ __forceinline__ float lo_part(float x) {
  return x - __bfloat162float(__float2bfloat16(x));
}

// MFMA table slot builders (proven rounds 11-13).
__device__ float qslot(int h, int s, const float* spro, const float* cc,
                       float wl, float wc) {
  if (s < 16) return wl * spro[h * 16 + s];
  if (s < 28) return wc * spro[192 + h * 12 + (s - 16)];
  if (s < 32) return 0.f;
  if (s < 44) return wc * spro[192 + h * 12 + (s - 32)];
  if (s < 56) return lo_part(wc * spro[192 + h * 12 + (s - 44)]);
  if (s < 64) return 0.f;
  if (s < 67) return cc[s - 64];
  if (s < 70) return cc[s - 67];
  if (s < 73) return lo_part(cc[s - 70]);
  return 0.f;
}
__device__ float kslot(int h, int s, const float* spro, const float* cc) {
  if (s < 16) return spro[64 + h * 16 + s];
  if (s < 28) return spro[240 + h * 12 + (s - 16)];
  if (s < 32) return 0.f;
  if (s < 44) return lo_part(spro[240 + h * 12 + (s - 32)]);
  if (s < 56) return spro[240 + h * 12 + (s - 44)];
  if (s < 64) return 0.f;
  if (s < 67) return cc[s - 64];
  if (s < 70) return lo_part(cc[s - 67]);
  if (s < 73) return cc[s - 70];
  return 0.f;
}

// ---------------------------------------------------------------------------
// Kernel A: projections + MFMA table packing. 4 rows/block (grid 1024 x 512)
// — W re-read per block drops 4x (L2-BW relief). In-block dtype detect
// (fp32 low-halves trip exp>=0xC0 ~25%; bf16 N(0,1) never).
// ---------------------------------------------------------------------------
__global__ __launch_bounds__(512) void proj_kernel(
    const void* feat, const void* coords,
    const void* Wq,  const void* bq,  const void* Wk,  const void* bk,
    const void* Wv,  const void* bv,  const void* Wqp, const void* bqp,
    const void* Wkp, const void* bkp, const void* Wvp, const void* bvp,
    const void* w_c, const void* w_l, float* ws)
{
  const int t = threadIdx.x;
  const int row0 = blockIdx.x * 4;
  const int b = row0 >> 11;
  __shared__ int scnt;
  __shared__ float sfT[64 * 4];       // [f][rr]
  __shared__ float spro[4][336];

  // in-block dtype detect over feat[0..511] ushorts
  if (t == 0) scnt = 0;
  __syncthreads();
  {
    const unsigned short uv = ((const unsigned short*)feat)[t];
    const unsigned e = (uv >> 7) & 0xFFu;
    const unsigned long long bl = __ballot(e >= 0xC0u);
    if ((t & 63) == 0) atomicAdd(&scnt, (int)__popcll(bl));
  }
  __syncthreads();
  const int mode = (scnt > 16) ? 1 : 0;

  if (t < 256) {
    const int rr = t >> 6, f = t & 63;
    sfT[f * 4 + rr] = ldm(feat, (size_t)(row0 + rr) * 64 + f, mode);
  }
  __syncthreads();

  if (t < 336) {
    const void *W, *bias; int odim, c, cls, ofs;
    if (t < 64)       { W = Wq;  bias = bq;  odim = 64; c = t;       cls = 0; ofs = 0; }
    else if (t < 128) { W = Wk;  bias = bk;  odim = 64; c = t - 64;  cls = 1; ofs = 64; }
    else if (t < 192) { W = Wv;  bias = bv;  odim = 64; c = t - 128; cls = 2; ofs = 128; }
    else if (t < 240) { W = Wqp; bias = bqp; odim = 48; c = t - 192; cls = 3; ofs = 192; }
    else if (t < 288) { W = Wkp; bias = bkp; odim = 48; c = t - 240; cls = 4; ofs = 240; }
    else              { W = Wvp; bias = bvp; odim = 48; c = t - 288; cls = 5; ofs = 288; }
    const float bb = ldm(bias, c, mode);
    float a0 = bb, a1 = bb, a2 = bb, a3 = bb;
    if (mode) {
      const float* Wf = (const float*)W;
      #pragma unroll 8
      for (int f = 0; f < 64; ++f) {
        const float wf = Wf[(size_t)f * odim + c];
        const float4 fv = *(const float4*)(sfT + f * 4);
        a0 = fmaf(fv.x, wf, a0); a1 = fmaf(fv.y, wf, a1);
        a2 = fmaf(fv.z, wf, a2); a3 = fmaf(fv.w, wf, a3);
      }
    } else {
      const bf16* Wb = (const bf16*)W;
      #pragma unroll 8
      for (int f = 0; f < 64; ++f) {
        const float wf = b2f(Wb[(size_t)f * odim + c]);
        const float4 fv = *(const float4*)(sfT + f * 4);
        a0 = fmaf(fv.x, wf, a0); a1 = fmaf(fv.y, wf, a1);
        a2 = fmaf(fv.z, wf, a2); a3 = fmaf(fv.w, wf, a3);
      }
    }
    float av[4] = {a0, a1, a2, a3};
    #pragma unroll
    for (int rr = 0; rr < 4; ++rr) {
      float acc = av[rr];
      if (cls >= 3) {
        acc += ldm(coords, (size_t)(row0 + rr) * 3 + (c % 3), mode);
        if (cls == 3 || cls == 4) acc -= CENTER;   // center qp,kp (shift-inv)
      }
      spro[rr][ofs + c] = acc;
    }
  }
  __syncthreads();

  if (t < 384) {
    const bool isq = (t < 192);
    const int per = isq ? t : t - 192;
    const int h = per / 48, w = per - h * 48;
    const float wl = softplus_f(ldm(w_l, h, mode)) * 0.25f;
    const float wc = softplus_f(ldm(w_c, h, mode));
    uint32* tab = (uint32*)(ws + (isq ? QT_OFF : KT_OFF));
    #pragma unroll 1
    for (int rr = 0; rr < 4; ++rr) {
      const int row = row0 + rr, i = row & 2047;
      float cc[3];
      cc[0] = ldm(coords, (size_t)row * 3 + 0, mode) - CENTER;
      cc[1] = ldm(coords, (size_t)row * 3 + 1, mode) - CENTER;
      cc[2] = ldm(coords, (size_t)row * 3 + 2, mode) - CENTER;
      const float* sp = spro[rr];
      float a0, a1;
      if (isq) { a0 = qslot(h, 2 * w, sp, cc, wl, wc);
                 a1 = qslot(h, 2 * w + 1, sp, cc, wl, wc); }
      else     { a0 = kslot(h, 2 * w, sp, cc);
                 a1 = kslot(h, 2 * w + 1, sp, cc); }
      tab[((size_t)(b * 4 + h) * NN + i) * 48 + w] = pk2(a0, a1);
    }
  } else if (t < 496) {
    const int tt = t - 384;
    const int h = tt / 28, d = tt - h * 28;
    unsigned short* VTu = (unsigned short*)(ws + VT_OFF);
    #pragma unroll 1
    for (int rr = 0; rr < 4; ++rr) {
      const int row = row0 + rr, i = row & 2047;
      const float val = (d < 16) ? spro[rr][128 + h * 16 + d]
                                 : spro[rr][288 + h * 12 + (d - 16)];
      VTu[((size_t)((b * 4 + h) * 28 + d)) * NN + i] = f2bu(val);
    }
  } else if (t < 500) {
    const int h = t - 496;
    const float wc = softplus_f(ldm(w_c, h, mode));
    #pragma unroll 1
    for (int rr = 0; rr < 4; ++rr) {
      const int row = row0 + rr, i = row & 2047;
      float s = 0.f;
      #pragma unroll
      for (int e = 0; e < 12; ++e) {
        const float y = spro[rr][240 + h * 12 + e];
        s = fmaf(y, y, s);
      }
      ws[SB_OFF + (size_t)(b * 4 + h) * NN + i] = -0.5f * wc * s;
    }
  } else if (t == 500) {
    #pragma unroll 1
    for (int rr = 0; rr < 4; ++rr) {
      const int row = row0 + rr;
      float cc[3];
      cc[0] = ldm(coords, (size_t)row * 3 + 0, mode) - CENTER;
      cc[1] = ldm(coords, (size_t)row * 3 + 1, mode) - CENTER;
      cc[2] = ldm(coords, (size_t)row * 3 + 2, mode) - CENTER;
      ws[CQ_OFF + row] = fmaf(cc[0], cc[0], fmaf(cc[1], cc[1], cc[2] * cc[2]));
    }
  }
}

// ---------------------------------------------------------------------------
// Kernel B: MFMA flash attention. Delta from passing round 13: the P LDS
// round-trip is gone. V is staged with j-chunks interleaved [0,4,1,5,2,6,3,7]
// (sigma(8g+e) = e<4 ? 4g+e : 16+4g+(e-4)), so the PV B-operand is exactly
// the lane's own 4 pk2 words — same verified k-slot layout as the S-step.
// grid (jc=4, it=16, bh=8), 512 threads.
// ---------------------------------------------------------------------------
__global__ __launch_bounds__(512) void attn_kernel(
    const uint32* __restrict__ QTg, const uint32* __restrict__ KTg,
    const uint32* __restrict__ VTg, const float* __restrict__ CQ,
    const float* __restrict__ SBt, float* __restrict__ parb)
{
  const int tid = threadIdx.x;
  const int lane = tid & 63;
  const int li = lane & 15, g = lane >> 4;
  const int jc = blockIdx.x;        // 0..3   (512 j)
  const int it = blockIdx.y;        // 0..15  (128 i)
  const int bh = blockIdx.z;        // 0..7
  const int b = bh >> 2;
  const int iloc = it * 128 + (tid >> 6) * 16 + li;
  const int j0base = jc * 512;

  const uint32* qrow = QTg + ((size_t)bh * NN + iloc) * 48;
  const bf16x8 B1 = *(const bf16x8*)(qrow + 4 * g);
  const bf16x8 B2 = *(const bf16x8*)(qrow + 16 + 4 * g);
  const bf16x8 B3 = *(const bf16x8*)(qrow + 32 + 4 * g);
  const float ciq = CQ[(size_t)b * NN + iloc];

  float m = -1e9f, l = 0.f;
  f32x4 acc0 = {0.f, 0.f, 0.f, 0.f};
  f32x4 acc1 = {0.f, 0.f, 0.f, 0.f};

  __shared__ uint32 sKT[32 * 52];    // [32 j][104 bf16] padded rows
  __shared__ uint32 sVT[32 * 20];    // [32 d][40 bf16], sigma-permuted slots
  __shared__ float  sCS[64];         // [32 j][cjq, sbias]

  if (tid < 80) sVT[560 + tid] = 0;  // zero d=28..31 rows

  const float4* KT4 = (const float4*)(KTg + ((size_t)bh * NN + j0base) * 48);
  const float4* VT4 = (const float4*)VTg;
  const size_t vbase = (size_t)(bh * 28) * 256 + (j0base >> 3);

  float4 kreg = {0.f, 0.f, 0.f, 0.f};
  float4 vreg = {0.f, 0.f, 0.f, 0.f};
  float  creg = 0.f;
  const int kj = tid / 12, kq = tid - kj * 12;     // tid<384 role
  const int vd = tid >> 2, vq = tid & 3;           // tid<112 role
  const int cx = tid - 448, cj = cx & 31;          // tid>=448 role
  const int vA = (vq < 2) ? (8 * vq) : (8 * vq - 14);  // sigma chunk offsets

  auto issue = [&](int jt) {
    if (tid < 384) kreg = KT4[(size_t)jt * 384 + kj * 12 + kq];
    if (tid < 112) vreg = VT4[vbase + (size_t)vd * 256 + jt * 4 + vq];
    if (tid >= 448) {
      const int jg = j0base + jt * 32 + cj;
      creg = (cx < 32) ? CQ[(size_t)b * NN + jg] : SBt[(size_t)bh * NN + jg];
    }
  };

  issue(0);

  #pragma unroll 1
  for (int jt = 0; jt < 16; ++jt) {
    if (tid < 384) *(float4*)(sKT + kj * 52 + kq * 4) = kreg;
    if (tid < 112) {
      *(float2*)(sVT + vd * 20 + vA)     = make_float2(vreg.x, vreg.y);
      *(float2*)(sVT + vd * 20 + vA + 4) = make_float2(vreg.z, vreg.w);
    }
    if (tid >= 448) sCS[(cj << 1) | (cx >> 5)] = creg;
    __syncthreads();
    if (jt < 15) issue(jt + 1);    // async: latency hides under compute below

    float s[8];
    const f32x4 z = {0.f, 0.f, 0.f, 0.f};
    __builtin_amdgcn_s_setprio(1);
    #pragma unroll
    for (int h2 = 0; h2 < 2; ++h2) {
      const uint32* arow = sKT + (h2 * 16 + li) * 52;
      const bf16x8 A1 = *(const bf16x8*)(arow + 4 * g);
      const bf16x8 A2 = *(const bf16x8*)(arow + 16 + 4 * g);
      const bf16x8 A3 = *(const bf16x8*)(arow + 32 + 4 * g);
      f32x4 Cs = __builtin_amdgcn_mfma_f32_16x16x32_bf16(A1, B1, z, 0, 0, 0);
      Cs = __builtin_amdgcn_mfma_f32_16x16x32_bf16(A2, B2, Cs, 0, 0, 0);
      const f32x4 Cd = __builtin_amdgcn_mfma_f32_16x16x32_bf16(A3, B3, z, 0, 0, 0);
      #pragma unroll
      for (int r = 0; r < 4; ++r) {
        const int jj = h2 * 16 + g * 4 + r;
        const float cjq = sCS[jj * 2], sb = sCS[jj * 2 + 1];
        const float d2 = fmaf(-2.f, Cd[r], ciq + cjq);
        const float sv = Cs[r] + sb;
        s[h2 * 4 + r] = (d2 > 100.f) ? -1e30f : sv;
      }
    }
    __builtin_amdgcn_s_setprio(0);

    float smax = fmaxf(fmaxf(fmaxf(s[0], s[1]), fmaxf(s[2], s[3])),
                       fmaxf(fmaxf(s[4], s[5]), fmaxf(s[6], s[7])));
    smax = fmaxf(smax, __shfl_xor(smax, 16));
    smax = fmaxf(smax, __shfl_xor(smax, 32));
    const float mnew = fmaxf(m, smax);
    const float alpha = __expf(m - mnew);
    m = mnew;
    l *= alpha; acc0 *= alpha; acc1 *= alpha;
    float p[8];
    #pragma unroll
    for (int k = 0; k < 8; ++k) p[k] = __expf(s[k] - m);
    l += ((p[0] + p[1]) + (p[2] + p[3])) + ((p[4] + p[5]) + (p[6] + p[7]));

    // PV B-operand built entirely in-register (sigma-matched V staging)
    union { uint32 u[4]; bf16x8 v; } bp;
    bp.u[0] = pk2(p[0], p[1]); bp.u[1] = pk2(p[2], p[3]);
    bp.u[2] = pk2(p[4], p[5]); bp.u[3] = pk2(p[6], p[7]);

    const bf16x8 Av0 = *(const bf16x8*)(sVT + li * 20 + 4 * g);
    const bf16x8 Av1 = *(const bf16x8*)(sVT + (16 + li) * 20 + 4 * g);
    __builtin_amdgcn_s_setprio(1);
    acc0 = __builtin_amdgcn_mfma_f32_16x16x32_bf16(Av0, bp.v, acc0, 0, 0, 0);
    acc1 = __builtin_amdgcn_mfma_f32_16x16x32_bf16(Av1, bp.v, acc1, 0, 0, 0);
    __builtin_amdgcn_s_setprio(0);
    __syncthreads();
  }

  l += __shfl_xor(l, 16);
  l += __shfl_xor(l, 32);

  float* rec = parb + ((size_t)(bh * 4 + jc) * NN + iloc) * 16;
  rec[0] = m; rec[1] = l;                    // 4 lanes write same values
  uint32* ru = (uint32*)(rec + 2);
  ru[2 * g]     = pk2(acc0[0], acc0[1]);     // slot s holds acc[2s],acc[2s+1]
  ru[2 * g + 1] = pk2(acc0[2], acc0[3]);
  if (g < 3) {
    ru[8 + 2 * g]     = pk2(acc1[0], acc1[1]);
    ru[8 + 2 * g + 1] = pk2(acc1[2], acc1[3]);
  }
}

// ---------------------------------------------------------------------------
// Kernel C: fused combine + output GEMM (proven round 13) + in-block detect.
// ---------------------------------------------------------------------------
__global__ __launch_bounds__(256) void out_kernel(
    const float* __restrict__ parb, const void* Wo, const void* bo,
    const unsigned short* __restrict__ ufeat, void* outp)
{
  const int t = threadIdx.x;
  const int blk = blockIdx.x;
  __shared__ int scnt;
  __shared__ float si[4 * 112];
  __shared__ float sM[16], sIL[16];

  if (t == 0) scnt = 0;
  __syncthreads();
  {
    const unsigned e = (ufeat[t] >> 7) & 0xFFu;
    const unsigned long long bl = __ballot(e >= 0xC0u);
    if ((t & 63) == 0) atomicAdd(&scnt, (int)__popcll(bl));
  }
  __syncthreads();
  const int mode = (scnt > 8) ? 1 : 0;

  if (t < 16) {
    const int lr = t >> 2, h = t & 3;
    const int row = blk * 4 + lr, b = row >> 11, i = row & 2047;
    const int bh = b * 4 + h;
    const float* base = parb + ((size_t)(bh * 4) * NN + i) * 16;
    float M = -1e9f;
    #pragma unroll
    for (int c = 0; c < 4; ++c) M = fmaxf(M, base[(size_t)c * NN * 16]);
    float L = 0.f;
    #pragma unroll
    for (int c = 0; c < 4; ++c) {
      const float* r = base + (size_t)c * NN * 16;
      L = fmaf(r[1], __expf(r[0] - M), L);
    }
    sM[t] = M; sIL[t] = 1.f / L;
  }
  __syncthreads();

  if (t < 224) {
    const int u = t / 14, pr = t - u * 14;   // u: (lr,h) 0..15, pr: pair 0..13
    const int lr = u >> 2, h = u & 3;
    const int row = blk * 4 + lr, b = row >> 11, i = row & 2047;
    const int bh = b * 4 + h;
    const float* base = parb + ((size_t)(bh * 4) * NN + i) * 16;
    const float M = sM[u], iL = sIL[u];
    float o0 = 0.f, o1 = 0.f;
    #pragma unroll
    for (int c = 0; c < 4; ++c) {
      const float* r = base + (size_t)c * NN * 16;
      const float wgt = __expf(r[0] - M);
      const float2 f = upk2(((const unsigned*)(r + 2))[pr]);
      o0 = fmaf(f.x, wgt, o0); o1 = fmaf(f.y, wgt, o1);
    }
    const int d = 2 * pr;
    const int col = (d < 16) ? (h * 16 + d) : (64 + h * 12 + (d - 16));
    si[lr * 112 + col]     = o0 * iL;
    si[lr * 112 + col + 1] = o1 * iL;
  }
  __syncthreads();

  const int lr = t >> 6, c = t & 63;
  float acc = mode ? ((const float*)bo)[c] : b2f(((const bf16*)bo)[c]);
  if (mode) {
    const float* Wf = (const float*)Wo;
    #pragma unroll 16
    for (int kk = 0; kk < 112; ++kk)
      acc = fmaf(si[lr * 112 + kk], Wf[(size_t)kk * 64 + c], acc);
  } else {
    const bf16* Wb = (const bf16*)Wo;
    #pragma unroll 16
    for (int kk = 0; kk < 112; ++kk)
      acc = fmaf(si[lr * 112 + kk], b2f(Wb[(size_t)kk * 64 + c]), acc);
  }
  const size_t oi = (size_t)(blk * 4 + lr) * 64 + c;
  if (mode) ((float*)outp)[oi] = acc;
  else      ((bf16*)outp)[oi] = __float2bfloat16(acc);
}

extern "C" void kernel_launch(void* const* d_in, const int* in_sizes, int n_in,
                              void* d_out, int out_size, void* d_ws, size_t ws_size,
                              hipStream_t stream)
{
  float* ws = (float*)d_ws;

  proj_kernel<<<BB * NN / 4, 512, 0, stream>>>(d_in[0], d_in[1], d_in[2], d_in[3],
      d_in[4], d_in[5], d_in[6], d_in[7], d_in[8], d_in[9], d_in[10], d_in[11],
      d_in[12], d_in[13], d_in[16], d_in[17], ws);

  attn_kernel<<<dim3(4, 16, 8), 512, 0, stream>>>(
      (const uint32*)(ws + QT_OFF), (const uint32*)(ws + KT_OFF),
      (const uint32*)(ws + VT_OFF), ws + CQ_OFF, ws + SB_OFF, ws + PAR_OFF);

  out_kernel<<<(BB * NN) / 4, 256, 0, stream>>>(
      ws + PAR_OFF, d_in[14], d_in[15], (const unsigned short*)d_in[0], d_out);
}